// Round 13
// baseline (162.098 us; speedup 1.0000x reference)
//
#include <hip/hip_runtime.h>

typedef unsigned short u16;
typedef unsigned int   u32;
typedef __attribute__((ext_vector_type(8))) short bf16x8;
typedef __attribute__((ext_vector_type(4))) short s16x4;
typedef __attribute__((ext_vector_type(4))) float f32x4;

#define MFMA16(a,b,c) __builtin_amdgcn_mfma_f32_16x16x32_bf16((a),(b),(c),0,0,0)

__device__ __forceinline__ float bf2f(u16 u){ return __uint_as_float(((u32)u)<<16); }
__device__ __forceinline__ u16 f2bf(float f){
  u32 u = __float_as_uint(f);
  return (u16)((u + 0x7fffu + ((u>>16)&1u)) >> 16);
}
__device__ __forceinline__ u32 encf(float f){ u32 u=__float_as_uint(f); return (u&0x80000000u)? ~u : (u|0x80000000u); }
__device__ __forceinline__ float decf(u32 u){ return (u&0x80000000u)? __uint_as_float(u&0x7fffffffu) : __uint_as_float(~u); }

__device__ __forceinline__ void async_lds16(u16* lds, const u16* g){
  __builtin_amdgcn_global_load_lds((const __attribute__((address_space(1))) void*)g,
                                   (__attribute__((address_space(3))) void*)lds,
                                   16, 0, 0);
}

template<int ROWS>
__device__ __forceinline__ void stage64(u16* dst, const u16* src, int srcStride, int tid){
  #pragma unroll
  for (int u=tid; u<ROWS*8; u+=256){
    int r=u>>3, c=(u&7)<<3;
    *(int4*)&dst[r*72+c] = *(const int4*)&src[(size_t)r*srcStride + c];
  }
}

// ---------------- setup: W transposes (0..1023) + init/cast/ones (1024..1279) ----------------
__global__ __launch_bounds__(256) void k_setup(u32* kmaxEnc, u16* projS, u16* vTA,
    float* ctxs, float* kcss,
    const float* __restrict__ proj, const float* __restrict__ x, u16* __restrict__ xb,
    const float* s0, const float* s1, const float* s2, const float* s3,
    u16* d0, u16* d1, u16* d2, u16* d3)
{
  int bid=blockIdx.x, tid=threadIdx.x;
  if (bid < 1024){
    int z = bid>>8, t = bid&255;
    const float* src = z==0?s0:(z==1?s1:(z==2?s2:s3));
    u16* dst         = z==0?d0:(z==1?d1:(z==2?d2:d3));
    __shared__ u16 tl[32][34];
    int c0=(t&15)*32, r0=(t>>4)*32;
    for (int u=tid; u<1024; u+=256){ int r=u>>5, c=u&31; tl[r][c]=f2bf(src[(size_t)(r0+r)*512 + c0+c]); }
    __syncthreads();
    for (int u=tid; u<1024; u+=256){ int c=u>>5, r=u&31; dst[(size_t)(c0+c)*512 + r0+r]=tl[r][c]; }
  } else {
    int i = (bid-1024)*256 + tid;
    int st = 256*256;
    for (int j=i; j<32; j+=st) kmaxEnc[j]=0u;
    for (int j=i; j<2048; j+=st) ctxs[j]=0.f;
    for (int j=i; j<32; j+=st) kcss[j]=0.f;
    const float dn = 0.35355339059327373f;
    for (int j=i; j<512*64; j+=st) projS[j] = f2bf(dn*proj[j]);
    for (int j=i; j<524288; j+=st){
      float4 a = *(const float4*)&x[(size_t)j*8];
      float4 b = *(const float4*)&x[(size_t)j*8+4];
      u16 tmp[8] = {f2bf(a.x),f2bf(a.y),f2bf(a.z),f2bf(a.w),
                    f2bf(b.x),f2bf(b.y),f2bf(b.z),f2bf(b.w)};
      *(int4*)&xb[(size_t)j*8] = *(const int4*)tmp;
    }
    for (int j=i; j<1048576; j+=st){
      int gbh = j>>15, rr = (j>>11)&15, n = j&2047;
      vTA[(size_t)gbh*80*2048 + (size_t)(64+rr)*2048 + n] = (rr==0) ? (u16)0x3F80 : (u16)0;
    }
  }
}

// ---------------- prep: trv (0..4095) into vTA rows 0..63 + vsum (4096..4127) ----------------
__global__ __launch_bounds__(256) void k_prep(const u16* __restrict__ vB, u16* __restrict__ vTA,
    float* __restrict__ vsum)
{
  int bid=blockIdx.x, tid=threadIdx.x;
  if (bid < 4096){
    int xx=bid&1, y=(bid>>1)&63, bh=bid>>7;
    int b=bh>>3, h=bh&7;
    int dd0=xx*32, n0=y*32;
    __shared__ u16 t[32][34];
    const u16* s = vB + (size_t)(b*2048)*512 + h*64;
    for (int u=tid; u<1024; u+=256){ int r=u>>5, c=u&31; t[r][c]=s[(size_t)(n0+r)*512 + dd0+c]; }
    __syncthreads();
    u16* d = vTA + (size_t)bh*80*2048;
    for (int u=tid; u<1024; u+=256){ int c=u>>5, r=u&31; d[(size_t)(dd0+c)*2048 + n0+r]=t[r][c]; }
  } else {
    int bh=bid-4096; int b=bh>>3, h=bh&7;
    int d=tid&63, part=tid>>6;
    const u16* src = vB + (size_t)(b*2048 + part*512)*512 + h*64 + d;
    float s=0.f;
    for (int n=0;n<512;++n) s += bf2f(src[(size_t)n*512]);
    __shared__ float red[256];
    red[tid]=s; __syncthreads();
    if (part==0) vsum[bh*64+d]=red[d]+red[64+d]+red[128+d]+red[192+d];
  }
}

// ---------------- GEMM m97-style ----------------
template<bool OF32>
__global__ __launch_bounds__(256) void k_gemm2(const u16* __restrict__ A,
    const u16* BT0, const u16* BT1, const u16* BT2,
    const float* b0, const float* b1, const float* b2,
    void* O0, void* O1, void* O2)
{
  int z = blockIdx.z;
  const u16* BT    = z==0?BT0:(z==1?BT1:BT2);
  const float* bias= z==0?b0 :(z==1?b1 :b2 );
  void* Ov         = z==0?O0 :(z==1?O1 :O2 );
  int bm = blockIdx.x*128, bn = blockIdx.y*64;
  __shared__ u16 sA[128*64];
  __shared__ u16 sB[64*64];
  int tid=threadIdx.x, w=tid>>6, lane=tid&63;
  int lr = lane>>3, lc = (lane&7)*8;
  f32x4 acc[8] = {};
  for (int kk=0; kk<512; kk+=64){
    __syncthreads();
    #pragma unroll
    for (int i=0;i<4;++i){
      int idx = w*4+i;
      async_lds16(&sA[idx*512], A + (size_t)(bm + idx*8 + lr)*512 + kk + lc);
    }
    #pragma unroll
    for (int i=0;i<2;++i){
      int idx = w*2+i;
      async_lds16(&sB[idx*512], BT + (size_t)(bn + idx*8 + lr)*512 + kk + lc);
    }
    __syncthreads();
    int fr = lane&15, kb=(lane>>4)*8;
    #pragma unroll
    for (int rt=0; rt<2; ++rt){
      int ar = (w*2+rt)*16 + fr;
      #pragma unroll
      for (int ct=0; ct<4; ++ct){
        int br = ct*16 + fr;
        #pragma unroll
        for (int kc=0; kc<2; ++kc){
          bf16x8 av = *(const bf16x8*)&sA[ar*64 + kc*32 + kb];
          bf16x8 bv = *(const bf16x8*)&sB[br*64 + kc*32 + kb];
          acc[rt*4+ct] = MFMA16(av,bv,acc[rt*4+ct]);
        }
      }
    }
  }
  int colg = lane&15, rowg=(lane>>4)*4;
  #pragma unroll
  for (int rt=0; rt<2; ++rt){
    #pragma unroll
    for (int ct=0; ct<4; ++ct){
      int col = bn + ct*16 + colg;
      float bv = bias[col];
      #pragma unroll
      for (int j=0;j<4;++j){
        int row = bm + (w*2+rt)*16 + rowg + j;
        if constexpr (OF32) ((float*)Ov)[(size_t)row*512 + col] = acc[rt*4+ct][j] + bv;
        else                ((u16*) Ov)[(size_t)row*512 + col] = f2bf(acc[rt*4+ct][j] + bv);
      }
    }
  }
}

// ---------------- one-shot k-feature GEMM ----------------
__global__ __launch_bounds__(256) void k_feat(const u16* __restrict__ kB, const u16* __restrict__ projS,
    u16* __restrict__ kpT, u32* __restrict__ kmaxEnc, int hbase, int NHP)
{
  int xx=blockIdx.x, hy=blockIdx.y;
  int bm = xx&63, bn = xx>>6;
  int h = hbase + hy;
  int b = bm>>4;
  int gbh = b*8 + h;
  int lbh = b*NHP + hy;
  __shared__ __align__(16) u16 sA[128*72];
  __shared__ __align__(16) u16 sB[64*72];
  __shared__ float diag[128];
  __shared__ float red[4];
  u16* sT = sA;
  int tid=threadIdx.x, w=tid>>6, lane=tid&63;
  int fr=lane&15, kb=(lane>>4)*8, rowg=(lane>>4)*4;
  stage64<128>(sA, kB + (size_t)(bm*128)*512 + h*64, 512, tid);
  stage64<64> (sB, projS + bn*64*64, 64, tid);
  __syncthreads();
  if (tid<128){
    float s=0.f;
    #pragma unroll
    for (int c=0;c<64;c+=8){
      bf16x8 v=*(const bf16x8*)&sA[tid*72+c];
      #pragma unroll
      for (int j=0;j<8;++j){ float f=bf2f((u16)v[j]); s+=f*f; }
    }
    diag[tid]=0.0625f*s;
  }
  f32x4 acc[8];
  float lm=-3.0e38f;
  #pragma unroll
  for (int rt=0;rt<2;++rt){
    int ar=(w*2+rt)*16+fr;
    #pragma unroll
    for (int mt=0;mt<4;++mt){
      f32x4 a={0.f,0.f,0.f,0.f};
      a=MFMA16(*(const bf16x8*)&sA[ar*72+kb],    *(const bf16x8*)&sB[(mt*16+fr)*72+kb],    a);
      a=MFMA16(*(const bf16x8*)&sA[ar*72+32+kb], *(const bf16x8*)&sB[(mt*16+fr)*72+32+kb], a);
      acc[rt*4+mt]=a;
      lm=fmaxf(lm, fmaxf(fmaxf(a[0],a[1]),fmaxf(a[2],a[3])));
    }
  }
  __syncthreads();
  #pragma unroll
  for (int rt=0;rt<2;++rt){
    int nl=(w*2+rt)*16+rowg;
    #pragma unroll
    for (int mt=0;mt<4;++mt){
      int ml=mt*16+fr;
      s16x4 pk;
      #pragma unroll
      for (int j=0;j<4;++j) pk[j]=(short)f2bf(__expf(acc[rt*4+mt][j]-diag[nl+j]));
      *(s16x4*)&sT[ml*136+nl]=pk;
    }
  }
  #pragma unroll
  for (int m2=1;m2<64;m2<<=1) lm=fmaxf(lm,__shfl_xor(lm,m2,64));
  if (lane==0) red[w]=lm;
  __syncthreads();
  if (tid==0) atomicMax(&kmaxEnc[gbh], encf(fmaxf(fmaxf(red[0],red[1]),fmaxf(red[2],red[3]))));
  for (int u=tid; u<1024; u+=256){
    int r=u>>4, c=(u&15)<<3;
    *(int4*)&kpT[((size_t)lbh*512 + bn*64 + r)*2048 + (bm&15)*128 + c] = *(const int4*)&sT[r*136+c];
  }
}

// ---------------- ctx GEMM, split-K=8, f32 partials ----------------
__global__ __launch_bounds__(256) void k_ctxg(const u16* __restrict__ kpT, const u16* __restrict__ vTA,
    float* __restrict__ ctxP, int hbase, int NHP)
{
  int NL = NHP*4;
  int x=blockIdx.x;
  int lbh = x % NL, rem = x / NL;
  int ks = rem>>2, mt4 = rem&3;
  int b = lbh/NHP, hy = lbh%NHP;
  int gbh = b*8 + hbase + hy;
  int m0 = mt4*128;
  __shared__ u16 sA[128*64];
  __shared__ u16 sB[80*64];
  int tid=threadIdx.x, w=tid>>6, lane=tid&63;
  int lr=lane>>3, lc=(lane&7)*8;
  int fr=lane&15, kb=(lane>>4)*8, rowg=(lane>>4)*4;
  const u16* Ab = kpT + ((size_t)lbh*512 + m0)*2048 + ks*256;
  const u16* Bb = vTA + (size_t)gbh*80*2048 + ks*256;
  f32x4 acc[10] = {};
  for (int kk=0; kk<256; kk+=64){
    __syncthreads();
    #pragma unroll
    for (int i=0;i<4;++i){
      int idx = w*4+i;
      async_lds16(&sA[idx*512], Ab + (size_t)(idx*8+lr)*2048 + kk + lc);
    }
    for (int c=w; c<10; c+=4){
      async_lds16(&sB[c*512], Bb + (size_t)(c*8+lr)*2048 + kk + lc);
    }
    __syncthreads();
    #pragma unroll
    for (int rt=0; rt<2; ++rt){
      int ar = (w*2+rt)*16 + fr;
      #pragma unroll
      for (int ct=0; ct<5; ++ct){
        int br = ct*16 + fr;
        #pragma unroll
        for (int kc=0; kc<2; ++kc){
          bf16x8 av = *(const bf16x8*)&sA[ar*64 + kc*32 + kb];
          bf16x8 bv = *(const bf16x8*)&sB[br*64 + kc*32 + kb];
          acc[rt*5+ct] = MFMA16(av,bv,acc[rt*5+ct]);
        }
      }
    }
  }
  #pragma unroll
  for (int rt=0;rt<2;++rt){
    #pragma unroll
    for (int ct=0;ct<5;++ct){
      int col = ct*16 + fr;
      #pragma unroll
      for (int j=0;j<4;++j){
        int row = m0 + (w*2+rt)*16 + rowg + j;
        ctxP[(((size_t)ks*NL + lbh)*512 + row)*80 + col] = acc[rt*5+ct][j];
      }
    }
  }
}

// ---------------- combine 8 f32 partials -> ctxT + kcs + sums ----------------
__global__ __launch_bounds__(256) void k_combK(const float* __restrict__ ctxP, u16* __restrict__ ctxT,
    float* __restrict__ kcs, float* __restrict__ ctxsum, float* __restrict__ kcssum, int hbase, int NHP)
{
  int NL = NHP*4;
  int lbh=blockIdx.x, mblk=blockIdx.y;
  int b=lbh/NHP, hy=lbh%NHP, gbh=b*8+hbase+hy;
  int m0=mblk*128;
  __shared__ float sAcc[128*80];
  int tid=threadIdx.x;
  #pragma unroll
  for (int i=0;i<5;++i){
    int u=tid+i*256;
    int r=u/10, c=(u%10)*8;
    float a8[8]={0.f,0.f,0.f,0.f,0.f,0.f,0.f,0.f};
    #pragma unroll
    for (int ks=0;ks<8;++ks){
      const float* p = &ctxP[(((size_t)ks*NL+lbh)*512 + m0+r)*80 + c];
      float4 v0=*(const float4*)p;
      float4 v1=*(const float4*)(p+4);
      a8[0]+=v0.x; a8[1]+=v0.y; a8[2]+=v0.z; a8[3]+=v0.w;
      a8[4]+=v1.x; a8[5]+=v1.y; a8[6]+=v1.z; a8[7]+=v1.w;
    }
    #pragma unroll
    for (int j=0;j<8;++j) sAcc[r*80+c+j]=a8[j];
  }
  __syncthreads();
  for (int u=tid; u<2048; u+=256){
    int d=u>>5, ml=(u&31)*4;
    u16 t[4];
    #pragma unroll
    for (int j=0;j<4;++j) t[j]=f2bf(sAcc[(ml+j)*80 + d]);
    *(int2*)&ctxT[((size_t)gbh*64 + d)*512 + m0 + ml] = *(const int2*)t;
  }
  if (tid<64){
    float s=0.f;
    for (int m=0;m<128;++m) s += bf2f(f2bf(sAcc[m*80+tid]));
    atomicAdd(&ctxsum[gbh*64+tid], s);
  }
  if (tid>=128 && tid<256){
    int m=tid-128;
    float v=sAcc[m*80+64];
    kcs[(size_t)gbh*512 + m0 + m] = v;
    float a=v;
    #pragma unroll
    for (int s2=1;s2<64;s2<<=1) a += __shfl_xor(a,s2,64);
    if ((m&63)==0) atomicAdd(&kcssum[gbh], a);   // BOTH waves contribute (bug fix)
  }
}

// ---------------- q features + PV + eps epilogue (round-6 proven, unchanged) ----------------
__global__ __launch_bounds__(256) void k_qpout2(const u16* __restrict__ qB, const u16* __restrict__ projS,
    const float* __restrict__ kcs, const u16* __restrict__ ctxT,
    const float* __restrict__ ctxsum, const float* __restrict__ kcssum,
    const float* __restrict__ vsum, const u32* __restrict__ kmaxEnc,
    u16* __restrict__ outc)
{
  int h=blockIdx.x, chunk=blockIdx.y, b=blockIdx.z;
  int bh=b*8+h;
  int t0 = b*2048 + chunk*128;
  __shared__ u16 sP[2][64*64];
  __shared__ u16 sCt[2][64*64];
  __shared__ u16 qpL[128*72];
  __shared__ float sK[512];
  __shared__ float diag[128];
  int tid=threadIdx.x, w=tid>>6, lane=tid&63;
  int fr=lane&15, kb=(lane>>4)*8, rowg=(lane>>4)*4;
  bf16x8 qf[2][2];
  #pragma unroll
  for (int rt=0;rt<2;++rt)
    #pragma unroll
    for (int kc=0;kc<2;++kc)
      qf[rt][kc] = *(const bf16x8*)&qB[(size_t)(t0 + w*32 + rt*16 + fr)*512 + h*64 + kc*32 + kb];
  #pragma unroll
  for (int rt=0;rt<2;++rt){
    float s=0.f;
    #pragma unroll
    for (int kc=0;kc<2;++kc)
      #pragma unroll
      for (int j=0;j<8;++j){ float f=bf2f((u16)qf[rt][kc][j]); s+=f*f; }
    s += __shfl_xor(s,16,64); s += __shfl_xor(s,32,64);
    if (lane<16) diag[w*32 + rt*16 + fr] = 0.0625f*s;
  }
  for (int u=tid; u<512; u+=256) sK[u] = kcs[(size_t)bh*512 + u];
  {
    const u16* gp = projS;
    const u16* gc = ctxT + (size_t)bh*64*512;
    int lr=lane>>3, lc=(lane&7)*8;
    #pragma unroll
    for (int i=0;i<2;++i){
      int idx = w*2+i;
      async_lds16(&sP[0][idx*512], gp + idx*512 + lane*8);
      async_lds16(&sCt[0][idx*512], gc + (size_t)(idx*8+lr)*512 + lc);
    }
  }
  f32x4 acc2[2][4]={};
  float mx[2][4], dp[2][4], rs[2][4];
  #pragma unroll
  for (int rt=0;rt<2;++rt)
    #pragma unroll
    for (int j=0;j<4;++j){ mx[rt][j]=-3.0e38f; dp[rt][j]=0.f; rs[rt][j]=0.f; }
  __syncthreads();
  for (int mc=0; mc<8; ++mc){
    int cur = mc&1;
    if (mc<7){
      int nxt = cur^1;
      const u16* gp = projS + (mc+1)*64*64;
      const u16* gc = ctxT + (size_t)bh*64*512 + (mc+1)*64;
      int lr=lane>>3, lc=(lane&7)*8;
      #pragma unroll
      for (int i=0;i<2;++i){
        int idx = w*2+i;
        async_lds16(&sP[nxt][idx*512], gp + idx*512 + lane*8);
        async_lds16(&sCt[nxt][idx*512], gc + (size_t)(idx*8+lr)*512 + lc);
      }
    }
    f32x4 facc[2][4];
    #pragma unroll
    for (int rt=0;rt<2;++rt){
      #pragma unroll
      for (int mt=0;mt<4;++mt){
        f32x4 a={0.f,0.f,0.f,0.f};
        #pragma unroll
        for (int kc=0;kc<2;++kc){
          bf16x8 bv = *(const bf16x8*)&sP[cur][(mt*16+fr)*64 + kc*32 + kb];
          a = MFMA16(qf[rt][kc], bv, a);
        }
        facc[rt][mt]=a;
      }
    }
    #pragma unroll
    for (int rt=0;rt<2;++rt){
      #pragma unroll
      for (int mt=0;mt<4;++mt){
        #pragma unroll
        for (int j=0;j<4;++j){
          int rl = w*32 + rt*16 + rowg + j;
          mx[rt][j] = fmaxf(mx[rt][j], facc[rt][mt][j]);
          float vq = __expf(facc[rt][mt][j] - diag[rl]);
          u16 us = f2bf(vq);
          qpL[rl*72 + mt*16 + fr] = us;
          float uf = bf2f(us);
          dp[rt][j] += uf*sK[mc*64 + mt*16 + fr];
          rs[rt][j] += uf;
        }
      }
    }
    __syncthreads();
    #pragma unroll
    for (int rt=0;rt<2;++rt){
      #pragma unroll
      for (int ct=0;ct<4;++ct){
        #pragma unroll
        for (int kc=0;kc<2;++kc){
          bf16x8 av = *(const bf16x8*)&qpL[(w*32+rt*16+fr)*72 + kc*32 + kb];
          bf16x8 bv = *(const bf16x8*)&sCt[cur][(ct*16+fr)*64 + kc*32 + kb];
          acc2[rt][ct] = MFMA16(av,bv,acc2[rt][ct]);
        }
      }
    }
    __syncthreads();
  }
  #pragma unroll
  for (int rt=0;rt<2;++rt){
    #pragma unroll
    for (int j=0;j<4;++j){
      #pragma unroll
      for (int s=1;s<16;s<<=1){
        dp[rt][j] += __shfl_xor(dp[rt][j],s,64);
        rs[rt][j] += __shfl_xor(rs[rt][j],s,64);
        mx[rt][j]  = fmaxf(mx[rt][j], __shfl_xor(mx[rt][j],s,64));
      }
    }
  }
  float mk  = decf(kmaxEnc[bh]);
  float emk = __expf(mk);
  float Ssum = kcssum[bh];
  const float eps=1e-4f;
  float emq[2][4];
  #pragma unroll
  for (int rt=0;rt<2;++rt)
    #pragma unroll
    for (int j=0;j<4;++j) emq[rt][j]=__expf(mx[rt][j]);
  #pragma unroll
  for (int rt=0;rt<2;++rt){
    #pragma unroll
    for (int ct=0;ct<4;++ct){
      int d = ct*16 + fr;
      float cs = ctxsum[bh*64 + d];
      float vs = vsum[bh*64 + d];
      #pragma unroll
      for (int j=0;j<4;++j){
        float eq = emq[rt][j];
        float numer = acc2[rt][ct][j] + eps*(emk*vs*rs[rt][j] + eq*cs + eps*eq*emk*512.0f*vs);
        float den   = dp[rt][j]       + eps*(emk*2048.0f*rs[rt][j] + eq*Ssum + eps*eq*emk*512.0f*2048.0f);
        int row = t0 + w*32 + rt*16 + rowg + j;
        outc[(size_t)row*512 + h*64 + d] = f2bf(numer/den);
      }
    }
  }
}

extern "C" void kernel_launch(void* const* d_in, const int* in_sizes, int n_in,
                              void* d_out, int out_size, void* d_ws, size_t ws_size,
                              hipStream_t stream)
{
  (void)in_sizes; (void)n_in; (void)out_size;
  const float* x    = (const float*)d_in[0];
  const float* Wq   = (const float*)d_in[1];
  const float* bq   = (const float*)d_in[2];
  const float* Wk   = (const float*)d_in[3];
  const float* bk   = (const float*)d_in[4];
  const float* Wv   = (const float*)d_in[5];
  const float* bv   = (const float*)d_in[6];
  const float* Wo   = (const float*)d_in[7];
  const float* bo   = (const float*)d_in[8];
  const float* proj = (const float*)d_in[9];

  char* w = (char*)d_ws;
  size_t off=0;
  auto alloc=[&](size_t bytes)->char*{ char* p=w+off; off=(off+bytes+255)&~(size_t)255; return p; };
  u16*  qB   = (u16*)alloc(8192ull*512*2);
  u16*  kBf  = (u16*)alloc(8192ull*512*2);
  u16*  vTA  = (u16*)alloc(32ull*80*2048*2);
  u16*  WqT  = (u16*)alloc(512ull*512*2);
  u16*  WkT  = (u16*)alloc(512ull*512*2);
  u16*  WvT  = (u16*)alloc(512ull*512*2);
  u16*  WoT  = (u16*)alloc(512ull*512*2);
  u16*  projS= (u16*)alloc(512ull*64*2);
  u16*  ctxT = (u16*)alloc(32ull*64*512*2);
  float* kcs = (float*)alloc(32ull*512*4);
  u32*  kmx  = (u32*)alloc(256);
  float* ctxs= (float*)alloc(32ull*64*4);
  float* kcss= (float*)alloc(32ull*4);
  float* vsm = (float*)alloc(32ull*64*4);
  char* vx   = alloc(2ull*8192*512*2);          // vB(8MB) + xb(8MB); later reused as ctxP (f32)
  u16*  vB   = (u16*)vx;
  u16*  xb   = (u16*)(vx + 8192ull*512*2);
  size_t fixed = off;
  size_t ctxP8 = 8ull*32*512*80*4;              // f32 partials, NHP=8
  size_t kpT8  = 32ull*512*2048*2;
  size_t need8 = fixed + (ctxP8>16777216 ? ctxP8-16777216 : 0) + kpT8 + (1ull<<20);
  int NHP = (ws_size >= need8 + (4ull<<20)) ? 8 : 4;
  int NL  = NHP*4;
  size_t ctxPsz = 8ull*(size_t)NL*512*80*4;     // f32
  if (ctxPsz > 16777216) alloc(ctxPsz - 16777216);
  float* ctxP = (float*)vx;
  u16* kpT  = (u16*)alloc((size_t)NL*512*2048*2);
  u16* outc = kBf;

  dim3 TB(256);
  k_setup<<<dim3(1280),TB,0,stream>>>(kmx,projS,vTA,ctxs,kcss,proj,x,xb, Wq,Wk,Wv,Wo, WqT,WkT,WvT,WoT);
  k_gemm2<false><<<dim3(64,8,3),TB,0,stream>>>(xb, WqT,WkT,WvT, bq,bk,bv, qB,kBf,vB);
  k_prep<<<dim3(4128),TB,0,stream>>>(vB, vTA, vsm);
  for (int pass=0; pass<8/NHP; ++pass){
    int hbase = pass*NHP;
    k_feat <<<dim3(512,NHP),TB,0,stream>>>(kBf, projS, kpT, kmx, hbase, NHP);
    k_ctxg <<<dim3(NL*32),TB,0,stream>>>(kpT, vTA, ctxP, hbase, NHP);
    k_combK<<<dim3(NL,4),TB,0,stream>>>(ctxP, ctxT, kcs, ctxs, kcss, hbase, NHP);
  }
  k_qpout2<<<dim3(8,16,4),TB,0,stream>>>(qB, projS, kcs, ctxT, ctxs, kcss, vsm, kmx, outc);
  k_gemm2<true><<<dim3(64,8,1),TB,0,stream>>>(outc, WoT,WoT,WoT, bo,bo,bo,
                                              d_out,d_out,d_out);
}

// Round 14
// 155.802 us; speedup vs baseline: 1.0404x; 1.0404x over previous
//
#include <hip/hip_runtime.h>

typedef unsigned short u16;
typedef unsigned int   u32;
typedef __attribute__((ext_vector_type(8))) short bf16x8;
typedef __attribute__((ext_vector_type(4))) short s16x4;
typedef __attribute__((ext_vector_type(4))) float f32x4;

#define MFMA16(a,b,c) __builtin_amdgcn_mfma_f32_16x16x32_bf16((a),(b),(c),0,0,0)

__device__ __forceinline__ float bf2f(u16 u){ return __uint_as_float(((u32)u)<<16); }
__device__ __forceinline__ u16 f2bf(float f){
  u32 u = __float_as_uint(f);
  return (u16)((u + 0x7fffu + ((u>>16)&1u)) >> 16);
}
__device__ __forceinline__ u32 encf(float f){ u32 u=__float_as_uint(f); return (u&0x80000000u)? ~u : (u|0x80000000u); }
__device__ __forceinline__ float decf(u32 u){ return (u&0x80000000u)? __uint_as_float(u&0x7fffffffu) : __uint_as_float(~u); }

__device__ __forceinline__ void async_lds16(u16* lds, const u16* g){
  __builtin_amdgcn_global_load_lds((const __attribute__((address_space(1))) void*)g,
                                   (__attribute__((address_space(3))) void*)lds,
                                   16, 0, 0);
}

// stage ROWS x 64 bf16 from global into LDS padded to 72/row
template<int ROWS>
__device__ __forceinline__ void stage64(u16* dst, const u16* src, int srcStride, int tid){
  #pragma unroll
  for (int u=tid; u<ROWS*8; u+=256){
    int r=u>>3, c=(u&7)<<3;
    *(int4*)&dst[r*72+c] = *(const int4*)&src[(size_t)r*srcStride + c];
  }
}

// ---------------- setup: W transposes (0..1023) + init/cast (1024..1279) ----------------
__global__ __launch_bounds__(256) void k_setup(u32* kmaxEnc, u16* projS,
    const float* __restrict__ proj, const float* __restrict__ x, u16* __restrict__ xb,
    const float* s0, const float* s1, const float* s2, const float* s3,
    u16* d0, u16* d1, u16* d2, u16* d3)
{
  int bid=blockIdx.x, tid=threadIdx.x;
  if (bid < 1024){
    int z = bid>>8, t = bid&255;
    const float* src = z==0?s0:(z==1?s1:(z==2?s2:s3));
    u16* dst         = z==0?d0:(z==1?d1:(z==2?d2:d3));
    __shared__ u16 tl[32][34];
    int c0=(t&15)*32, r0=(t>>4)*32;
    for (int u=tid; u<1024; u+=256){ int r=u>>5, c=u&31; tl[r][c]=f2bf(src[(size_t)(r0+r)*512 + c0+c]); }
    __syncthreads();
    for (int u=tid; u<1024; u+=256){ int c=u>>5, r=u&31; dst[(size_t)(c0+c)*512 + r0+r]=tl[r][c]; }
  } else {
    int i = (bid-1024)*256 + tid;
    int st = 256*256;
    for (int j=i; j<32; j+=st) kmaxEnc[j]=0u;
    const float dn = 0.35355339059327373f;
    for (int j=i; j<512*64; j+=st) projS[j] = f2bf(dn*proj[j]);
    for (int j=i; j<524288; j+=st){
      float4 a = *(const float4*)&x[(size_t)j*8];
      float4 b = *(const float4*)&x[(size_t)j*8+4];
      u16 tmp[8] = {f2bf(a.x),f2bf(a.y),f2bf(a.z),f2bf(a.w),
                    f2bf(b.x),f2bf(b.y),f2bf(b.z),f2bf(b.w)};
      *(int4*)&xb[(size_t)j*8] = *(const int4*)tmp;
    }
  }
}

// ---------------- prep: trv (0..4095) + vsum (4096..4127) + kdiag (4128..4383) ----------------
__global__ __launch_bounds__(256) void k_prep(const u16* __restrict__ vB, u16* __restrict__ vT,
    float* __restrict__ vsum, const u16* __restrict__ kB, float* __restrict__ diagK)
{
  int bid=blockIdx.x, tid=threadIdx.x;
  if (bid < 4096){
    int xx=bid&1, y=(bid>>1)&63, bh=bid>>7;
    int b=bh>>3, h=bh&7;
    int dd0=xx*32, n0=y*32;
    __shared__ u16 t[32][34];
    const u16* s = vB + (size_t)(b*2048)*512 + h*64;
    for (int u=tid; u<1024; u+=256){ int r=u>>5, c=u&31; t[r][c]=s[(size_t)(n0+r)*512 + dd0+c]; }
    __syncthreads();
    u16* d = vT + (size_t)bh*64*2048;
    for (int u=tid; u<1024; u+=256){ int c=u>>5, r=u&31; d[(size_t)(dd0+c)*2048 + n0+r]=t[r][c]; }
  } else if (bid < 4128){
    int bh=bid-4096; int b=bh>>3, h=bh&7;
    int d=tid&63, part=tid>>6;
    const u16* src = vB + (size_t)(b*2048 + part*512)*512 + h*64 + d;
    float s=0.f;
    for (int n=0;n<512;++n) s += bf2f(src[(size_t)n*512]);
    __shared__ float red[256];
    red[tid]=s; __syncthreads();
    if (part==0) vsum[bh*64+d]=red[d]+red[64+d]+red[128+d]+red[192+d];
  } else {
    int idx=bid-4128;
    int bh=idx&31, seg=idx>>5;
    int b=bh>>3, h=bh&7;
    int part=tid&7;
    const u16* base = kB + (size_t)(b*2048 + seg*256)*512 + h*64 + part*8;
    for (int n0=0; n0<256; n0+=32){
      int n = n0 + (tid>>3);
      bf16x8 v = *(const bf16x8*)&base[(size_t)n*512];
      float sq=0.f;
      #pragma unroll
      for (int j=0;j<8;++j){ float f=bf2f((u16)v[j]); sq+=f*f; }
      sq += __shfl_xor(sq,1,64); sq += __shfl_xor(sq,2,64); sq += __shfl_xor(sq,4,64);
      if (part==0) diagK[(size_t)bh*2048 + seg*256 + n] = 0.0625f*sq;
    }
  }
}

// ---------------- GEMM m97-style: O[8192x512] = A(bf16) @ BT^T + bias ----------------
template<bool OF32>
__global__ __launch_bounds__(256) void k_gemm2(const u16* __restrict__ A,
    const u16* BT0, const u16* BT1, const u16* BT2,
    const float* b0, const float* b1, const float* b2,
    void* O0, void* O1, void* O2)
{
  int z = blockIdx.z;
  const u16* BT    = z==0?BT0:(z==1?BT1:BT2);
  const float* bias= z==0?b0 :(z==1?b1 :b2 );
  void* Ov         = z==0?O0 :(z==1?O1 :O2 );
  int bm = blockIdx.x*128, bn = blockIdx.y*64;
  __shared__ u16 sA[128*64];
  __shared__ u16 sB[64*64];
  int tid=threadIdx.x, w=tid>>6, lane=tid&63;
  int lr = lane>>3, lc = (lane&7)*8;
  f32x4 acc[8] = {};
  for (int kk=0; kk<512; kk+=64){
    __syncthreads();
    #pragma unroll
    for (int i=0;i<4;++i){
      int idx = w*4+i;
      async_lds16(&sA[idx*512], A + (size_t)(bm + idx*8 + lr)*512 + kk + lc);
    }
    #pragma unroll
    for (int i=0;i<2;++i){
      int idx = w*2+i;
      async_lds16(&sB[idx*512], BT + (size_t)(bn + idx*8 + lr)*512 + kk + lc);
    }
    __syncthreads();
    int fr = lane&15, kb=(lane>>4)*8;
    #pragma unroll
    for (int rt=0; rt<2; ++rt){
      int ar = (w*2+rt)*16 + fr;
      #pragma unroll
      for (int ct=0; ct<4; ++ct){
        int br = ct*16 + fr;
        #pragma unroll
        for (int kc=0; kc<2; ++kc){
          bf16x8 av = *(const bf16x8*)&sA[ar*64 + kc*32 + kb];
          bf16x8 bv = *(const bf16x8*)&sB[br*64 + kc*32 + kb];
          acc[rt*4+ct] = MFMA16(av,bv,acc[rt*4+ct]);
        }
      }
    }
  }
  int colg = lane&15, rowg=(lane>>4)*4;
  #pragma unroll
  for (int rt=0; rt<2; ++rt){
    #pragma unroll
    for (int ct=0; ct<4; ++ct){
      int col = bn + ct*16 + colg;
      float bv = bias[col];
      #pragma unroll
      for (int j=0;j<4;++j){
        int row = bm + (w*2+rt)*16 + rowg + j;
        if constexpr (OF32) ((float*)Ov)[(size_t)row*512 + col] = acc[rt*4+ct][j] + bv;
        else                ((u16*) Ov)[(size_t)row*512 + col] = f2bf(acc[rt*4+ct][j] + bv);
      }
    }
  }
}

// ---------------- k features (exp-only) + half-n ctx partial + S (in-reg) + mk ----------------
__global__ __launch_bounds__(256) void k_kpctx3(const u16* __restrict__ kB, const u16* __restrict__ projS,
    const u16* __restrict__ vT, const float* __restrict__ diagK,
    float* __restrict__ ctxPT, float* __restrict__ kcsP, u32* __restrict__ kmaxEnc)
{
  int h=blockIdx.x, y=blockIdx.y, b=blockIdx.z;
  int mblk = y&7, s = y>>3;
  int bh=b*8+h;
  int m0 = mblk*64;
  __shared__ __align__(16) u16 sK[128*72];
  __shared__ __align__(16) u16 sV[64*136];
  __shared__ __align__(16) u16 sP[64*72];
  __shared__ __align__(16) u16 sT[64*136];
  __shared__ float sDg[128];
  __shared__ float red[4];
  __shared__ float sRed[4][64];
  int tid=threadIdx.x, w=tid>>6, lane=tid&63;
  int fr=lane&15, kbg=lane>>4, kb=kbg*8, rowg=kbg*4;
  stage64<64>(sP, projS + m0*64, 64, tid);
  f32x4 accc[4]={};
  float sSm[4]={0.f,0.f,0.f,0.f};
  float lm=-3.0e38f;
  const u16* gK = kB + (size_t)(b*2048 + s*1024)*512 + h*64;
  const u16* gV = vT + (size_t)bh*64*2048 + s*1024;
  const float* gD = diagK + (size_t)bh*2048 + s*1024;
  int4 pK[4], pV[4]; float4 pD={0.f,0.f,0.f,0.f};
  #pragma unroll
  for (int i=0;i<4;++i){ int u=tid+i*256; int r=u>>3,c=(u&7)<<3; pK[i]=*(const int4*)&gK[(size_t)r*512 + c]; }
  #pragma unroll
  for (int i=0;i<4;++i){ int u=tid+i*256; int r=u>>4,c=(u&15)<<3; pV[i]=*(const int4*)&gV[(size_t)r*2048 + c]; }
  if (tid<32) pD = *(const float4*)&gD[tid*4];
  for (int nc=0; nc<8; ++nc){
    #pragma unroll
    for (int i=0;i<4;++i){ int u=tid+i*256; int r=u>>3,c=(u&7)<<3; *(int4*)&sK[r*72+c]=pK[i]; }
    #pragma unroll
    for (int i=0;i<4;++i){ int u=tid+i*256; int r=u>>4,c=(u&15)<<3; *(int4*)&sV[r*136+c]=pV[i]; }
    if (tid<32) *(float4*)&sDg[tid*4] = pD;
    __syncthreads();
    if (nc<7){
      #pragma unroll
      for (int i=0;i<4;++i){ int u=tid+i*256; int r=u>>3,c=(u&7)<<3; pK[i]=*(const int4*)&gK[(size_t)((nc+1)*128+r)*512 + c]; }
      #pragma unroll
      for (int i=0;i<4;++i){ int u=tid+i*256; int r=u>>4,c=(u&15)<<3; pV[i]=*(const int4*)&gV[(size_t)r*2048 + (nc+1)*128 + c]; }
      if (tid<32) pD = *(const float4*)&gD[(nc+1)*128 + tid*4];
    }
    f32x4 facc[2][4];
    __builtin_amdgcn_s_setprio(1);
    #pragma unroll
    for (int rt=0;rt<2;++rt){
      int ar=(w*2+rt)*16+fr;
      #pragma unroll
      for (int mt=0;mt<4;++mt){
        f32x4 a={0.f,0.f,0.f,0.f};
        a=MFMA16(*(const bf16x8*)&sK[ar*72+kb],    *(const bf16x8*)&sP[(mt*16+fr)*72+kb],    a);
        a=MFMA16(*(const bf16x8*)&sK[ar*72+32+kb], *(const bf16x8*)&sP[(mt*16+fr)*72+32+kb], a);
        facc[rt][mt]=a;
        lm=fmaxf(lm, fmaxf(fmaxf(a[0],a[1]),fmaxf(a[2],a[3])));
      }
    }
    __builtin_amdgcn_s_setprio(0);
    #pragma unroll
    for (int rt=0;rt<2;++rt){
      int nl=(w*2+rt)*16+rowg;
      #pragma unroll
      for (int mt=0;mt<4;++mt){
        int ml=mt*16+fr;
        s16x4 pk;
        #pragma unroll
        for (int j=0;j<4;++j){
          float vk = __expf(facc[rt][mt][j]-sDg[nl+j]);
          u16 us = f2bf(vk);
          pk[j]=(short)us;
          sSm[mt] += bf2f(us);
        }
        *(s16x4*)&sT[ml*136+nl]=pk;
      }
    }
    __syncthreads();
    int am=w*16+fr;
    __builtin_amdgcn_s_setprio(1);
    #pragma unroll
    for (int ct=0;ct<4;++ct){
      #pragma unroll
      for (int ks=0;ks<4;++ks){
        accc[ct]=MFMA16(*(const bf16x8*)&sT[am*136+ks*32+kb],
                        *(const bf16x8*)&sV[(ct*16+fr)*136+ks*32+kb], accc[ct]);
      }
    }
    __builtin_amdgcn_s_setprio(0);
    __syncthreads();
  }
  #pragma unroll
  for (int mt=0;mt<4;++mt){
    float t=sSm[mt];
    t += __shfl_xor(t,16,64); t += __shfl_xor(t,32,64);
    if (kbg==0) sRed[w][mt*16+fr]=t;
  }
  #pragma unroll
  for (int m2=1;m2<64;m2<<=1) lm=fmaxf(lm,__shfl_xor(lm,m2,64));
  if (lane==0) red[w]=lm;
  float* sTf = (float*)sT;
  int mloc = w*16+rowg;
  #pragma unroll
  for (int ct=0;ct<4;++ct){
    #pragma unroll
    for (int j=0;j<4;++j) sTf[(ct*16+fr)*68 + mloc + j] = accc[ct][j];
  }
  __syncthreads();
  if (tid==0) atomicMax(&kmaxEnc[bh], encf(fmaxf(fmaxf(red[0],red[1]),fmaxf(red[2],red[3]))));
  if (tid<64) kcsP[(size_t)(s*32+bh)*512 + m0 + tid] =
      sRed[0][tid]+sRed[1][tid]+sRed[2][tid]+sRed[3][tid];
  for (int u=tid; u<1024; u+=256){
    int r=u>>4, c=(u&15)*4;
    *(float4*)&ctxPT[((size_t)(s*32+bh)*64 + r)*512 + m0 + c] = *(const float4*)&sTf[r*68+c];
  }
}

// ---------------- combine split-n partials -> ctxT bf16 + kcs, fused ctxsum/kcssum ----------------
__global__ __launch_bounds__(256) void k_comb2(const float* __restrict__ ctxPT, u16* __restrict__ ctxT,
    const float* __restrict__ kcsP, float* __restrict__ kcs,
    float* __restrict__ ctxsum, float* __restrict__ kcssum)
{
  int bh=blockIdx.x, dblk=blockIdx.y;
  int tid=threadIdx.x;
  int d0=dblk*8;
  __shared__ float sDsum[8];
  __shared__ float sKsum[256];
  if (tid<8) sDsum[tid]=0.f;
  __syncthreads();
  const float* p0 = ctxPT + ((size_t)bh*64 + d0)*512;
  const float* p1 = ctxPT + ((size_t)(32+bh)*64 + d0)*512;
  u16* o = ctxT + ((size_t)bh*64 + d0)*512;
  for (int u=tid; u<1024; u+=256){
    int r=u>>7, c=(u&127)*4;
    float4 a=*(const float4*)&p0[(size_t)r*512+c];
    float4 bq=*(const float4*)&p1[(size_t)r*512+c];
    float vx=a.x+bq.x, vy=a.y+bq.y, vz=a.z+bq.z, vw=a.w+bq.w;
    u16 t[4]={f2bf(vx),f2bf(vy),f2bf(vz),f2bf(vw)};
    *(int2*)&o[(size_t)r*512+c] = *(const int2*)t;
    atomicAdd(&sDsum[r], bf2f(t[0])+bf2f(t[1])+bf2f(t[2])+bf2f(t[3]));
  }
  float tpart=0.f;
  if (dblk==0){
    for (int u=tid; u<512; u+=256){
      float t = kcsP[(size_t)bh*512+u] + kcsP[(size_t)(32+bh)*512+u];
      kcs[(size_t)bh*512+u]=t;
      tpart += t;
    }
  }
  sKsum[tid]=tpart;
  __syncthreads();
  if (tid<8) ctxsum[bh*64 + d0 + tid] = sDsum[tid];
  if (dblk==0 && tid<64){
    float a=sKsum[tid]+sKsum[tid+64]+sKsum[tid+128]+sKsum[tid+192];
    #pragma unroll
    for (int m2=1;m2<64;m2<<=1) a += __shfl_xor(a,m2,64);
    if (tid==0) kcssum[bh]=a;
  }
}

// ---------------- q features + PV + eps epilogue: PAIRED chunks (8 barriers, clustered MFMA) ----------------
__global__ __launch_bounds__(256) void k_qpout5(const u16* __restrict__ qB, const u16* __restrict__ projS,
    const float* __restrict__ kcs, const u16* __restrict__ ctxT,
    const float* __restrict__ ctxsum, const float* __restrict__ kcssum,
    const float* __restrict__ vsum, const u32* __restrict__ kmaxEnc,
    u16* __restrict__ outc)
{
  int h=blockIdx.x, chunk=blockIdx.y, b=blockIdx.z;
  int bh=b*8+h;
  int t0 = b*2048 + chunk*128;
  __shared__ u16 sP[2][64*64];
  __shared__ u16 sCt[2][64*64];
  __shared__ u16 qpL[128*72];
  __shared__ float sK[512];
  __shared__ float diag[128];
  int tid=threadIdx.x, w=tid>>6, lane=tid&63;
  int fr=lane&15, kb=(lane>>4)*8, rowg=(lane>>4)*4;
  int lr=lane>>3, lc=(lane&7)*8;
  bf16x8 qf[2][2];
  #pragma unroll
  for (int rt=0;rt<2;++rt)
    #pragma unroll
    for (int kc=0;kc<2;++kc)
      qf[rt][kc] = *(const bf16x8*)&qB[(size_t)(t0 + w*32 + rt*16 + fr)*512 + h*64 + kc*32 + kb];
  #pragma unroll
  for (int rt=0;rt<2;++rt){
    float s=0.f;
    #pragma unroll
    for (int kc=0;kc<2;++kc)
      #pragma unroll
      for (int j=0;j<8;++j){ float f=bf2f((u16)qf[rt][kc][j]); s+=f*f; }
    s += __shfl_xor(s,16,64); s += __shfl_xor(s,32,64);
    if (lane<16) diag[w*32 + rt*16 + fr] = 0.0625f*s;
  }
  for (int u=tid; u<512; u+=256) sK[u] = kcs[(size_t)bh*512 + u];
  const u16* gc = ctxT + (size_t)bh*64*512;
  f32x4 acc2[2][4]={};
  float mx[2][4], dp[2][4], rs[2][4];
  #pragma unroll
  for (int rt=0;rt<2;++rt)
    #pragma unroll
    for (int j=0;j<4;++j){ mx[rt][j]=-3.0e38f; dp[rt][j]=0.f; rs[rt][j]=0.f; }
  __syncthreads();   // diag + sK published
  for (int pr=0; pr<4; ++pr){
    int mc0 = pr*2;
    // stage BOTH chunks of the pair (8 asyncs/wave)
    #pragma unroll
    for (int hf=0; hf<2; ++hf){
      const u16* gp = projS + (mc0+hf)*64*64;
      #pragma unroll
      for (int i=0;i<2;++i){
        int idx = w*2+i;
        async_lds16(&sP[hf][idx*512], gp + idx*512 + lane*8);
        async_lds16(&sCt[hf][idx*512], gc + (size_t)(idx*8+lr)*512 + (mc0+hf)*64 + lc);
      }
    }
    __syncthreads();   // drains vmcnt, publishes pair tiles
    // clustered feature MFMA: both halves (16 MFMA)
    f32x4 facc[2][2][4];
    __builtin_amdgcn_s_setprio(1);
    #pragma unroll
    for (int hf=0; hf<2; ++hf){
      #pragma unroll
      for (int rt=0;rt<2;++rt){
        #pragma unroll
        for (int mt=0;mt<4;++mt){
          f32x4 a={0.f,0.f,0.f,0.f};
          #pragma unroll
          for (int kc=0;kc<2;++kc){
            bf16x8 bv = *(const bf16x8*)&sP[hf][(mt*16+fr)*64 + kc*32 + kb];
            a = MFMA16(qf[rt][kc], bv, a);
          }
          facc[hf][rt][mt]=a;
        }
      }
    }
    __builtin_amdgcn_s_setprio(0);
    // per half: exp -> qpL (wave-private rows; intra-wave DS ordering), then PV
    #pragma unroll
    for (int hf=0; hf<2; ++hf){
      #pragma unroll
      for (int rt=0;rt<2;++rt){
        #pragma unroll
        for (int mt=0;mt<4;++mt){
          float skv = sK[(mc0+hf)*64 + mt*16 + fr];
          #pragma unroll
          for (int j=0;j<4;++j){
            int rl = w*32 + rt*16 + rowg + j;
            mx[rt][j] = fmaxf(mx[rt][j], facc[hf][rt][mt][j]);
            float vq = __expf(facc[hf][rt][mt][j] - diag[rl]);
            u16 us = f2bf(vq);
            qpL[rl*72 + mt*16 + fr] = us;
            float uf = bf2f(us);
            dp[rt][j] += uf*skv;
            rs[rt][j] += uf;
          }
        }
      }
      __builtin_amdgcn_s_setprio(1);
      #pragma unroll
      for (int rt=0;rt<2;++rt){
        #pragma unroll
        for (int ct=0;ct<4;++ct){
          #pragma unroll
          for (int kc=0;kc<2;++kc){
            bf16x8 av = *(const bf16x8*)&qpL[(w*32+rt*16+fr)*72 + kc*32 + kb];
            bf16x8 bv = *(const bf16x8*)&sCt[hf][(ct*16+fr)*64 + kc*32 + kb];
            acc2[rt][ct] = MFMA16(av,bv,acc2[rt][ct]);
          }
        }
      }
      __builtin_amdgcn_s_setprio(0);
    }
    __syncthreads();   // pair tiles free for next pair
  }
  #pragma unroll
  for (int rt=0;rt<2;++rt){
    #pragma unroll
    for (int j=0;j<4;++j){
      #pragma unroll
      for (int s=1;s<16;s<<=1){
        dp[rt][j] += __shfl_xor(dp[rt][j],s,64);
        rs[rt][j] += __shfl_xor(rs[rt][j],s,64);
        mx[rt][j]  = fmaxf(mx[rt][j], __shfl_xor(mx[rt][j],s,64));
      }
    }
  }
  float mk  = decf(kmaxEnc[bh]);
  float emk = __expf(mk);
  float Ssum = kcssum[bh];
  const float eps=1e-4f;
  float emq[2][4];
  #pragma unroll
  for (int rt=0;rt<2;++rt)
    #pragma unroll
    for (int j=0;j<4;++j) emq[rt][j]=__expf(mx[rt][j]);
  #pragma unroll
  for (int rt=0;rt<2;++rt){
    #pragma unroll
    for (int ct=0;ct<4;++ct){
      int d = ct*16 + fr;
      float cs = ctxsum[bh*64 + d];
      float vs = vsum[bh*64 + d];
      #pragma unroll
      for (int j=0;j<4;++j){
        float eq = emq[rt][j];
        float numer = acc2[rt][ct][j] + eps*(emk*vs*rs[rt][j] + eq*cs + eps*eq*emk*512.0f*vs);
        float den   = dp[rt][j]       + eps*(emk*2048.0f*rs[rt][j] + eq*Ssum + eps*eq*emk*512.0f*2048.0f);
        int row = t0 + w*32 + rt*16 + rowg + j;
        outc[(size_t)row*512 + h*64 + d] = f2bf(numer/den);
      }
    }
  }
}

extern "C" void kernel_launch(void* const* d_in, const int* in_sizes, int n_in,
                              void* d_out, int out_size, void* d_ws, size_t ws_size,
                              hipStream_t stream)
{
  (void)in_sizes; (void)n_in; (void)out_size; (void)ws_size;
  const float* x    = (const float*)d_in[0];
  const float* Wq   = (const float*)d_in[1];
  const float* bq   = (const float*)d_in[2];
  const float* Wk   = (const float*)d_in[3];
  const float* bk   = (const float*)d_in[4];
  const float* Wv   = (const float*)d_in[5];
  const float* bv   = (const float*)d_in[6];
  const float* Wo   = (const float*)d_in[7];
  const float* bo   = (const float*)d_in[8];
  const float* proj = (const float*)d_in[9];

  char* w = (char*)d_ws;
  size_t off=0;
  auto alloc=[&](size_t bytes)->char*{ char* p=w+off; off=(off+bytes+255)&~(size_t)255; return p; };
  u16*  xb   = (u16*)alloc(8192ull*512*2);
  u16*  qB   = (u16*)alloc(8192ull*512*2);
  u16*  kBf  = (u16*)alloc(8192ull*512*2);
  u16*  vB   = (u16*)alloc(8192ull*512*2);
  u16*  vT   = (u16*)alloc(32ull*64*2048*2);
  u16*  WqT  = (u16*)alloc(512ull*512*2);
  u16*  WkT  = (u16*)alloc(512ull*512*2);
  u16*  WvT  = (u16*)alloc(512ull*512*2);
  u16*  WoT  = (u16*)alloc(512ull*512*2);
  u16*  projS= (u16*)alloc(512ull*64*2);
  u16*  ctxT = (u16*)alloc(32ull*64*512*2);
  float* ctxPT=(float*)alloc(2ull*32*64*512*4);
  float* kcs = (float*)alloc(32ull*512*4);
  float* kcsP= (float*)alloc(2ull*32*512*4);
  float* diagK=(float*)alloc(32ull*2048*4);
  u32*  kmx  = (u32*)alloc(256);
  float* ctxs= (float*)alloc(32ull*64*4);
  float* kcss= (float*)alloc(32ull*4);
  float* vsm = (float*)alloc(32ull*64*4);
  u16*  outc = kBf;  // kBf dead after k_kpctx3; reuse

  dim3 TB(256);
  k_setup<<<dim3(1280),TB,0,stream>>>(kmx,projS,proj,x,xb, Wq,Wk,Wv,Wo, WqT,WkT,WvT,WoT);
  k_gemm2<false><<<dim3(64,8,3),TB,0,stream>>>(xb, WqT,WkT,WvT, bq,bk,bv, qB,kBf,vB);
  k_prep<<<dim3(4384),TB,0,stream>>>(vB, vT, vsm, kBf, diagK);
  k_kpctx3<<<dim3(8,16,4),TB,0,stream>>>(kBf, projS, vT, diagK, ctxPT, kcsP, kmx);
  k_comb2<<<dim3(32,8),TB,0,stream>>>(ctxPT, ctxT, kcsP, kcs, ctxs, kcss);
  k_qpout5<<<dim3(8,16,4),TB,0,stream>>>(qB, projS, kcs, ctxT, ctxs, kcss, vsm, kmx, outc);
  k_gemm2<true><<<dim3(64,8,1),TB,0,stream>>>(outc, WoT,WoT,WoT, bo,bo,bo,
                                              d_out,d_out,d_out);
}

// Round 15
// 146.821 us; speedup vs baseline: 1.1041x; 1.0612x over previous
//
#include <hip/hip_runtime.h>

typedef unsigned short u16;
typedef unsigned int   u32;
typedef __attribute__((ext_vector_type(8))) short bf16x8;
typedef __attribute__((ext_vector_type(4))) short s16x4;
typedef __attribute__((ext_vector_type(4))) float f32x4;

#define MFMA16(a,b,c) __builtin_amdgcn_mfma_f32_16x16x32_bf16((a),(b),(c),0,0,0)

__device__ __forceinline__ float bf2f(u16 u){ return __uint_as_float(((u32)u)<<16); }
__device__ __forceinline__ u16 f2bf(float f){
  u32 u = __float_as_uint(f);
  return (u16)((u + 0x7fffu + ((u>>16)&1u)) >> 16);
}
__device__ __forceinline__ u32 encf(float f){ u32 u=__float_as_uint(f); return (u&0x80000000u)? ~u : (u|0x80000000u); }
__device__ __forceinline__ float decf(u32 u){ return (u&0x80000000u)? __uint_as_float(u&0x7fffffffu) : __uint_as_float(~u); }

__device__ __forceinline__ void async_lds16(u16* lds, const u16* g){
  __builtin_amdgcn_global_load_lds((const __attribute__((address_space(1))) void*)g,
                                   (__attribute__((address_space(3))) void*)lds,
                                   16, 0, 0);
}

// stage ROWS x 64 bf16 from global into LDS padded to 72/row
template<int ROWS>
__device__ __forceinline__ void stage64(u16* dst, const u16* src, int srcStride, int tid){
  #pragma unroll
  for (int u=tid; u<ROWS*8; u+=256){
    int r=u>>3, c=(u&7)<<3;
    *(int4*)&dst[r*72+c] = *(const int4*)&src[(size_t)r*srcStride + c];
  }
}

// ---------------- setup: weight transposes (blocks 0..1023) + init/cast (blocks 1024..1279) ----------------
__global__ __launch_bounds__(256) void k_setup(u32* kmaxEnc, u16* projS,
    const float* __restrict__ proj, const float* __restrict__ x, u16* __restrict__ xb,
    const float* s0, const float* s1, const float* s2, const float* s3,
    u16* d0, u16* d1, u16* d2, u16* d3)
{
  int bid=blockIdx.x, tid=threadIdx.x;
  if (bid < 1024){
    int z = bid>>8, t = bid&255;
    const float* src = z==0?s0:(z==1?s1:(z==2?s2:s3));
    u16* dst         = z==0?d0:(z==1?d1:(z==2?d2:d3));
    __shared__ u16 tl[32][34];
    int c0=(t&15)*32, r0=(t>>4)*32;
    for (int u=tid; u<1024; u+=256){ int r=u>>5, c=u&31; tl[r][c]=f2bf(src[(size_t)(r0+r)*512 + c0+c]); }
    __syncthreads();
    for (int u=tid; u<1024; u+=256){ int c=u>>5, r=u&31; dst[(size_t)(c0+c)*512 + r0+r]=tl[r][c]; }
  } else {
    int i = (bid-1024)*256 + tid;
    int st = 256*256;
    for (int j=i; j<32; j+=st) kmaxEnc[j]=0u;
    const float dn = 0.35355339059327373f; // 64^-0.25
    for (int j=i; j<512*64; j+=st) projS[j] = f2bf(dn*proj[j]);
    for (int j=i; j<524288; j+=st){
      float4 a = *(const float4*)&x[(size_t)j*8];
      float4 b = *(const float4*)&x[(size_t)j*8+4];
      u16 tmp[8] = {f2bf(a.x),f2bf(a.y),f2bf(a.z),f2bf(a.w),
                    f2bf(b.x),f2bf(b.y),f2bf(b.z),f2bf(b.w)};
      *(int4*)&xb[(size_t)j*8] = *(const int4*)tmp;
    }
  }
}

// ---------------- prep: trv (0..4095) + vsum (4096..4127) + kdiag (4128..4383) ----------------
__global__ __launch_bounds__(256) void k_prep(const u16* __restrict__ vB, u16* __restrict__ vT,
    float* __restrict__ vsum, const u16* __restrict__ kB, float* __restrict__ diagK)
{
  int bid=blockIdx.x, tid=threadIdx.x;
  if (bid < 4096){
    int xx=bid&1, y=(bid>>1)&63, bh=bid>>7;
    int b=bh>>3, h=bh&7;
    int dd0=xx*32, n0=y*32;
    __shared__ u16 t[32][34];
    const u16* s = vB + (size_t)(b*2048)*512 + h*64;
    for (int u=tid; u<1024; u+=256){ int r=u>>5, c=u&31; t[r][c]=s[(size_t)(n0+r)*512 + dd0+c]; }
    __syncthreads();
    u16* d = vT + (size_t)bh*64*2048;
    for (int u=tid; u<1024; u+=256){ int c=u>>5, r=u&31; d[(size_t)(dd0+c)*2048 + n0+r]=t[r][c]; }
  } else if (bid < 4128){
    int bh=bid-4096; int b=bh>>3, h=bh&7;
    int d=tid&63, part=tid>>6;
    const u16* src = vB + (size_t)(b*2048 + part*512)*512 + h*64 + d;
    float s=0.f;
    for (int n=0;n<512;++n) s += bf2f(src[(size_t)n*512]);
    __shared__ float red[256];
    red[tid]=s; __syncthreads();
    if (part==0) vsum[bh*64+d]=red[d]+red[64+d]+red[128+d]+red[192+d];
  } else {
    int idx=bid-4128;
    int bh=idx&31, seg=idx>>5;
    int b=bh>>3, h=bh&7;
    int part=tid&7;
    const u16* base = kB + (size_t)(b*2048 + seg*256)*512 + h*64 + part*8;
    for (int n0=0; n0<256; n0+=32){
      int n = n0 + (tid>>3);
      bf16x8 v = *(const bf16x8*)&base[(size_t)n*512];
      float sq=0.f;
      #pragma unroll
      for (int j=0;j<8;++j){ float f=bf2f((u16)v[j]); sq+=f*f; }
      sq += __shfl_xor(sq,1,64); sq += __shfl_xor(sq,2,64); sq += __shfl_xor(sq,4,64);
      if (part==0) diagK[(size_t)bh*2048 + seg*256 + n] = 0.0625f*sq;
    }
  }
}

// ---------------- GEMM m97-style (round-6 proven): O[8192x512] = A(bf16) @ BT^T + bias ----------------
template<bool OF32>
__global__ __launch_bounds__(256) void k_gemm2(const u16* __restrict__ A,
    const u16* BT0, const u16* BT1, const u16* BT2,
    const float* b0, const float* b1, const float* b2,
    void* O0, void* O1, void* O2)
{
  int z = blockIdx.z;
  const u16* BT    = z==0?BT0:(z==1?BT1:BT2);
  const float* bias= z==0?b0 :(z==1?b1 :b2 );
  void* Ov         = z==0?O0 :(z==1?O1 :O2 );
  int bm = blockIdx.x*128, bn = blockIdx.y*64;
  __shared__ u16 sA[128*64];
  __shared__ u16 sB[64*64];
  int tid=threadIdx.x, w=tid>>6, lane=tid&63;
  int lr = lane>>3, lc = (lane&7)*8;
  f32x4 acc[8] = {};
  for (int kk=0; kk<512; kk+=64){
    __syncthreads();
    #pragma unroll
    for (int i=0;i<4;++i){
      int idx = w*4+i;
      async_lds16(&sA[idx*512], A + (size_t)(bm + idx*8 + lr)*512 + kk + lc);
    }
    #pragma unroll
    for (int i=0;i<2;++i){
      int idx = w*2+i;
      async_lds16(&sB[idx*512], BT + (size_t)(bn + idx*8 + lr)*512 + kk + lc);
    }
    __syncthreads();
    int fr = lane&15, kb=(lane>>4)*8;
    #pragma unroll
    for (int rt=0; rt<2; ++rt){
      int ar = (w*2+rt)*16 + fr;
      #pragma unroll
      for (int ct=0; ct<4; ++ct){
        int br = ct*16 + fr;
        #pragma unroll
        for (int kc=0; kc<2; ++kc){
          bf16x8 av = *(const bf16x8*)&sA[ar*64 + kc*32 + kb];
          bf16x8 bv = *(const bf16x8*)&sB[br*64 + kc*32 + kb];
          acc[rt*4+ct] = MFMA16(av,bv,acc[rt*4+ct]);
        }
      }
    }
  }
  int colg = lane&15, rowg=(lane>>4)*4;
  #pragma unroll
  for (int rt=0; rt<2; ++rt){
    #pragma unroll
    for (int ct=0; ct<4; ++ct){
      int col = bn + ct*16 + colg;
      float bv = bias[col];
      #pragma unroll
      for (int j=0;j<4;++j){
        int row = bm + (w*2+rt)*16 + rowg + j;
        if constexpr (OF32) ((float*)Ov)[(size_t)row*512 + col] = acc[rt*4+ct][j] + bv;
        else                ((u16*) Ov)[(size_t)row*512 + col] = f2bf(acc[rt*4+ct][j] + bv);
      }
    }
  }
}

// ---------------- k features (exp-only) + half-n ctx partial + S (in-reg) + mk ----------------
// round-6 structure; S accumulated in registers during exp (no per-chunk scalar LDS reads).
__global__ __launch_bounds__(256) void k_kpctx3(const u16* __restrict__ kB, const u16* __restrict__ projS,
    const u16* __restrict__ vT, const float* __restrict__ diagK,
    float* __restrict__ ctxPT, float* __restrict__ kcsP, u32* __restrict__ kmaxEnc)
{
  int h=blockIdx.x, y=blockIdx.y, b=blockIdx.z;
  int mblk = y&7, s = y>>3;
  int bh=b*8+h;
  int m0 = mblk*64;
  __shared__ __align__(16) u16 sK[128*72];
  __shared__ __align__(16) u16 sV[64*136];
  __shared__ __align__(16) u16 sP[64*72];
  __shared__ __align__(16) u16 sT[64*136];
  __shared__ float sDg[128];
  __shared__ float red[4];
  __shared__ float sRed[4][64];
  int tid=threadIdx.x, w=tid>>6, lane=tid&63;
  int fr=lane&15, kbg=lane>>4, kb=kbg*8, rowg=kbg*4;
  stage64<64>(sP, projS + m0*64, 64, tid);
  f32x4 accc[4]={};
  float sSm[4]={0.f,0.f,0.f,0.f};   // per-thread S partial for m = mt*16+fr
  float lm=-3.0e38f;
  const u16* gK = kB + (size_t)(b*2048 + s*1024)*512 + h*64;
  const u16* gV = vT + (size_t)bh*64*2048 + s*1024;
  const float* gD = diagK + (size_t)bh*2048 + s*1024;
  int4 pK[4], pV[4]; float4 pD={0.f,0.f,0.f,0.f};
  #pragma unroll
  for (int i=0;i<4;++i){ int u=tid+i*256; int r=u>>3,c=(u&7)<<3; pK[i]=*(const int4*)&gK[(size_t)r*512 + c]; }
  #pragma unroll
  for (int i=0;i<4;++i){ int u=tid+i*256; int r=u>>4,c=(u&15)<<3; pV[i]=*(const int4*)&gV[(size_t)r*2048 + c]; }
  if (tid<32) pD = *(const float4*)&gD[tid*4];
  for (int nc=0; nc<8; ++nc){
    #pragma unroll
    for (int i=0;i<4;++i){ int u=tid+i*256; int r=u>>3,c=(u&7)<<3; *(int4*)&sK[r*72+c]=pK[i]; }
    #pragma unroll
    for (int i=0;i<4;++i){ int u=tid+i*256; int r=u>>4,c=(u&15)<<3; *(int4*)&sV[r*136+c]=pV[i]; }
    if (tid<32) *(float4*)&sDg[tid*4] = pD;
    __syncthreads();
    if (nc<7){
      #pragma unroll
      for (int i=0;i<4;++i){ int u=tid+i*256; int r=u>>3,c=(u&7)<<3; pK[i]=*(const int4*)&gK[(size_t)((nc+1)*128+r)*512 + c]; }
      #pragma unroll
      for (int i=0;i<4;++i){ int u=tid+i*256; int r=u>>4,c=(u&15)<<3; pV[i]=*(const int4*)&gV[(size_t)r*2048 + (nc+1)*128 + c]; }
      if (tid<32) pD = *(const float4*)&gD[(nc+1)*128 + tid*4];
    }
    // feature MFMA: dd[128 n][64 m]
    f32x4 facc[2][4];
    #pragma unroll
    for (int rt=0;rt<2;++rt){
      int ar=(w*2+rt)*16+fr;
      #pragma unroll
      for (int mt=0;mt<4;++mt){
        f32x4 a={0.f,0.f,0.f,0.f};
        a=MFMA16(*(const bf16x8*)&sK[ar*72+kb],    *(const bf16x8*)&sP[(mt*16+fr)*72+kb],    a);
        a=MFMA16(*(const bf16x8*)&sK[ar*72+32+kb], *(const bf16x8*)&sP[(mt*16+fr)*72+32+kb], a);
        facc[rt][mt]=a;
        lm=fmaxf(lm, fmaxf(fmaxf(a[0],a[1]),fmaxf(a[2],a[3])));
      }
    }
    // exp -> sT[m][n], S accumulated in regs
    #pragma unroll
    for (int rt=0;rt<2;++rt){
      int nl=(w*2+rt)*16+rowg;
      #pragma unroll
      for (int mt=0;mt<4;++mt){
        int ml=mt*16+fr;
        s16x4 pk;
        #pragma unroll
        for (int j=0;j<4;++j){
          float vk = __expf(facc[rt][mt][j]-sDg[nl+j]);
          u16 us = f2bf(vk);
          pk[j]=(short)us;
          sSm[mt] += bf2f(us);
        }
        *(s16x4*)&sT[ml*136+nl]=pk;
      }
    }
    __syncthreads();
    // PV MFMA
    int am=w*16+fr;
    #pragma unroll
    for (int ct=0;ct<4;++ct){
      #pragma unroll
      for (int ks=0;ks<4;++ks){
        accc[ct]=MFMA16(*(const bf16x8*)&sT[am*136+ks*32+kb],
                        *(const bf16x8*)&sV[(ct*16+fr)*136+ks*32+kb], accc[ct]);
      }
    }
    __syncthreads();
  }
  // S reduce: across kbg groups (same w, same fr), store per-w partial
  #pragma unroll
  for (int mt=0;mt<4;++mt){
    float t=sSm[mt];
    t += __shfl_xor(t,16,64); t += __shfl_xor(t,32,64);
    if (kbg==0) sRed[w][mt*16+fr]=t;
  }
  // mk partial
  #pragma unroll
  for (int m2=1;m2<64;m2<<=1) lm=fmaxf(lm,__shfl_xor(lm,m2,64));
  if (lane==0) red[w]=lm;
  // ctx partial f32, transposed [d][m] via LDS bounce (reuse sT as float[64][68])
  float* sTf = (float*)sT;
  int mloc = w*16+rowg;
  #pragma unroll
  for (int ct=0;ct<4;++ct){
    #pragma unroll
    for (int j=0;j<4;++j) sTf[(ct*16+fr)*68 + mloc + j] = accc[ct][j];
  }
  __syncthreads();
  if (tid==0) atomicMax(&kmaxEnc[bh], encf(fmaxf(fmaxf(red[0],red[1]),fmaxf(red[2],red[3]))));
  if (tid<64) kcsP[(size_t)(s*32+bh)*512 + m0 + tid] =
      sRed[0][tid]+sRed[1][tid]+sRed[2][tid]+sRed[3][tid];
  for (int u=tid; u<1024; u+=256){
    int r=u>>4, c=(u&15)*4;
    *(float4*)&ctxPT[((size_t)(s*32+bh)*64 + r)*512 + m0 + c] = *(const float4*)&sTf[r*68+c];
  }
}

// ---------------- combine split-n partials -> ctxT bf16 + kcs, fused ctxsum/kcssum ----------------
__global__ __launch_bounds__(256) void k_comb2(const float* __restrict__ ctxPT, u16* __restrict__ ctxT,
    const float* __restrict__ kcsP, float* __restrict__ kcs,
    float* __restrict__ ctxsum, float* __restrict__ kcssum)
{
  int bh=blockIdx.x, dblk=blockIdx.y;
  int tid=threadIdx.x;
  int d0=dblk*8;
  __shared__ float sDsum[8];
  __shared__ float sKsum[256];
  if (tid<8) sDsum[tid]=0.f;
  __syncthreads();
  const float* p0 = ctxPT + ((size_t)bh*64 + d0)*512;
  const float* p1 = ctxPT + ((size_t)(32+bh)*64 + d0)*512;
  u16* o = ctxT + ((size_t)bh*64 + d0)*512;
  for (int u=tid; u<1024; u+=256){
    int r=u>>7, c=(u&127)*4;
    float4 a=*(const float4*)&p0[(size_t)r*512+c];
    float4 bq=*(const float4*)&p1[(size_t)r*512+c];
    float vx=a.x+bq.x, vy=a.y+bq.y, vz=a.z+bq.z, vw=a.w+bq.w;
    u16 t[4]={f2bf(vx),f2bf(vy),f2bf(vz),f2bf(vw)};
    *(int2*)&o[(size_t)r*512+c] = *(const int2*)t;
    // use bf16-rounded values for the sum (matches prior k_sums numerics)
    atomicAdd(&sDsum[r], bf2f(t[0])+bf2f(t[1])+bf2f(t[2])+bf2f(t[3]));
  }
  float tpart=0.f;
  if (dblk==0){
    for (int u=tid; u<512; u+=256){
      float t = kcsP[(size_t)bh*512+u] + kcsP[(size_t)(32+bh)*512+u];
      kcs[(size_t)bh*512+u]=t;
      tpart += t;
    }
  }
  sKsum[tid]=tpart;
  __syncthreads();
  if (tid<8) ctxsum[bh*64 + d0 + tid] = sDsum[tid];
  if (dblk==0 && tid<64){
    float a=sKsum[tid]+sKsum[tid+64]+sKsum[tid+128]+sKsum[tid+192];
    #pragma unroll
    for (int m2=1;m2<64;m2<<=1) a += __shfl_xor(a,m2,64);
    if (tid==0) kcssum[bh]=a;
  }
}

// ---------------- q features (exp-only) + PV + exact eps epilogue (round-6 proven) ----------------
__global__ __launch_bounds__(256) void k_qpout2(const u16* __restrict__ qB, const u16* __restrict__ projS,
    const float* __restrict__ kcs, const u16* __restrict__ ctxT,
    const float* __restrict__ ctxsum, const float* __restrict__ kcssum,
    const float* __restrict__ vsum, const u32* __restrict__ kmaxEnc,
    u16* __restrict__ outc)
{
  int h=blockIdx.x, chunk=blockIdx.y, b=blockIdx.z;
  int bh=b*8+h;
  int t0 = b*2048 + chunk*128;
  __shared__ u16 sP[2][64*64];
  __shared__ u16 sCt[2][64*64];
  __shared__ u16 qpL[128*72];
  __shared__ float sK[512];
  __shared__ float diag[128];
  int tid=threadIdx.x, w=tid>>6, lane=tid&63;
  int fr=lane&15, kb=(lane>>4)*8, rowg=(lane>>4)*4;
  bf16x8 qf[2][2];
  #pragma unroll
  for (int rt=0;rt<2;++rt)
    #pragma unroll
    for (int kc=0;kc<2;++kc)
      qf[rt][kc] = *(const bf16x8*)&qB[(size_t)(t0 + w*32 + rt*16 + fr)*512 + h*64 + kc*32 + kb];
  #pragma unroll
  for (int rt=0;rt<2;++rt){
    float s=0.f;
    #pragma unroll
    for (int kc=0;kc<2;++kc)
      #pragma unroll
      for (int j=0;j<8;++j){ float f=bf2f((u16)qf[rt][kc][j]); s+=f*f; }
    s += __shfl_xor(s,16,64); s += __shfl_xor(s,32,64);
    if (lane<16) diag[w*32 + rt*16 + fr] = 0.0625f*s;
  }
  for (int u=tid; u<512; u+=256) sK[u] = kcs[(size_t)bh*512 + u];
  {
    const u16* gp = projS;
    const u16* gc = ctxT + (size_t)bh*64*512;
    int lr=lane>>3, lc=(lane&7)*8;
    #pragma unroll
    for (int i=0;i<2;++i){
      int idx = w*2+i;
      async_lds16(&sP[0][idx*512], gp + idx*512 + lane*8);
      async_lds16(&sCt[0][idx*512], gc + (size_t)(idx*8+lr)*512 + lc);
    }
  }
  f32x4 acc2[2][4]={};
  float mx[2][4], dp[2][4], rs[2][4];
  #pragma unroll
  for (int rt=0;rt<2;++rt)
    #pragma unroll
    for (int j=0;j<4;++j){ mx[rt][j]=-3.0e38f; dp[rt][j]=0.f; rs[rt][j]=0.f; }
  __syncthreads();
  for (int mc=0; mc<8; ++mc){
    int cur = mc&1;
    if (mc<7){
      int nxt = cur^1;
      const u16* gp = projS + (mc+1)*64*64;
      const u16* gc = ctxT + (size_t)bh*64*512 + (mc+1)*64;
      int lr=lane>>3, lc=(lane&7)*8;
      #pragma unroll
      for (int i=0;i<2;++i){
        int idx = w*2+i;
        async_lds16(&sP[nxt][idx*512], gp + idx*512 + lane*8);
        async_lds16(&sCt[nxt][idx*512], gc + (size_t)(idx*8+lr)*512 + lc);
      }
    }
    f32x4 facc[2][4];
    #pragma unroll
    for (int rt=0;rt<2;++rt){
      #pragma unroll
      for (int mt=0;mt<4;++mt){
        f32x4 a={0.f,0.f,0.f,0.f};
        #pragma unroll
        for (int kc=0;kc<2;++kc){
          bf16x8 bv = *(const bf16x8*)&sP[cur][(mt*16+fr)*64 + kc*32 + kb];
          a = MFMA16(qf[rt][kc], bv, a);
        }
        facc[rt][mt]=a;
      }
    }
    #pragma unroll
    for (int rt=0;rt<2;++rt){
      #pragma unroll
      for (int mt=0;mt<4;++mt){
        #pragma unroll
        for (int j=0;j<4;++j){
          int rl = w*32 + rt*16 + rowg + j;
          mx[rt][j] = fmaxf(mx[rt][j], facc[rt][mt][j]);
          float vq = __expf(facc[rt][mt][j] - diag[rl]);
          u16 us = f2bf(vq);
          qpL[rl*72 + mt*16 + fr] = us;
          float uf = bf2f(us);
          dp[rt][j] += uf*sK[mc*64 + mt*16 + fr];
          rs[rt][j] += uf;
        }
      }
    }
    __syncthreads();
    #pragma unroll
    for (int rt=0;rt<2;++rt){
      #pragma unroll
      for (int ct=0;ct<4;++ct){
        #pragma unroll
        for (int kc=0;kc<2;++kc){
          bf16x8 av = *(const bf16x8*)&qpL[(w*32+rt*16+fr)*72 + kc*32 + kb];
          bf16x8 bv = *(const bf16x8*)&sCt[cur][(ct*16+fr)*64 + kc*32 + kb];
          acc2[rt][ct] = MFMA16(av,bv,acc2[rt][ct]);
        }
      }
    }
    __syncthreads();
  }
  #pragma unroll
  for (int rt=0;rt<2;++rt){
    #pragma unroll
    for (int j=0;j<4;++j){
      #pragma unroll
      for (int s=1;s<16;s<<=1){
        dp[rt][j] += __shfl_xor(dp[rt][j],s,64);
        rs[rt][j] += __shfl_xor(rs[rt][j],s,64);
        mx[rt][j]  = fmaxf(mx[rt][j], __shfl_xor(mx[rt][j],s,64));
      }
    }
  }
  float mk  = decf(kmaxEnc[bh]);
  float emk = __expf(mk);
  float Ssum = kcssum[bh];
  const float eps=1e-4f;
  float emq[2][4];
  #pragma unroll
  for (int rt=0;rt<2;++rt)
    #pragma unroll
    for (int j=0;j<4;++j) emq[rt][j]=__expf(mx[rt][j]);
  #pragma unroll
  for (int rt=0;rt<2;++rt){
    #pragma unroll
    for (int ct=0;ct<4;++ct){
      int d = ct*16 + fr;
      float cs = ctxsum[bh*64 + d];
      float vs = vsum[bh*64 + d];
      #pragma unroll
      for (int j=0;j<4;++j){
        float eq = emq[rt][j];
        float numer = acc2[rt][ct][j] + eps*(emk*vs*rs[rt][j] + eq*cs + eps*eq*emk*512.0f*vs);
        float den   = dp[rt][j]       + eps*(emk*2048.0f*rs[rt][j] + eq*Ssum + eps*eq*emk*512.0f*2048.0f);
        int row = t0 + w*32 + rt*16 + rowg + j;
        outc[(size_t)row*512 + h*64 + d] = f2bf(numer/den);
      }
    }
  }
}

extern "C" void kernel_launch(void* const* d_in, const int* in_sizes, int n_in,
                              void* d_out, int out_size, void* d_ws, size_t ws_size,
                              hipStream_t stream)
{
  (void)in_sizes; (void)n_in; (void)out_size; (void)ws_size;
  const float* x    = (const float*)d_in[0];
  const float* Wq   = (const float*)d_in[1];
  const float* bq   = (const float*)d_in[2];
  const float* Wk   = (const float*)d_in[3];
  const float* bk   = (const float*)d_in[4];
  const float* Wv   = (const float*)d_in[5];
  const float* bv   = (const float*)d_in[6];
  const float* Wo   = (const float*)d_in[7];
  const float* bo   = (const float*)d_in[8];
  const float* proj = (const float*)d_in[9];

  char* w = (char*)d_ws;
  size_t off=0;
  auto alloc=[&](size_t bytes)->char*{ char* p=w+off; off=(off+bytes+255)&~(size_t)255; return p; };
  u16*  xb   = (u16*)alloc(8192ull*512*2);
  u16*  qB   = (u16*)alloc(8192ull*512*2);
  u16*  kBf  = (u16*)alloc(8192ull*512*2);
  u16*  vB   = (u16*)alloc(8192ull*512*2);
  u16*  vT   = (u16*)alloc(32ull*64*2048*2);
  u16*  WqT  = (u16*)alloc(512ull*512*2);
  u16*  WkT  = (u16*)alloc(512ull*512*2);
  u16*  WvT  = (u16*)alloc(512ull*512*2);
  u16*  WoT  = (u16*)alloc(512ull*512*2);
  u16*  projS= (u16*)alloc(512ull*64*2);
  u16*  ctxT = (u16*)alloc(32ull*64*512*2);
  float* ctxPT=(float*)alloc(2ull*32*64*512*4);
  float* kcs = (float*)alloc(32ull*512*4);
  float* kcsP= (float*)alloc(2ull*32*512*4);
  float* diagK=(float*)alloc(32ull*2048*4);
  u32*  kmx  = (u32*)alloc(256);
  float* ctxs= (float*)alloc(32ull*64*4);
  float* kcss= (float*)alloc(32ull*4);
  float* vsm = (float*)alloc(32ull*64*4);
  u16*  outc = kBf;  // kBf dead after k_kpctx3; reuse

  dim3 TB(256);
  k_setup<<<dim3(1280),TB,0,stream>>>(kmx,projS,proj,x,xb, Wq,Wk,Wv,Wo, WqT,WkT,WvT,WoT);
  k_gemm2<false><<<dim3(64,8,3),TB,0,stream>>>(xb, WqT,WkT,WvT, bq,bk,bv, qB,kBf,vB);
  k_prep<<<dim3(4384),TB,0,stream>>>(vB, vT, vsm, kBf, diagK);
  k_kpctx3<<<dim3(8,16,4),TB,0,stream>>>(kBf, projS, vT, diagK, ctxPT, kcsP, kmx);
  k_comb2<<<dim3(32,8),TB,0,stream>>>(ctxPT, ctxT, kcsP, kcs, ctxs, kcss);
  k_qpout2<<<dim3(8,16,4),TB,0,stream>>>(qB, projS, kcs, ctxT, ctxs, kcss, vsm, kmx, outc);
  k_gemm2<true><<<dim3(64,8,1),TB,0,stream>>>(outc, WoT,WoT,WoT, bo,bo,bo,
                                              d_out,d_out,d_out);
}

// Round 16
// 145.009 us; speedup vs baseline: 1.1179x; 1.0125x over previous
//
#include <hip/hip_runtime.h>

typedef unsigned short u16;
typedef unsigned int   u32;
typedef __attribute__((ext_vector_type(8))) short bf16x8;
typedef __attribute__((ext_vector_type(4))) short s16x4;
typedef __attribute__((ext_vector_type(4))) float f32x4;

#define MFMA16(a,b,c) __builtin_amdgcn_mfma_f32_16x16x32_bf16((a),(b),(c),0,0,0)

// soft barriers: raw s_barrier + counted waits
#define SOFT_BAR_LG() do{ asm volatile("s_waitcnt lgkmcnt(0)" ::: "memory"); \
  __builtin_amdgcn_s_barrier(); __builtin_amdgcn_sched_barrier(0); }while(0)
#define SOFT_BAR_VM(N) do{ asm volatile("s_waitcnt vmcnt(" #N ") lgkmcnt(0)" ::: "memory"); \
  __builtin_amdgcn_s_barrier(); __builtin_amdgcn_sched_barrier(0); }while(0)

__device__ __forceinline__ float bf2f(u16 u){ return __uint_as_float(((u32)u)<<16); }
__device__ __forceinline__ u16 f2bf(float f){
  u32 u = __float_as_uint(f);
  return (u16)((u + 0x7fffu + ((u>>16)&1u)) >> 16);
}
__device__ __forceinline__ u32 encf(float f){ u32 u=__float_as_uint(f); return (u&0x80000000u)? ~u : (u|0x80000000u); }
__device__ __forceinline__ float decf(u32 u){ return (u&0x80000000u)? __uint_as_float(u&0x7fffffffu) : __uint_as_float(~u); }

__device__ __forceinline__ void async_lds16(u16* lds, const u16* g){
  __builtin_amdgcn_global_load_lds((const __attribute__((address_space(1))) void*)g,
                                   (__attribute__((address_space(3))) void*)lds,
                                   16, 0, 0);
}

// stage ROWS x 64 bf16 from global into LDS padded to 72/row
template<int ROWS>
__device__ __forceinline__ void stage64(u16* dst, const u16* src, int srcStride, int tid){
  #pragma unroll
  for (int u=tid; u<ROWS*8; u+=256){
    int r=u>>3, c=(u&7)<<3;
    *(int4*)&dst[r*72+c] = *(const int4*)&src[(size_t)r*srcStride + c];
  }
}

// ---------------- setup: weight transposes (blocks 0..1023) + init/cast (blocks 1024..1279) ----------------
__global__ __launch_bounds__(256) void k_setup(u32* kmaxEnc, u16* projS,
    const float* __restrict__ proj, const float* __restrict__ x, u16* __restrict__ xb,
    const float* s0, const float* s1, const float* s2, const float* s3,
    u16* d0, u16* d1, u16* d2, u16* d3)
{
  int bid=blockIdx.x, tid=threadIdx.x;
  if (bid < 1024){
    int z = bid>>8, t = bid&255;
    const float* src = z==0?s0:(z==1?s1:(z==2?s2:s3));
    u16* dst         = z==0?d0:(z==1?d1:(z==2?d2:d3));
    __shared__ u16 tl[32][34];
    int c0=(t&15)*32, r0=(t>>4)*32;
    for (int u=tid; u<1024; u+=256){ int r=u>>5, c=u&31; tl[r][c]=f2bf(src[(size_t)(r0+r)*512 + c0+c]); }
    __syncthreads();
    for (int u=tid; u<1024; u+=256){ int c=u>>5, r=u&31; dst[(size_t)(c0+c)*512 + r0+r]=tl[r][c]; }
  } else {
    int i = (bid-1024)*256 + tid;
    int st = 256*256;
    for (int j=i; j<32; j+=st) kmaxEnc[j]=0u;
    const float dn = 0.35355339059327373f; // 64^-0.25
    for (int j=i; j<512*64; j+=st) projS[j] = f2bf(dn*proj[j]);
    for (int j=i; j<524288; j+=st){
      float4 a = *(const float4*)&x[(size_t)j*8];
      float4 b = *(const float4*)&x[(size_t)j*8+4];
      u16 tmp[8] = {f2bf(a.x),f2bf(a.y),f2bf(a.z),f2bf(a.w),
                    f2bf(b.x),f2bf(b.y),f2bf(b.z),f2bf(b.w)};
      *(int4*)&xb[(size_t)j*8] = *(const int4*)tmp;
    }
  }
}

// ---------------- prep: trv (0..4095) + vsum (4096..4127) + kdiag (4128..4383) ----------------
__global__ __launch_bounds__(256) void k_prep(const u16* __restrict__ vB, u16* __restrict__ vT,
    float* __restrict__ vsum, const u16* __restrict__ kB, float* __restrict__ diagK)
{
  int bid=blockIdx.x, tid=threadIdx.x;
  if (bid < 4096){
    int xx=bid&1, y=(bid>>1)&63, bh=bid>>7;
    int b=bh>>3, h=bh&7;
    int dd0=xx*32, n0=y*32;
    __shared__ u16 t[32][34];
    const u16* s = vB + (size_t)(b*2048)*512 + h*64;
    for (int u=tid; u<1024; u+=256){ int r=u>>5, c=u&31; t[r][c]=s[(size_t)(n0+r)*512 + dd0+c]; }
    __syncthreads();
    u16* d = vT + (size_t)bh*64*2048;
    for (int u=tid; u<1024; u+=256){ int c=u>>5, r=u&31; d[(size_t)(dd0+c)*2048 + n0+r]=t[r][c]; }
  } else if (bid < 4128){
    int bh=bid-4096; int b=bh>>3, h=bh&7;
    int d=tid&63, part=tid>>6;
    const u16* src = vB + (size_t)(b*2048 + part*512)*512 + h*64 + d;
    float s=0.f;
    for (int n=0;n<512;++n) s += bf2f(src[(size_t)n*512]);
    __shared__ float red[256];
    red[tid]=s; __syncthreads();
    if (part==0) vsum[bh*64+d]=red[d]+red[64+d]+red[128+d]+red[192+d];
  } else {
    int idx=bid-4128;
    int bh=idx&31, seg=idx>>5;
    int b=bh>>3, h=bh&7;
    int part=tid&7;
    const u16* base = kB + (size_t)(b*2048 + seg*256)*512 + h*64 + part*8;
    for (int n0=0; n0<256; n0+=32){
      int n = n0 + (tid>>3);
      bf16x8 v = *(const bf16x8*)&base[(size_t)n*512];
      float sq=0.f;
      #pragma unroll
      for (int j=0;j<8;++j){ float f=bf2f((u16)v[j]); sq+=f*f; }
      sq += __shfl_xor(sq,1,64); sq += __shfl_xor(sq,2,64); sq += __shfl_xor(sq,4,64);
      if (part==0) diagK[(size_t)bh*2048 + seg*256 + n] = 0.0625f*sq;
    }
  }
}

// ---------------- GEMM m97-style (round-6 proven): O[8192x512] = A(bf16) @ BT^T + bias ----------------
template<bool OF32>
__global__ __launch_bounds__(256) void k_gemm2(const u16* __restrict__ A,
    const u16* BT0, const u16* BT1, const u16* BT2,
    const float* b0, const float* b1, const float* b2,
    void* O0, void* O1, void* O2)
{
  int z = blockIdx.z;
  const u16* BT    = z==0?BT0:(z==1?BT1:BT2);
  const float* bias= z==0?b0 :(z==1?b1 :b2 );
  void* Ov         = z==0?O0 :(z==1?O1 :O2 );
  int bm = blockIdx.x*128, bn = blockIdx.y*64;
  __shared__ u16 sA[128*64];
  __shared__ u16 sB[64*64];
  int tid=threadIdx.x, w=tid>>6, lane=tid&63;
  int lr = lane>>3, lc = (lane&7)*8;
  f32x4 acc[8] = {};
  for (int kk=0; kk<512; kk+=64){
    __syncthreads();
    #pragma unroll
    for (int i=0;i<4;++i){
      int idx = w*4+i;
      async_lds16(&sA[idx*512], A + (size_t)(bm + idx*8 + lr)*512 + kk + lc);
    }
    #pragma unroll
    for (int i=0;i<2;++i){
      int idx = w*2+i;
      async_lds16(&sB[idx*512], BT + (size_t)(bn + idx*8 + lr)*512 + kk + lc);
    }
    __syncthreads();
    int fr = lane&15, kb=(lane>>4)*8;
    #pragma unroll
    for (int rt=0; rt<2; ++rt){
      int ar = (w*2+rt)*16 + fr;
      #pragma unroll
      for (int ct=0; ct<4; ++ct){
        int br = ct*16 + fr;
        #pragma unroll
        for (int kc=0; kc<2; ++kc){
          bf16x8 av = *(const bf16x8*)&sA[ar*64 + kc*32 + kb];
          bf16x8 bv = *(const bf16x8*)&sB[br*64 + kc*32 + kb];
          acc[rt*4+ct] = MFMA16(av,bv,acc[rt*4+ct]);
        }
      }
    }
  }
  int colg = lane&15, rowg=(lane>>4)*4;
  #pragma unroll
  for (int rt=0; rt<2; ++rt){
    #pragma unroll
    for (int ct=0; ct<4; ++ct){
      int col = bn + ct*16 + colg;
      float bv = bias[col];
      #pragma unroll
      for (int j=0;j<4;++j){
        int row = bm + (w*2+rt)*16 + rowg + j;
        if constexpr (OF32) ((float*)Ov)[(size_t)row*512 + col] = acc[rt*4+ct][j] + bv;
        else                ((u16*) Ov)[(size_t)row*512 + col] = f2bf(acc[rt*4+ct][j] + bv);
      }
    }
  }
}

// ---------------- k features (exp-only) + half-n ctx partial + S (in-reg) + mk ----------------
__global__ __launch_bounds__(256) void k_kpctx3(const u16* __restrict__ kB, const u16* __restrict__ projS,
    const u16* __restrict__ vT, const float* __restrict__ diagK,
    float* __restrict__ ctxPT, float* __restrict__ kcsP, u32* __restrict__ kmaxEnc)
{
  int h=blockIdx.x, y=blockIdx.y, b=blockIdx.z;
  int mblk = y&7, s = y>>3;
  int bh=b*8+h;
  int m0 = mblk*64;
  __shared__ __align__(16) u16 sK[128*72];
  __shared__ __align__(16) u16 sV[64*136];
  __shared__ __align__(16) u16 sP[64*72];
  __shared__ __align__(16) u16 sT[64*136];
  __shared__ float sDg[128];
  __shared__ float red[4];
  __shared__ float sRed[4][64];
  int tid=threadIdx.x, w=tid>>6, lane=tid&63;
  int fr=lane&15, kbg=lane>>4, kb=kbg*8, rowg=kbg*4;
  stage64<64>(sP, projS + m0*64, 64, tid);
  f32x4 accc[4]={};
  float sSm[4]={0.f,0.f,0.f,0.f};
  float lm=-3.0e38f;
  const u16* gK = kB + (size_t)(b*2048 + s*1024)*512 + h*64;
  const u16* gV = vT + (size_t)bh*64*2048 + s*1024;
  const float* gD = diagK + (size_t)bh*2048 + s*1024;
  int4 pK[4], pV[4]; float4 pD={0.f,0.f,0.f,0.f};
  #pragma unroll
  for (int i=0;i<4;++i){ int u=tid+i*256; int r=u>>3,c=(u&7)<<3; pK[i]=*(const int4*)&gK[(size_t)r*512 + c]; }
  #pragma unroll
  for (int i=0;i<4;++i){ int u=tid+i*256; int r=u>>4,c=(u&15)<<3; pV[i]=*(const int4*)&gV[(size_t)r*2048 + c]; }
  if (tid<32) pD = *(const float4*)&gD[tid*4];
  for (int nc=0; nc<8; ++nc){
    #pragma unroll
    for (int i=0;i<4;++i){ int u=tid+i*256; int r=u>>3,c=(u&7)<<3; *(int4*)&sK[r*72+c]=pK[i]; }
    #pragma unroll
    for (int i=0;i<4;++i){ int u=tid+i*256; int r=u>>4,c=(u&15)<<3; *(int4*)&sV[r*136+c]=pV[i]; }
    if (tid<32) *(float4*)&sDg[tid*4] = pD;
    __syncthreads();
    if (nc<7){
      #pragma unroll
      for (int i=0;i<4;++i){ int u=tid+i*256; int r=u>>3,c=(u&7)<<3; pK[i]=*(const int4*)&gK[(size_t)((nc+1)*128+r)*512 + c]; }
      #pragma unroll
      for (int i=0;i<4;++i){ int u=tid+i*256; int r=u>>4,c=(u&15)<<3; pV[i]=*(const int4*)&gV[(size_t)r*2048 + (nc+1)*128 + c]; }
      if (tid<32) pD = *(const float4*)&gD[(nc+1)*128 + tid*4];
    }
    f32x4 facc[2][4];
    #pragma unroll
    for (int rt=0;rt<2;++rt){
      int ar=(w*2+rt)*16+fr;
      #pragma unroll
      for (int mt=0;mt<4;++mt){
        f32x4 a={0.f,0.f,0.f,0.f};
        a=MFMA16(*(const bf16x8*)&sK[ar*72+kb],    *(const bf16x8*)&sP[(mt*16+fr)*72+kb],    a);
        a=MFMA16(*(const bf16x8*)&sK[ar*72+32+kb], *(const bf16x8*)&sP[(mt*16+fr)*72+32+kb], a);
        facc[rt][mt]=a;
        lm=fmaxf(lm, fmaxf(fmaxf(a[0],a[1]),fmaxf(a[2],a[3])));
      }
    }
    #pragma unroll
    for (int rt=0;rt<2;++rt){
      int nl=(w*2+rt)*16+rowg;
      #pragma unroll
      for (int mt=0;mt<4;++mt){
        int ml=mt*16+fr;
        s16x4 pk;
        #pragma unroll
        for (int j=0;j<4;++j){
          float vk = __expf(facc[rt][mt][j]-sDg[nl+j]);
          u16 us = f2bf(vk);
          pk[j]=(short)us;
          sSm[mt] += bf2f(us);
        }
        *(s16x4*)&sT[ml*136+nl]=pk;
      }
    }
    __syncthreads();
    int am=w*16+fr;
    #pragma unroll
    for (int ct=0;ct<4;++ct){
      #pragma unroll
      for (int ks=0;ks<4;++ks){
        accc[ct]=MFMA16(*(const bf16x8*)&sT[am*136+ks*32+kb],
                        *(const bf16x8*)&sV[(ct*16+fr)*136+ks*32+kb], accc[ct]);
      }
    }
    __syncthreads();
  }
  #pragma unroll
  for (int mt=0;mt<4;++mt){
    float t=sSm[mt];
    t += __shfl_xor(t,16,64); t += __shfl_xor(t,32,64);
    if (kbg==0) sRed[w][mt*16+fr]=t;
  }
  #pragma unroll
  for (int m2=1;m2<64;m2<<=1) lm=fmaxf(lm,__shfl_xor(lm,m2,64));
  if (lane==0) red[w]=lm;
  float* sTf = (float*)sT;
  int mloc = w*16+rowg;
  #pragma unroll
  for (int ct=0;ct<4;++ct){
    #pragma unroll
    for (int j=0;j<4;++j) sTf[(ct*16+fr)*68 + mloc + j] = accc[ct][j];
  }
  __syncthreads();
  if (tid==0) atomicMax(&kmaxEnc[bh], encf(fmaxf(fmaxf(red[0],red[1]),fmaxf(red[2],red[3]))));
  if (tid<64) kcsP[(size_t)(s*32+bh)*512 + m0 + tid] =
      sRed[0][tid]+sRed[1][tid]+sRed[2][tid]+sRed[3][tid];
  for (int u=tid; u<1024; u+=256){
    int r=u>>4, c=(u&15)*4;
    *(float4*)&ctxPT[((size_t)(s*32+bh)*64 + r)*512 + m0 + c] = *(const float4*)&sTf[r*68+c];
  }
}

// ---------------- combine split-n partials -> ctxT bf16 + kcs, fused ctxsum/kcssum ----------------
__global__ __launch_bounds__(256) void k_comb2(const float* __restrict__ ctxPT, u16* __restrict__ ctxT,
    const float* __restrict__ kcsP, float* __restrict__ kcs,
    float* __restrict__ ctxsum, float* __restrict__ kcssum)
{
  int bh=blockIdx.x, dblk=blockIdx.y;
  int tid=threadIdx.x;
  int d0=dblk*8;
  __shared__ float sDsum[8];
  __shared__ float sKsum[256];
  if (tid<8) sDsum[tid]=0.f;
  __syncthreads();
  const float* p0 = ctxPT + ((size_t)bh*64 + d0)*512;
  const float* p1 = ctxPT + ((size_t)(32+bh)*64 + d0)*512;
  u16* o = ctxT + ((size_t)bh*64 + d0)*512;
  for (int u=tid; u<1024; u+=256){
    int r=u>>7, c=(u&127)*4;
    float4 a=*(const float4*)&p0[(size_t)r*512+c];
    float4 bq=*(const float4*)&p1[(size_t)r*512+c];
    float vx=a.x+bq.x, vy=a.y+bq.y, vz=a.z+bq.z, vw=a.w+bq.w;
    u16 t[4]={f2bf(vx),f2bf(vy),f2bf(vz),f2bf(vw)};
    *(int2*)&o[(size_t)r*512+c] = *(const int2*)t;
    atomicAdd(&sDsum[r], bf2f(t[0])+bf2f(t[1])+bf2f(t[2])+bf2f(t[3]));
  }
  float tpart=0.f;
  if (dblk==0){
    for (int u=tid; u<512; u+=256){
      float t = kcsP[(size_t)bh*512+u] + kcsP[(size_t)(32+bh)*512+u];
      kcs[(size_t)bh*512+u]=t;
      tpart += t;
    }
  }
  sKsum[tid]=tpart;
  __syncthreads();
  if (tid<8) ctxsum[bh*64 + d0 + tid] = sDsum[tid];
  if (dblk==0 && tid<64){
    float a=sKsum[tid]+sKsum[tid+64]+sKsum[tid+128]+sKsum[tid+192];
    #pragma unroll
    for (int m2=1;m2<64;m2<<=1) a += __shfl_xor(a,m2,64);
    if (tid==0) kcssum[bh]=a;
  }
}

// ---------------- q features + PV + eps epilogue: 64 rows/block, swizzled LDS, 1024 blocks ----------------
// (round-9 kernel, refcheck-passed at absmax 1.5259e-4; isolated A/B vs qpout2 this round)
__global__ __launch_bounds__(256) void k_qpout3(const u16* __restrict__ qB, const u16* __restrict__ projS,
    const float* __restrict__ kcs, const u16* __restrict__ ctxT,
    const float* __restrict__ ctxsum, const float* __restrict__ kcssum,
    const float* __restrict__ vsum, const u32* __restrict__ kmaxEnc,
    u16* __restrict__ outc)
{
  int h=blockIdx.x, chunk=blockIdx.y, b=blockIdx.z;
  int bh=b*8+h;
  int t0 = b*2048 + chunk*64;
  __shared__ u16 sP[2][64*64];
  __shared__ u16 sCt[64*64];
  __shared__ u16 qpL[64*72];
  __shared__ float sK[512];
  __shared__ float diag[64];
  int tid=threadIdx.x, w=tid>>6, lane=tid&63;
  int fr=lane&15, kbg=lane>>4, kb=kbg*8, rowg=kbg*4;
  int lr=lane>>3, lgl=((lane&7)^lr)*8;   // swizzled source granule offset (elems)
  int sw=fr&7;                            // read-side XOR key (row&7)
  bf16x8 qf[2];
  #pragma unroll
  for (int kc=0;kc<2;++kc)
    qf[kc] = *(const bf16x8*)&qB[(size_t)(t0 + w*16 + fr)*512 + h*64 + kc*32 + kb];
  {
    float ssum=0.f;
    #pragma unroll
    for (int kc=0;kc<2;++kc)
      #pragma unroll
      for (int j=0;j<8;++j){ float f=bf2f((u16)qf[kc][j]); ssum+=f*f; }
    ssum += __shfl_xor(ssum,16,64); ssum += __shfl_xor(ssum,32,64);
    if (lane<16) diag[w*16 + fr] = 0.0625f*ssum;
  }
  for (int u=tid; u<512; u+=256) sK[u] = kcs[(size_t)bh*512 + u];
  const u16* gcB = ctxT + (size_t)bh*64*512;
  // prologue: stage sP(0), swizzled source
  #pragma unroll
  for (int i=0;i<2;++i){
    int idx = w*2+i;
    async_lds16(&sP[0][idx*512], projS + (size_t)(idx*8+lr)*64 + lgl);
  }
  f32x4 acc2[4]={};
  float mx[4], dp[4], rs[4];
  #pragma unroll
  for (int j=0;j<4;++j){ mx[j]=-3.0e38f; dp[j]=0.f; rs[j]=0.f; }
  SOFT_BAR_VM(0);
  for (int mc=0; mc<8; ++mc){
    int cur = mc&1;
    // A: issue sCt(mc), then sP(mc+1) — both swizzled-source
    #pragma unroll
    for (int i=0;i<2;++i){
      int idx = w*2+i;
      async_lds16(&sCt[idx*512], gcB + (size_t)(idx*8+lr)*512 + mc*64 + lgl);
    }
    if (mc<7){
      const u16* gp = projS + (mc+1)*64*64;
      #pragma unroll
      for (int i=0;i<2;++i){
        int idx = w*2+i;
        async_lds16(&sP[cur^1][idx*512], gp + (size_t)(idx*8+lr)*64 + lgl);
      }
    }
    // B: feature MFMA on sP[cur] (swizzled read)
    f32x4 facc[4];
    #pragma unroll
    for (int mt=0;mt<4;++mt){
      f32x4 a={0.f,0.f,0.f,0.f};
      #pragma unroll
      for (int kc=0;kc<2;++kc){
        bf16x8 bv = *(const bf16x8*)&sP[cur][(mt*16+fr)*64 + (((kc*4+kbg)^sw)<<3)];
        a = MFMA16(qf[kc], bv, a);
      }
      facc[mt]=a;
    }
    // exp -> qpL (wave-private rows w*16..w*16+15)
    #pragma unroll
    for (int mt=0;mt<4;++mt){
      #pragma unroll
      for (int j=0;j<4;++j){
        int rl = w*16 + rowg + j;
        mx[j] = fmaxf(mx[j], facc[mt][j]);
        float vq = __expf(facc[mt][j] - diag[rl]);
        u16 us = f2bf(vq);
        qpL[rl*72 + mt*16 + fr] = us;
        float uf = bf2f(us);
        dp[j] += uf*sK[mc*64 + mt*16 + fr];
        rs[j] += uf;
      }
    }
    // C: retire sCt (keep sP(mc+1) in flight), publish
    if (mc<7) { SOFT_BAR_VM(2); } else { SOFT_BAR_VM(0); }
    // D: PV on qpL (same wave) + sCt (swizzled read)
    #pragma unroll
    for (int ct=0;ct<4;++ct){
      #pragma unroll
      for (int kc=0;kc<2;++kc){
        bf16x8 av = *(const bf16x8*)&qpL[(w*16+fr)*72 + kc*32 + kb];
        bf16x8 bv = *(const bf16x8*)&sCt[(ct*16+fr)*64 + (((kc*4+kbg)^sw)<<3)];
        acc2[ct] = MFMA16(av,bv,acc2[ct]);
      }
    }
    // E: retire sP(mc+1) + publish; protects sCt overwrite next chunk
    if (mc<7) { SOFT_BAR_VM(0); }
  }
  #pragma unroll
  for (int j=0;j<4;++j){
    #pragma unroll
    for (int s=1;s<16;s<<=1){
      dp[j] += __shfl_xor(dp[j],s,64);
      rs[j] += __shfl_xor(rs[j],s,64);
      mx[j]  = fmaxf(mx[j], __shfl_xor(mx[j],s,64));
    }
  }
  float mk  = decf(kmaxEnc[bh]);
  float emk = __expf(mk);
  float Ssum = kcssum[bh];
  const float eps=1e-4f;
  float emq[4];
  #pragma unroll
  for (int j=0;j<4;++j) emq[j]=__expf(mx[j]);
  #pragma unroll
  for (int ct=0;ct<4;++ct){
    int d = ct*16 + fr;
    float cs = ctxsum[bh*64 + d];
    float vs = vsum[bh*64 + d];
    #pragma unroll
    for (int j=0;j<4;++j){
      float eq = emq[j];
      float numer = acc2[ct][j] + eps*(emk*vs*rs[j] + eq*cs + eps*eq*emk*512.0f*vs);
      float den   = dp[j]       + eps*(emk*2048.0f*rs[j] + eq*Ssum + eps*eq*emk*512.0f*2048.0f);
      int row = t0 + w*16 + rowg + j;
      outc[(size_t)row*512 + h*64 + d] = f2bf(numer/den);
    }
  }
}

extern "C" void kernel_launch(void* const* d_in, const int* in_sizes, int n_in,
                              void* d_out, int out_size, void* d_ws, size_t ws_size,
                              hipStream_t stream)
{
  (void)in_sizes; (void)n_in; (void)out_size; (void)ws_size;
  const float* x    = (const float*)d_in[0];
  const float* Wq   = (const float*)d_in[1];
  const float* bq   = (const float*)d_in[2];
  const float* Wk   = (const float*)d_in[3];
  const float* bk   = (const float*)d_in[4];
  const float* Wv   = (const float*)d_in[5];
  const float* bv   = (const float*)d_in[6];
  const float* Wo   = (const float*)d_in[7];
  const float* bo   = (const float*)d_in[8];
  const float* proj = (const float*)d_in[9];

  char* w = (char*)d_ws;
  size_t off=0;
  auto alloc=[&](size_t bytes)->char*{ char* p=w+off; off=(off+bytes+255)&~(size_t)255; return p; };
  u16*  xb   = (u16*)alloc(8192ull*512*2);
  u16*  qB   = (u16*)alloc(8192ull*512*2);
  u16*  kBf  = (u16*)alloc(8192ull*512*2);
  u16*  vB   = (u16*)alloc(8192ull*512*2);
  u16*  vT   = (u16*)alloc(32ull*64*2048*2);
  u16*  WqT  = (u16*)alloc(512ull*512*2);
  u16*  WkT  = (u16*)alloc(512ull*512*2);
  u16*  WvT  = (u16*)alloc(512ull*512*2);
  u16*  WoT  = (u16*)alloc(512ull*512*2);
  u16*  projS= (u16*)alloc(512ull*64*2);
  u16*  ctxT = (u16*)alloc(32ull*64*512*2);
  float* ctxPT=(float*)alloc(2ull*32*64*512*4);
  float* kcs = (float*)alloc(32ull*512*4);
  float* kcsP= (float*)alloc(2ull*32*512*4);
  float* diagK=(float*)alloc(32ull*2048*4);
  u32*  kmx  = (u32*)alloc(256);
  float* ctxs= (float*)alloc(32ull*64*4);
  float* kcss= (float*)alloc(32ull*4);
  float* vsm = (float*)alloc(32ull*64*4);
  u16*  outc = kBf;  // kBf dead after k_kpctx3; reuse

  dim3 TB(256);
  k_setup<<<dim3(1280),TB,0,stream>>>(kmx,projS,proj,x,xb, Wq,Wk,Wv,Wo, WqT,WkT,WvT,WoT);
  k_gemm2<false><<<dim3(64,8,3),TB,0,stream>>>(xb, WqT,WkT,WvT, bq,bk,bv, qB,kBf,vB);
  k_prep<<<dim3(4384),TB,0,stream>>>(vB, vT, vsm, kBf, diagK);
  k_kpctx3<<<dim3(8,16,4),TB,0,stream>>>(kBf, projS, vT, diagK, ctxPT, kcsP, kmx);
  k_comb2<<<dim3(32,8),TB,0,stream>>>(ctxPT, ctxT, kcsP, kcs, ctxs, kcss);
  k_qpout3<<<dim3(8,32,4),TB,0,stream>>>(qB, projS, kcs, ctxT, ctxs, kcss, vsm, kmx, outc);
  k_gemm2<true><<<dim3(64,8,1),TB,0,stream>>>(outc, WoT,WoT,WoT, bo,bo,bo,
                                              d_out,d_out,d_out);
}

// Round 17
// 132.477 us; speedup vs baseline: 1.2236x; 1.0946x over previous
//
#include <hip/hip_runtime.h>

typedef unsigned short u16;
typedef unsigned int   u32;
typedef __attribute__((ext_vector_type(8))) short bf16x8;
typedef __attribute__((ext_vector_type(4))) short s16x4;
typedef __attribute__((ext_vector_type(4))) float f32x4;

#define MFMA16(a,b,c) __builtin_amdgcn_mfma_f32_16x16x32_bf16((a),(b),(c),0,0,0)

// soft barriers: raw s_barrier + counted waits
#define SOFT_BAR_LG() do{ asm volatile("s_waitcnt lgkmcnt(0)" ::: "memory"); \
  __builtin_amdgcn_s_barrier(); __builtin_amdgcn_sched_barrier(0); }while(0)
#define SOFT_BAR_VM(N) do{ asm volatile("s_waitcnt vmcnt(" #N ") lgkmcnt(0)" ::: "memory"); \
  __builtin_amdgcn_s_barrier(); __builtin_amdgcn_sched_barrier(0); }while(0)

__device__ __forceinline__ float bf2f(u16 u){ return __uint_as_float(((u32)u)<<16); }
__device__ __forceinline__ u16 f2bf(float f){
  u32 u = __float_as_uint(f);
  return (u16)((u + 0x7fffu + ((u>>16)&1u)) >> 16);
}
__device__ __forceinline__ u32 encf(float f){ u32 u=__float_as_uint(f); return (u&0x80000000u)? ~u : (u|0x80000000u); }
__device__ __forceinline__ float decf(u32 u){ return (u&0x80000000u)? __uint_as_float(u&0x7fffffffu) : __uint_as_float(~u); }

__device__ __forceinline__ void async_lds16(u16* lds, const u16* g){
  __builtin_amdgcn_global_load_lds((const __attribute__((address_space(1))) void*)g,
                                   (__attribute__((address_space(3))) void*)lds,
                                   16, 0, 0);
}

// stage ROWS x 64 bf16 from global into LDS padded to 72/row
template<int ROWS>
__device__ __forceinline__ void stage64(u16* dst, const u16* src, int srcStride, int tid){
  #pragma unroll
  for (int u=tid; u<ROWS*8; u+=256){
    int r=u>>3, c=(u&7)<<3;
    *(int4*)&dst[r*72+c] = *(const int4*)&src[(size_t)r*srcStride + c];
  }
}

// ---------------- setup: weight transposes (blocks 0..1023) + init/cast (blocks 1024..1279) ----------------
__global__ __launch_bounds__(256) void k_setup(u32* kmaxEnc, u16* projS,
    const float* __restrict__ proj, const float* __restrict__ x, u16* __restrict__ xb,
    const float* s0, const float* s1, const float* s2, const float* s3,
    u16* d0, u16* d1, u16* d2, u16* d3)
{
  int bid=blockIdx.x, tid=threadIdx.x;
  if (bid < 1024){
    int z = bid>>8, t = bid&255;
    const float* src = z==0?s0:(z==1?s1:(z==2?s2:s3));
    u16* dst         = z==0?d0:(z==1?d1:(z==2?d2:d3));
    __shared__ u16 tl[32][34];
    int c0=(t&15)*32, r0=(t>>4)*32;
    for (int u=tid; u<1024; u+=256){ int r=u>>5, c=u&31; tl[r][c]=f2bf(src[(size_t)(r0+r)*512 + c0+c]); }
    __syncthreads();
    for (int u=tid; u<1024; u+=256){ int c=u>>5, r=u&31; dst[(size_t)(c0+c)*512 + r0+r]=tl[r][c]; }
  } else {
    int i = (bid-1024)*256 + tid;
    int st = 256*256;
    for (int j=i; j<32; j+=st) kmaxEnc[j]=0u;
    const float dn = 0.35355339059327373f; // 64^-0.25
    for (int j=i; j<512*64; j+=st) projS[j] = f2bf(dn*proj[j]);
    for (int j=i; j<524288; j+=st){
      float4 a = *(const float4*)&x[(size_t)j*8];
      float4 b = *(const float4*)&x[(size_t)j*8+4];
      u16 tmp[8] = {f2bf(a.x),f2bf(a.y),f2bf(a.z),f2bf(a.w),
                    f2bf(b.x),f2bf(b.y),f2bf(b.z),f2bf(b.w)};
      *(int4*)&xb[(size_t)j*8] = *(const int4*)tmp;
    }
  }
}

// ---------------- prep: trv (0..4095) + vsum (4096..4127) + kdiag (4128..4383) ----------------
__global__ __launch_bounds__(256) void k_prep(const u16* __restrict__ vB, u16* __restrict__ vT,
    float* __restrict__ vsum, const u16* __restrict__ kB, float* __restrict__ diagK)
{
  int bid=blockIdx.x, tid=threadIdx.x;
  if (bid < 4096){
    int xx=bid&1, y=(bid>>1)&63, bh=bid>>7;
    int b=bh>>3, h=bh&7;
    int dd0=xx*32, n0=y*32;
    __shared__ u16 t[32][34];
    const u16* s = vB + (size_t)(b*2048)*512 + h*64;
    for (int u=tid; u<1024; u+=256){ int r=u>>5, c=u&31; t[r][c]=s[(size_t)(n0+r)*512 + dd0+c]; }
    __syncthreads();
    u16* d = vT + (size_t)bh*64*2048;
    for (int u=tid; u<1024; u+=256){ int c=u>>5, r=u&31; d[(size_t)(dd0+c)*2048 + n0+r]=t[r][c]; }
  } else if (bid < 4128){
    int bh=bid-4096; int b=bh>>3, h=bh&7;
    int d=tid&63, part=tid>>6;
    const u16* src = vB + (size_t)(b*2048 + part*512)*512 + h*64 + d;
    float s=0.f;
    for (int n=0;n<512;++n) s += bf2f(src[(size_t)n*512]);
    __shared__ float red[256];
    red[tid]=s; __syncthreads();
    if (part==0) vsum[bh*64+d]=red[d]+red[64+d]+red[128+d]+red[192+d];
  } else {
    int idx=bid-4128;
    int bh=idx&31, seg=idx>>5;
    int b=bh>>3, h=bh&7;
    int part=tid&7;
    const u16* base = kB + (size_t)(b*2048 + seg*256)*512 + h*64 + part*8;
    for (int n0=0; n0<256; n0+=32){
      int n = n0 + (tid>>3);
      bf16x8 v = *(const bf16x8*)&base[(size_t)n*512];
      float sq=0.f;
      #pragma unroll
      for (int j=0;j<8;++j){ float f=bf2f((u16)v[j]); sq+=f*f; }
      sq += __shfl_xor(sq,1,64); sq += __shfl_xor(sq,2,64); sq += __shfl_xor(sq,4,64);
      if (part==0) diagK[(size_t)bh*2048 + seg*256 + n] = 0.0625f*sq;
    }
  }
}

// ---------------- GEMM m97-style (round-6 proven): O[8192x512] = A(bf16) @ BT^T + bias ----------------
template<bool OF32>
__global__ __launch_bounds__(256) void k_gemm2(const u16* __restrict__ A,
    const u16* BT0, const u16* BT1, const u16* BT2,
    const float* b0, const float* b1, const float* b2,
    void* O0, void* O1, void* O2)
{
  int z = blockIdx.z;
  const u16* BT    = z==0?BT0:(z==1?BT1:BT2);
  const float* bias= z==0?b0 :(z==1?b1 :b2 );
  void* Ov         = z==0?O0 :(z==1?O1 :O2 );
  int bm = blockIdx.x*128, bn = blockIdx.y*64;
  __shared__ u16 sA[128*64];
  __shared__ u16 sB[64*64];
  int tid=threadIdx.x, w=tid>>6, lane=tid&63;
  int lr = lane>>3, lc = (lane&7)*8;
  f32x4 acc[8] = {};
  for (int kk=0; kk<512; kk+=64){
    __syncthreads();
    #pragma unroll
    for (int i=0;i<4;++i){
      int idx = w*4+i;
      async_lds16(&sA[idx*512], A + (size_t)(bm + idx*8 + lr)*512 + kk + lc);
    }
    #pragma unroll
    for (int i=0;i<2;++i){
      int idx = w*2+i;
      async_lds16(&sB[idx*512], BT + (size_t)(bn + idx*8 + lr)*512 + kk + lc);
    }
    __syncthreads();
    int fr = lane&15, kb=(lane>>4)*8;
    #pragma unroll
    for (int rt=0; rt<2; ++rt){
      int ar = (w*2+rt)*16 + fr;
      #pragma unroll
      for (int ct=0; ct<4; ++ct){
        int br = ct*16 + fr;
        #pragma unroll
        for (int kc=0; kc<2; ++kc){
          bf16x8 av = *(const bf16x8*)&sA[ar*64 + kc*32 + kb];
          bf16x8 bv = *(const bf16x8*)&sB[br*64 + kc*32 + kb];
          acc[rt*4+ct] = MFMA16(av,bv,acc[rt*4+ct]);
        }
      }
    }
  }
  int colg = lane&15, rowg=(lane>>4)*4;
  #pragma unroll
  for (int rt=0; rt<2; ++rt){
    #pragma unroll
    for (int ct=0; ct<4; ++ct){
      int col = bn + ct*16 + colg;
      float bv = bias[col];
      #pragma unroll
      for (int j=0;j<4;++j){
        int row = bm + (w*2+rt)*16 + rowg + j;
        if constexpr (OF32) ((float*)Ov)[(size_t)row*512 + col] = acc[rt*4+ct][j] + bv;
        else                ((u16*) Ov)[(size_t)row*512 + col] = f2bf(acc[rt*4+ct][j] + bv);
      }
    }
  }
}

// ---------------- k features + quarter-n ctx partial: qpout3-style schedule ----------------
// grid (8 h, 32 = s*8+mblk, 4 b); s in 0..3 owns n-range [s*512,(s+1)*512), chunks of 64.
// sK dbuf + sV single via swizzled global_load_lds; counted vmcnt soft barriers; diag fully in regs.
__global__ __launch_bounds__(256) void k_kpctx6(const u16* __restrict__ kB, const u16* __restrict__ projS,
    const u16* __restrict__ vT, const float* __restrict__ diagK,
    float* __restrict__ ctxPT, float* __restrict__ kcsP, u32* __restrict__ kmaxEnc)
{
  int h=blockIdx.x, y=blockIdx.y, b=blockIdx.z;
  int mblk = y&7, s = y>>3;
  int bh=b*8+h;
  int m0 = mblk*64;
  __shared__ __align__(16) u16 sP[64*72];        // proj rows m0..m0+63, padded (loop-invariant)
  __shared__ __align__(16) u16 poolKV[3*4096];   // sK[0] | sK[1] | sV (linear, swizzled)
  __shared__ __align__(16) u16 sT[64*72];        // kp^T bounce, padded
  __shared__ float sRed[4][64];
  __shared__ float red[4];
  u16* sK0 = poolKV;
  u16* sK1 = poolKV + 4096;
  u16* sV  = poolKV + 8192;
  int tid=threadIdx.x, w=tid>>6, lane=tid&63;
  int fr=lane&15, kbg=lane>>4, kb=kbg*8, rowg=kbg*4;
  int lr=lane>>3, lgl=((lane&7)^lr)*8;   // swizzled source granule (elems)
  int sw=fr&7;                            // read-side XOR key
  const u16* gK = kB + (size_t)(b*2048 + s*512)*512 + h*64;
  const u16* gV = vT + (size_t)bh*64*2048 + s*512;
  const float* gD = diagK + (size_t)bh*2048 + s*512 + w*16 + rowg;
  // prologue: sP (padded reg-stage), diag for all 8 chunks into regs, sK chunk0
  stage64<64>(sP, projS + m0*64, 64, tid);
  float4 pD[8];
  #pragma unroll
  for (int mc=0;mc<8;++mc) pD[mc] = *(const float4*)&gD[mc*64];
  #pragma unroll
  for (int i=0;i<2;++i){
    int idx = w*2+i;
    async_lds16(&sK0[idx*512], gK + (size_t)(idx*8+lr)*512 + lgl);
  }
  f32x4 accc[4]={};
  float sSm[4]={0.f,0.f,0.f,0.f};
  float lm=-3.0e38f;
  SOFT_BAR_VM(0);   // sP (lgkm) + sK0 + pD loads all retired
  #pragma unroll
  for (int mc=0; mc<8; ++mc){
    u16* sKc = (mc&1) ? sK1 : sK0;
    u16* sKn = (mc&1) ? sK0 : sK1;
    // A: issue sV(mc) then sK(mc+1) — pure-async vm stream (oldest = sV)
    #pragma unroll
    for (int i=0;i<2;++i){
      int idx = w*2+i;
      async_lds16(&sV[idx*512], gV + (size_t)(idx*8+lr)*2048 + mc*64 + lgl);
    }
    if (mc<7){
      #pragma unroll
      for (int i=0;i<2;++i){
        int idx = w*2+i;
        async_lds16(&sKn[idx*512], gK + (size_t)((mc+1)*64 + idx*8+lr)*512 + lgl);
      }
    }
    // B: feature MFMA dd[64 n][64 m] on sK[cur] (swizzled) x sP (padded); wave w owns n rows w*16+fr
    int ar = w*16 + fr;
    f32x4 facc[4];
    #pragma unroll
    for (int mt=0;mt<4;++mt){
      f32x4 a={0.f,0.f,0.f,0.f};
      #pragma unroll
      for (int kc=0;kc<2;++kc){
        bf16x8 av = *(const bf16x8*)&sKc[ar*64 + (((kc*4+kbg)^sw)<<3)];
        bf16x8 bv = *(const bf16x8*)&sP[(mt*16+fr)*72 + kc*32 + kb];
        a = MFMA16(av,bv,a);
      }
      facc[mt]=a;
      lm=fmaxf(lm, fmaxf(fmaxf(a[0],a[1]),fmaxf(a[2],a[3])));
    }
    // exp -> sT[m][n] (padded), S in regs; diag from regs (no LDS, no cross-wave dep)
    {
      int nl = w*16 + rowg;
      #pragma unroll
      for (int mt=0;mt<4;++mt){
        int ml=mt*16+fr;
        s16x4 pk;
        #pragma unroll
        for (int j=0;j<4;++j){
          float vk = __expf(facc[mt][j]-pD[mc][j]);
          u16 us = f2bf(vk);
          pk[j]=(short)us;
          sSm[mt] += bf2f(us);
        }
        *(s16x4*)&sT[ml*72+nl]=pk;
      }
      (void)nl;
    }
    // C: retire sV (keep sK(mc+1) flying), publish sT
    if (mc<7) { SOFT_BAR_VM(2); } else { SOFT_BAR_VM(0); }
    // D: PV: ctx[m][d] += sT[m][n] @ sV[d][n]^T ; wave w owns m rows w*16..+15
    {
      int am=w*16+fr;
      #pragma unroll
      for (int ct=0;ct<4;++ct){
        #pragma unroll
        for (int kc=0;kc<2;++kc){
          bf16x8 av = *(const bf16x8*)&sT[am*72 + kc*32 + kb];
          bf16x8 bv = *(const bf16x8*)&sV[(ct*16+fr)*64 + (((kc*4+kbg)^sw)<<3)];
          accc[ct] = MFMA16(av,bv,accc[ct]);
        }
      }
    }
    // E: retire sK(mc+1); protect sV/sT overwrite next chunk
    if (mc<7) { SOFT_BAR_VM(0); }
  }
  __syncthreads();   // all PV reads done before poolKV/sT reuse
  // S reduce across kbg, per-wave partial
  #pragma unroll
  for (int mt=0;mt<4;++mt){
    float t=sSm[mt];
    t += __shfl_xor(t,16,64); t += __shfl_xor(t,32,64);
    if (kbg==0) sRed[w][mt*16+fr]=t;
  }
  // mk partial
  #pragma unroll
  for (int m2=1;m2<64;m2<<=1) lm=fmaxf(lm,__shfl_xor(lm,m2,64));
  if (lane==0) red[w]=lm;
  // ctx partial f32, transposed [d][m] bounce into poolKV region (dead now)
  float* sTf = (float*)poolKV;   // 64*68*4 = 17408B <= 24576B
  int mloc = w*16+rowg;
  #pragma unroll
  for (int ct=0;ct<4;++ct){
    #pragma unroll
    for (int j=0;j<4;++j) sTf[(ct*16+fr)*68 + mloc + j] = accc[ct][j];
  }
  __syncthreads();
  if (tid==0) atomicMax(&kmaxEnc[bh], encf(fmaxf(fmaxf(red[0],red[1]),fmaxf(red[2],red[3]))));
  if (tid<64) kcsP[(size_t)(s*32+bh)*512 + m0 + tid] =
      sRed[0][tid]+sRed[1][tid]+sRed[2][tid]+sRed[3][tid];
  for (int u=tid; u<1024; u+=256){
    int r=u>>4, c=(u&15)*4;
    *(float4*)&ctxPT[((size_t)(s*32+bh)*64 + r)*512 + m0 + c] = *(const float4*)&sTf[r*68+c];
  }
}

// ---------------- combine 4 split-n partials -> ctxT bf16 + kcs, fused ctxsum/kcssum ----------------
__global__ __launch_bounds__(256) void k_comb4(const float* __restrict__ ctxPT, u16* __restrict__ ctxT,
    const float* __restrict__ kcsP, float* __restrict__ kcs,
    float* __restrict__ ctxsum, float* __restrict__ kcssum)
{
  int bh=blockIdx.x, dblk=blockIdx.y;
  int tid=threadIdx.x;
  int d0=dblk*8;
  __shared__ float sDsum[8];
  __shared__ float sKsum[256];
  if (tid<8) sDsum[tid]=0.f;
  __syncthreads();
  u16* o = ctxT + ((size_t)bh*64 + d0)*512;
  for (int u=tid; u<1024; u+=256){
    int r=u>>7, c=(u&127)*4;
    float4 a={0.f,0.f,0.f,0.f};
    #pragma unroll
    for (int s=0;s<4;++s){
      float4 p=*(const float4*)&ctxPT[((size_t)(s*32+bh)*64 + d0+r)*512 + c];
      a.x+=p.x; a.y+=p.y; a.z+=p.z; a.w+=p.w;
    }
    u16 t[4]={f2bf(a.x),f2bf(a.y),f2bf(a.z),f2bf(a.w)};
    *(int2*)&o[(size_t)r*512+c] = *(const int2*)t;
    // bf16-rounded values for the sum (matches prior numerics)
    atomicAdd(&sDsum[r], bf2f(t[0])+bf2f(t[1])+bf2f(t[2])+bf2f(t[3]));
  }
  float tpart=0.f;
  if (dblk==0){
    for (int u=tid; u<512; u+=256){
      float t=0.f;
      #pragma unroll
      for (int s=0;s<4;++s) t += kcsP[(size_t)(s*32+bh)*512+u];
      kcs[(size_t)bh*512+u]=t;
      tpart += t;
    }
  }
  sKsum[tid]=tpart;
  __syncthreads();
  if (tid<8) ctxsum[bh*64 + d0 + tid] = sDsum[tid];
  if (dblk==0 && tid<64){
    float a=sKsum[tid]+sKsum[tid+64]+sKsum[tid+128]+sKsum[tid+192];
    #pragma unroll
    for (int m2=1;m2<64;m2<<=1) a += __shfl_xor(a,m2,64);
    if (tid==0) kcssum[bh]=a;
  }
}

// ---------------- q features + PV + eps epilogue: 64 rows/block, swizzled LDS (round-16 proven) ----------------
__global__ __launch_bounds__(256) void k_qpout3(const u16* __restrict__ qB, const u16* __restrict__ projS,
    const float* __restrict__ kcs, const u16* __restrict__ ctxT,
    const float* __restrict__ ctxsum, const float* __restrict__ kcssum,
    const float* __restrict__ vsum, const u32* __restrict__ kmaxEnc,
    u16* __restrict__ outc)
{
  int h=blockIdx.x, chunk=blockIdx.y, b=blockIdx.z;
  int bh=b*8+h;
  int t0 = b*2048 + chunk*64;
  __shared__ u16 sP[2][64*64];
  __shared__ u16 sCt[64*64];
  __shared__ u16 qpL[64*72];
  __shared__ float sK[512];
  __shared__ float diag[64];
  int tid=threadIdx.x, w=tid>>6, lane=tid&63;
  int fr=lane&15, kbg=lane>>4, kb=kbg*8, rowg=kbg*4;
  int lr=lane>>3, lgl=((lane&7)^lr)*8;
  int sw=fr&7;
  bf16x8 qf[2];
  #pragma unroll
  for (int kc=0;kc<2;++kc)
    qf[kc] = *(const bf16x8*)&qB[(size_t)(t0 + w*16 + fr)*512 + h*64 + kc*32 + kb];
  {
    float ssum=0.f;
    #pragma unroll
    for (int kc=0;kc<2;++kc)
      #pragma unroll
      for (int j=0;j<8;++j){ float f=bf2f((u16)qf[kc][j]); ssum+=f*f; }
    ssum += __shfl_xor(ssum,16,64); ssum += __shfl_xor(ssum,32,64);
    if (lane<16) diag[w*16 + fr] = 0.0625f*ssum;
  }
  for (int u=tid; u<512; u+=256) sK[u] = kcs[(size_t)bh*512 + u];
  const u16* gcB = ctxT + (size_t)bh*64*512;
  #pragma unroll
  for (int i=0;i<2;++i){
    int idx = w*2+i;
    async_lds16(&sP[0][idx*512], projS + (size_t)(idx*8+lr)*64 + lgl);
  }
  f32x4 acc2[4]={};
  float mx[4], dp[4], rs[4];
  #pragma unroll
  for (int j=0;j<4;++j){ mx[j]=-3.0e38f; dp[j]=0.f; rs[j]=0.f; }
  SOFT_BAR_VM(0);
  for (int mc=0; mc<8; ++mc){
    int cur = mc&1;
    #pragma unroll
    for (int i=0;i<2;++i){
      int idx = w*2+i;
      async_lds16(&sCt[idx*512], gcB + (size_t)(idx*8+lr)*512 + mc*64 + lgl);
    }
    if (mc<7){
      const u16* gp = projS + (mc+1)*64*64;
      #pragma unroll
      for (int i=0;i<2;++i){
        int idx = w*2+i;
        async_lds16(&sP[cur^1][idx*512], gp + (size_t)(idx*8+lr)*64 + lgl);
      }
    }
    f32x4 facc[4];
    #pragma unroll
    for (int mt=0;mt<4;++mt){
      f32x4 a={0.f,0.f,0.f,0.f};
      #pragma unroll
      for (int kc=0;kc<2;++kc){
        bf16x8 bv = *(const bf16x8*)&sP[cur][(mt*16+fr)*64 + (((kc*4+kbg)^sw)<<3)];
        a = MFMA16(qf[kc], bv, a);
      }
      facc[mt]=a;
    }
    #pragma unroll
    for (int mt=0;mt<4;++mt){
      #pragma unroll
      for (int j=0;j<4;++j){
        int rl = w*16 + rowg + j;
        mx[j] = fmaxf(mx[j], facc[mt][j]);
        float vq = __expf(facc[mt][j] - diag[rl]);
        u16 us = f2bf(vq);
        qpL[rl*72 + mt*16 + fr] = us;
        float uf = bf2f(us);
        dp[j] += uf*sK[mc*64 + mt*16 + fr];
        rs[j] += uf;
      }
    }
    if (mc<7) { SOFT_BAR_VM(2); } else { SOFT_BAR_VM(0); }
    #pragma unroll
    for (int ct=0;ct<4;++ct){
      #pragma unroll
      for (int kc=0;kc<2;++kc){
        bf16x8 av = *(const bf16x8*)&qpL[(w*16+fr)*72 + kc*32 + kb];
        bf16x8 bv = *(const bf16x8*)&sCt[(ct*16+fr)*64 + (((kc*4+kbg)^sw)<<3)];
        acc2[ct] = MFMA16(av,bv,acc2[ct]);
      }
    }
    if (mc<7) { SOFT_BAR_VM(0); }
  }
  #pragma unroll
  for (int j=0;j<4;++j){
    #pragma unroll
    for (int s=1;s<16;s<<=1){
      dp[j] += __shfl_xor(dp[j],s,64);
      rs[j] += __shfl_xor(rs[j],s,64);
      mx[j]  = fmaxf(mx[j], __shfl_xor(mx[j],s,64));
    }
  }
  float mk  = decf(kmaxEnc[bh]);
  float emk = __expf(mk);
  float Ssum = kcssum[bh];
  const float eps=1e-4f;
  float emq[4];
  #pragma unroll
  for (int j=0;j<4;++j) emq[j]=__expf(mx[j]);
  #pragma unroll
  for (int ct=0;ct<4;++ct){
    int d = ct*16 + fr;
    float cs = ctxsum[bh*64 + d];
    float vs = vsum[bh*64 + d];
    #pragma unroll
    for (int j=0;j<4;++j){
      float eq = emq[j];
      float numer = acc2[ct][j] + eps*(emk*vs*rs[j] + eq*cs + eps*eq*emk*512.0f*vs);
      float den   = dp[j]       + eps*(emk*2048.0f*rs[j] + eq*Ssum + eps*eq*emk*512.0f*2048.0f);
      int row = t0 + w*16 + rowg + j;
      outc[(size_t)row*512 + h*64 + d] = f2bf(numer/den);
    }
  }
}

extern "C" void kernel_launch(void* const* d_in, const int* in_sizes, int n_in,
                              void* d_out, int out_size, void* d_ws, size_t ws_size,
                              hipStream_t stream)
{
  (void)in_sizes; (void)n_in; (void)out_size; (void)ws_size;
  const float* x    = (const float*)d_in[0];
  const float* Wq   = (const float*)d_in[1];
  const float* bq   = (const float*)d_in[2];
  const float* Wk   = (const float*)d_in[3];
  const float* bk   = (const float*)d_in[4];
  const float* Wv   = (const float*)d_in[5];
  const float* bv   = (const float*)d_in[6];
  const float* Wo   = (const float*)d_in[7];
  const float* bo   = (const float*)d_in[8];
  const float* proj = (const float*)d_in[9];

  char* w = (char*)d_ws;
  size_t off=0;
  auto alloc=[&](size_t bytes)->char*{ char* p=w+off; off=(off+bytes+255)&~(size_t)255; return p; };
  u16*  xb   = (u16*)alloc(8192ull*512*2);
  u16*  qB   = (u16*)alloc(8192ull*512*2);
  u16*  kBf  = (u16*)alloc(8192ull*512*2);
  u16*  vB   = (u16*)alloc(8192ull*512*2);
  u16*  vT   = (u16*)alloc(32ull*64*2048*2);
  u16*  WqT  = (u16*)alloc(512ull*512*2);
  u16*  WkT  = (u16*)alloc(512ull*512*2);
  u16*  WvT  = (u16*)alloc(512ull*512*2);
  u16*  WoT  = (u16*)alloc(512ull*512*2);
  u16*  projS= (u16*)alloc(512ull*64*2);
  u16*  ctxT = (u16*)alloc(32ull*64*512*2);
  float* ctxPT=(float*)alloc(4ull*32*64*512*4);
  float* kcs = (float*)alloc(32ull*512*4);
  float* kcsP= (float*)alloc(4ull*32*512*4);
  float* diagK=(float*)alloc(32ull*2048*4);
  u32*  kmx  = (u32*)alloc(256);
  float* ctxs= (float*)alloc(32ull*64*4);
  float* kcss= (float*)alloc(32ull*4);
  float* vsm = (float*)alloc(32ull*64*4);
  u16*  outc = kBf;  // kBf dead after k_kpctx6; reuse

  dim3 TB(256);
  k_setup<<<dim3(1280),TB,0,stream>>>(kmx,projS,proj,x,xb, Wq,Wk,Wv,Wo, WqT,WkT,WvT,WoT);
  k_gemm2<false><<<dim3(64,8,3),TB,0,stream>>>(xb, WqT,WkT,WvT, bq,bk,bv, qB,kBf,vB);
  k_prep<<<dim3(4384),TB,0,stream>>>(vB, vT, vsm, kBf, diagK);
  k_kpctx6<<<dim3(8,32,4),TB,0,stream>>>(kBf, projS, vT, diagK, ctxPT, kcsP, kmx);
  k_comb4<<<dim3(32,8),TB,0,stream>>>(ctxPT, ctxT, kcsP, kcs, ctxs, kcss);
  k_qpout3<<<dim3(8,32,4),TB,0,stream>>>(qB, projS, kcs, ctxT, ctxs, kcss, vsm, kmx, outc);
  k_gemm2<true><<<dim3(64,8,1),TB,0,stream>>>(outc, WoT,WoT,WoT, bo,bo,bo,
                                              d_out,d_out,d_out);
}

// Round 18
// 126.433 us; speedup vs baseline: 1.2821x; 1.0478x over previous
//
#include <hip/hip_runtime.h>

typedef unsigned short u16;
typedef unsigned int   u32;
typedef __attribute__((ext_vector_type(8))) short bf16x8;
typedef __attribute__((ext_vector_type(4))) short s16x4;
typedef __attribute__((ext_vector_type(4))) float f32x4;

#define MFMA16(a,b,c) __builtin_amdgcn_mfma_f32_16x16x32_bf16((a),(b),(c),0,0,0)

// soft barriers: raw s_barrier + counted waits
#define SOFT_BAR_LG() do{ asm volatile("s_waitcnt lgkmcnt(0)" ::: "memory"); \
  __builtin_amdgcn_s_barrier(); __builtin_amdgcn_sched_barrier(0); }while(0)
#define SOFT_BAR_VM(N) do{ asm volatile("s_waitcnt vmcnt(" #N ") lgkmcnt(0)" ::: "memory"); \
  __builtin_amdgcn_s_barrier(); __builtin_amdgcn_sched_barrier(0); }while(0)

__device__ __forceinline__ float bf2f(u16 u){ return __uint_as_float(((u32)u)<<16); }
__device__ __forceinline__ u16 f2bf(float f){
  u32 u = __float_as_uint(f);
  return (u16)((u + 0x7fffu + ((u>>16)&1u)) >> 16);
}
__device__ __forceinline__ u32 encf(float f){ u32 u=__float_as_uint(f); return (u&0x80000000u)? ~u : (u|0x80000000u); }
__device__ __forceinline__ float decf(u32 u){ return (u&0x80000000u)? __uint_as_float(u&0x7fffffffu) : __uint_as_float(~u); }

__device__ __forceinline__ void async_lds16(u16* lds, const u16* g){
  __builtin_amdgcn_global_load_lds((const __attribute__((address_space(1))) void*)g,
                                   (__attribute__((address_space(3))) void*)lds,
                                   16, 0, 0);
}

// stage ROWS x 64 bf16 from global into LDS padded to 72/row
template<int ROWS>
__device__ __forceinline__ void stage64(u16* dst, const u16* src, int srcStride, int tid){
  #pragma unroll
  for (int u=tid; u<ROWS*8; u+=256){
    int r=u>>3, c=(u&7)<<3;
    *(int4*)&dst[r*72+c] = *(const int4*)&src[(size_t)r*srcStride + c];
  }
}

// ---------------- setup: weight transposes (blocks 0..1023) + init/cast (blocks 1024..1279) ----------------
__global__ __launch_bounds__(256) void k_setup(u32* kmaxEnc, u16* projS,
    const float* __restrict__ proj, const float* __restrict__ x, u16* __restrict__ xb,
    const float* s0, const float* s1, const float* s2, const float* s3,
    u16* d0, u16* d1, u16* d2, u16* d3)
{
  int bid=blockIdx.x, tid=threadIdx.x;
  if (bid < 1024){
    int z = bid>>8, t = bid&255;
    const float* src = z==0?s0:(z==1?s1:(z==2?s2:s3));
    u16* dst         = z==0?d0:(z==1?d1:(z==2?d2:d3));
    __shared__ u16 tl[32][34];
    int c0=(t&15)*32, r0=(t>>4)*32;
    for (int u=tid; u<1024; u+=256){ int r=u>>5, c=u&31; tl[r][c]=f2bf(src[(size_t)(r0+r)*512 + c0+c]); }
    __syncthreads();
    for (int u=tid; u<1024; u+=256){ int c=u>>5, r=u&31; dst[(size_t)(c0+c)*512 + r0+r]=tl[r][c]; }
  } else {
    int i = (bid-1024)*256 + tid;
    int st = 256*256;
    for (int j=i; j<32; j+=st) kmaxEnc[j]=0u;
    const float dn = 0.35355339059327373f; // 64^-0.25
    for (int j=i; j<512*64; j+=st) projS[j] = f2bf(dn*proj[j]);
    for (int j=i; j<524288; j+=st){
      float4 a = *(const float4*)&x[(size_t)j*8];
      float4 b = *(const float4*)&x[(size_t)j*8+4];
      u16 tmp[8] = {f2bf(a.x),f2bf(a.y),f2bf(a.z),f2bf(a.w),
                    f2bf(b.x),f2bf(b.y),f2bf(b.z),f2bf(b.w)};
      *(int4*)&xb[(size_t)j*8] = *(const int4*)tmp;
    }
  }
}

// ---------------- prep: trv (0..4095) + vsum (4096..4127) + kdiag (4128..4383) ----------------
__global__ __launch_bounds__(256) void k_prep(const u16* __restrict__ vB, u16* __restrict__ vT,
    float* __restrict__ vsum, const u16* __restrict__ kB, float* __restrict__ diagK)
{
  int bid=blockIdx.x, tid=threadIdx.x;
  if (bid < 4096){
    int xx=bid&1, y=(bid>>1)&63, bh=bid>>7;
    int b=bh>>3, h=bh&7;
    int dd0=xx*32, n0=y*32;
    __shared__ u16 t[32][34];
    const u16* s = vB + (size_t)(b*2048)*512 + h*64;
    for (int u=tid; u<1024; u+=256){ int r=u>>5, c=u&31; t[r][c]=s[(size_t)(n0+r)*512 + dd0+c]; }
    __syncthreads();
    u16* d = vT + (size_t)bh*64*2048;
    for (int u=tid; u<1024; u+=256){ int c=u>>5, r=u&31; d[(size_t)(dd0+c)*2048 + n0+r]=t[r][c]; }
  } else if (bid < 4128){
    int bh=bid-4096; int b=bh>>3, h=bh&7;
    int d=tid&63, part=tid>>6;
    const u16* src = vB + (size_t)(b*2048 + part*512)*512 + h*64 + d;
    float s=0.f;
    for (int n=0;n<512;++n) s += bf2f(src[(size_t)n*512]);
    __shared__ float red[256];
    red[tid]=s; __syncthreads();
    if (part==0) vsum[bh*64+d]=red[d]+red[64+d]+red[128+d]+red[192+d];
  } else {
    int idx=bid-4128;
    int bh=idx&31, seg=idx>>5;
    int b=bh>>3, h=bh&7;
    int part=tid&7;
    const u16* base = kB + (size_t)(b*2048 + seg*256)*512 + h*64 + part*8;
    for (int n0=0; n0<256; n0+=32){
      int n = n0 + (tid>>3);
      bf16x8 v = *(const bf16x8*)&base[(size_t)n*512];
      float sq=0.f;
      #pragma unroll
      for (int j=0;j<8;++j){ float f=bf2f((u16)v[j]); sq+=f*f; }
      sq += __shfl_xor(sq,1,64); sq += __shfl_xor(sq,2,64); sq += __shfl_xor(sq,4,64);
      if (part==0) diagK[(size_t)bh*2048 + seg*256 + n] = 0.0625f*sq;
    }
  }
}

// ---------------- GEMM m97-style + T2 swizzle (pre-swizzled source, XOR reads) ----------------
template<bool OF32>
__global__ __launch_bounds__(256) void k_gemm2(const u16* __restrict__ A,
    const u16* BT0, const u16* BT1, const u16* BT2,
    const float* b0, const float* b1, const float* b2,
    void* O0, void* O1, void* O2)
{
  int z = blockIdx.z;
  const u16* BT    = z==0?BT0:(z==1?BT1:BT2);
  const float* bias= z==0?b0 :(z==1?b1 :b2 );
  void* Ov         = z==0?O0 :(z==1?O1 :O2 );
  int bm = blockIdx.x*128, bn = blockIdx.y*64;
  __shared__ u16 sA[128*64];
  __shared__ u16 sB[64*64];
  int tid=threadIdx.x, w=tid>>6, lane=tid&63;
  int lr = lane>>3;
  int lgl = ((lane&7)^lr)*8;          // swizzled source granule (elems); involution g ^= row&7
  f32x4 acc[8] = {};
  for (int kk=0; kk<512; kk+=64){
    __syncthreads();
    #pragma unroll
    for (int i=0;i<4;++i){
      int idx = w*4+i;
      async_lds16(&sA[idx*512], A + (size_t)(bm + idx*8 + lr)*512 + kk + lgl);
    }
    #pragma unroll
    for (int i=0;i<2;++i){
      int idx = w*2+i;
      async_lds16(&sB[idx*512], BT + (size_t)(bn + idx*8 + lr)*512 + kk + lgl);
    }
    __syncthreads();
    int fr = lane&15, kbg=lane>>4, kb=kbg*8;
    int sw = fr&7;                    // read-side XOR key = row&7 (rows are 16*const + fr)
    #pragma unroll
    for (int rt=0; rt<2; ++rt){
      int ar = (w*2+rt)*16 + fr;
      #pragma unroll
      for (int ct=0; ct<4; ++ct){
        int br = ct*16 + fr;
        #pragma unroll
        for (int kc=0; kc<2; ++kc){
          bf16x8 av = *(const bf16x8*)&sA[ar*64 + (((kc*4+kbg)^sw)<<3)];
          bf16x8 bv = *(const bf16x8*)&sB[br*64 + (((kc*4+kbg)^sw)<<3)];
          acc[rt*4+ct] = MFMA16(av,bv,acc[rt*4+ct]);
        }
      }
    }
  }
  int colg = lane&15, rowg=(lane>>4)*4;
  #pragma unroll
  for (int rt=0; rt<2; ++rt){
    #pragma unroll
    for (int ct=0; ct<4; ++ct){
      int col = bn + ct*16 + colg;
      float bv = bias[col];
      #pragma unroll
      for (int j=0;j<4;++j){
        int row = bm + (w*2+rt)*16 + rowg + j;
        if constexpr (OF32) ((float*)Ov)[(size_t)row*512 + col] = acc[rt*4+ct][j] + bv;
        else                ((u16*) Ov)[(size_t)row*512 + col] = f2bf(acc[rt*4+ct][j] + bv);
      }
    }
  }
}

// ---------------- k features + quarter-n ctx partial: qpout3-style schedule (round-17 proven) ----------------
__global__ __launch_bounds__(256) void k_kpctx6(const u16* __restrict__ kB, const u16* __restrict__ projS,
    const u16* __restrict__ vT, const float* __restrict__ diagK,
    float* __restrict__ ctxPT, float* __restrict__ kcsP, u32* __restrict__ kmaxEnc)
{
  int h=blockIdx.x, y=blockIdx.y, b=blockIdx.z;
  int mblk = y&7, s = y>>3;
  int bh=b*8+h;
  int m0 = mblk*64;
  __shared__ __align__(16) u16 sP[64*72];
  __shared__ __align__(16) u16 poolKV[3*4096];
  __shared__ __align__(16) u16 sT[64*72];
  __shared__ float sRed[4][64];
  __shared__ float red[4];
  u16* sK0 = poolKV;
  u16* sK1 = poolKV + 4096;
  u16* sV  = poolKV + 8192;
  int tid=threadIdx.x, w=tid>>6, lane=tid&63;
  int fr=lane&15, kbg=lane>>4, kb=kbg*8, rowg=kbg*4;
  int lr=lane>>3, lgl=((lane&7)^lr)*8;
  int sw=fr&7;
  const u16* gK = kB + (size_t)(b*2048 + s*512)*512 + h*64;
  const u16* gV = vT + (size_t)bh*64*2048 + s*512;
  const float* gD = diagK + (size_t)bh*2048 + s*512 + w*16 + rowg;
  stage64<64>(sP, projS + m0*64, 64, tid);
  float4 pD[8];
  #pragma unroll
  for (int mc=0;mc<8;++mc) pD[mc] = *(const float4*)&gD[mc*64];
  #pragma unroll
  for (int i=0;i<2;++i){
    int idx = w*2+i;
    async_lds16(&sK0[idx*512], gK + (size_t)(idx*8+lr)*512 + lgl);
  }
  f32x4 accc[4]={};
  float sSm[4]={0.f,0.f,0.f,0.f};
  float lm=-3.0e38f;
  SOFT_BAR_VM(0);
  #pragma unroll
  for (int mc=0; mc<8; ++mc){
    u16* sKc = (mc&1) ? sK1 : sK0;
    u16* sKn = (mc&1) ? sK0 : sK1;
    #pragma unroll
    for (int i=0;i<2;++i){
      int idx = w*2+i;
      async_lds16(&sV[idx*512], gV + (size_t)(idx*8+lr)*2048 + mc*64 + lgl);
    }
    if (mc<7){
      #pragma unroll
      for (int i=0;i<2;++i){
        int idx = w*2+i;
        async_lds16(&sKn[idx*512], gK + (size_t)((mc+1)*64 + idx*8+lr)*512 + lgl);
      }
    }
    int ar = w*16 + fr;
    f32x4 facc[4];
    #pragma unroll
    for (int mt=0;mt<4;++mt){
      f32x4 a={0.f,0.f,0.f,0.f};
      #pragma unroll
      for (int kc=0;kc<2;++kc){
        bf16x8 av = *(const bf16x8*)&sKc[ar*64 + (((kc*4+kbg)^sw)<<3)];
        bf16x8 bv = *(const bf16x8*)&sP[(mt*16+fr)*72 + kc*32 + kb];
        a = MFMA16(av,bv,a);
      }
      facc[mt]=a;
      lm=fmaxf(lm, fmaxf(fmaxf(a[0],a[1]),fmaxf(a[2],a[3])));
    }
    {
      int nl = w*16 + rowg;
      #pragma unroll
      for (int mt=0;mt<4;++mt){
        int ml=mt*16+fr;
        s16x4 pk;
        #pragma unroll
        for (int j=0;j<4;++j){
          float vk = __expf(facc[mt][j]-pD[mc][j]);
          u16 us = f2bf(vk);
          pk[j]=(short)us;
          sSm[mt] += bf2f(us);
        }
        *(s16x4*)&sT[ml*72+nl]=pk;
      }
      (void)nl;
    }
    if (mc<7) { SOFT_BAR_VM(2); } else { SOFT_BAR_VM(0); }
    {
      int am=w*16+fr;
      #pragma unroll
      for (int ct=0;ct<4;++ct){
        #pragma unroll
        for (int kc=0;kc<2;++kc){
          bf16x8 av = *(const bf16x8*)&sT[am*72 + kc*32 + kb];
          bf16x8 bv = *(const bf16x8*)&sV[(ct*16+fr)*64 + (((kc*4+kbg)^sw)<<3)];
          accc[ct] = MFMA16(av,bv,accc[ct]);
        }
      }
    }
    if (mc<7) { SOFT_BAR_VM(0); }
  }
  __syncthreads();
  #pragma unroll
  for (int mt=0;mt<4;++mt){
    float t=sSm[mt];
    t += __shfl_xor(t,16,64); t += __shfl_xor(t,32,64);
    if (kbg==0) sRed[w][mt*16+fr]=t;
  }
  #pragma unroll
  for (int m2=1;m2<64;m2<<=1) lm=fmaxf(lm,__shfl_xor(lm,m2,64));
  if (lane==0) red[w]=lm;
  float* sTf = (float*)poolKV;
  int mloc = w*16+rowg;
  #pragma unroll
  for (int ct=0;ct<4;++ct){
    #pragma unroll
    for (int j=0;j<4;++j) sTf[(ct*16+fr)*68 + mloc + j] = accc[ct][j];
  }
  __syncthreads();
  if (tid==0) atomicMax(&kmaxEnc[bh], encf(fmaxf(fmaxf(red[0],red[1]),fmaxf(red[2],red[3]))));
  if (tid<64) kcsP[(size_t)(s*32+bh)*512 + m0 + tid] =
      sRed[0][tid]+sRed[1][tid]+sRed[2][tid]+sRed[3][tid];
  for (int u=tid; u<1024; u+=256){
    int r=u>>4, c=(u&15)*4;
    *(float4*)&ctxPT[((size_t)(s*32+bh)*64 + r)*512 + m0 + c] = *(const float4*)&sTf[r*68+c];
  }
}

// ---------------- combine 4 split-n partials -> ctxT bf16 + kcs, fused ctxsum/kcssum ----------------
__global__ __launch_bounds__(256) void k_comb4(const float* __restrict__ ctxPT, u16* __restrict__ ctxT,
    const float* __restrict__ kcsP, float* __restrict__ kcs,
    float* __restrict__ ctxsum, float* __restrict__ kcssum)
{
  int bh=blockIdx.x, dblk=blockIdx.y;
  int tid=threadIdx.x;
  int d0=dblk*8;
  __shared__ float sDsum[8];
  __shared__ float sKsum[256];
  if (tid<8) sDsum[tid]=0.f;
  __syncthreads();
  u16* o = ctxT + ((size_t)bh*64 + d0)*512;
  for (int u=tid; u<1024; u+=256){
    int r=u>>7, c=(u&127)*4;
    float4 a={0.f,0.f,0.f,0.f};
    #pragma unroll
    for (int s=0;s<4;++s){
      float4 p=*(const float4*)&ctxPT[((size_t)(s*32+bh)*64 + d0+r)*512 + c];
      a.x+=p.x; a.y+=p.y; a.z+=p.z; a.w+=p.w;
    }
    u16 t[4]={f2bf(a.x),f2bf(a.y),f2bf(a.z),f2bf(a.w)};
    *(int2*)&o[(size_t)r*512+c] = *(const int2*)t;
    atomicAdd(&sDsum[r], bf2f(t[0])+bf2f(t[1])+bf2f(t[2])+bf2f(t[3]));
  }
  float tpart=0.f;
  if (dblk==0){
    for (int u=tid; u<512; u+=256){
      float t=0.f;
      #pragma unroll
      for (int s=0;s<4;++s) t += kcsP[(size_t)(s*32+bh)*512+u];
      kcs[(size_t)bh*512+u]=t;
      tpart += t;
    }
  }
  sKsum[tid]=tpart;
  __syncthreads();
  if (tid<8) ctxsum[bh*64 + d0 + tid] = sDsum[tid];
  if (dblk==0 && tid<64){
    float a=sKsum[tid]+sKsum[tid+64]+sKsum[tid+128]+sKsum[tid+192];
    #pragma unroll
    for (int m2=1;m2<64;m2<<=1) a += __shfl_xor(a,m2,64);
    if (tid==0) kcssum[bh]=a;
  }
}

// ---------------- q features + PV + eps epilogue: 64 rows/block, swizzled LDS (round-16 proven) ----------------
__global__ __launch_bounds__(256) void k_qpout3(const u16* __restrict__ qB, const u16* __restrict__ projS,
    const float* __restrict__ kcs, const u16* __restrict__ ctxT,
    const float* __restrict__ ctxsum, const float* __restrict__ kcssum,
    const float* __restrict__ vsum, const u32* __restrict__ kmaxEnc,
    u16* __restrict__ outc)
{
  int h=blockIdx.x, chunk=blockIdx.y, b=blockIdx.z;
  int bh=b*8+h;
  int t0 = b*2048 + chunk*64;
  __shared__ u16 sP[2][64*64];
  __shared__ u16 sCt[64*64];
  __shared__ u16 qpL[64*72];
  __shared__ float sK[512];
  __shared__ float diag[64];
  int tid=threadIdx.x, w=tid>>6, lane=tid&63;
  int fr=lane&15, kbg=lane>>4, kb=kbg*8, rowg=kbg*4;
  int lr=lane>>3, lgl=((lane&7)^lr)*8;
  int sw=fr&7;
  bf16x8 qf[2];
  #pragma unroll
  for (int kc=0;kc<2;++kc)
    qf[kc] = *(const bf16x8*)&qB[(size_t)(t0 + w*16 + fr)*512 + h*64 + kc*32 + kb];
  {
    float ssum=0.f;
    #pragma unroll
    for (int kc=0;kc<2;++kc)
      #pragma unroll
      for (int j=0;j<8;++j){ float f=bf2f((u16)qf[kc][j]); ssum+=f*f; }
    ssum += __shfl_xor(ssum,16,64); ssum += __shfl_xor(ssum,32,64);
    if (lane<16) diag[w*16 + fr] = 0.0625f*ssum;
  }
  for (int u=tid; u<512; u+=256) sK[u] = kcs[(size_t)bh*512 + u];
  const u16* gcB = ctxT + (size_t)bh*64*512;
  #pragma unroll
  for (int i=0;i<2;++i){
    int idx = w*2+i;
    async_lds16(&sP[0][idx*512], projS + (size_t)(idx*8+lr)*64 + lgl);
  }
  f32x4 acc2[4]={};
  float mx[4], dp[4], rs[4];
  #pragma unroll
  for (int j=0;j<4;++j){ mx[j]=-3.0e38f; dp[j]=0.f; rs[j]=0.f; }
  SOFT_BAR_VM(0);
  for (int mc=0; mc<8; ++mc){
    int cur = mc&1;
    #pragma unroll
    for (int i=0;i<2;++i){
      int idx = w*2+i;
      async_lds16(&sCt[idx*512], gcB + (size_t)(idx*8+lr)*512 + mc*64 + lgl);
    }
    if (mc<7){
      const u16* gp = projS + (mc+1)*64*64;
      #pragma unroll
      for (int i=0;i<2;++i){
        int idx = w*2+i;
        async_lds16(&sP[cur^1][idx*512], gp + (size_t)(idx*8+lr)*64 + lgl);
      }
    }
    f32x4 facc[4];
    #pragma unroll
    for (int mt=0;mt<4;++mt){
      f32x4 a={0.f,0.f,0.f,0.f};
      #pragma unroll
      for (int kc=0;kc<2;++kc){
        bf16x8 bv = *(const bf16x8*)&sP[cur][(mt*16+fr)*64 + (((kc*4+kbg)^sw)<<3)];
        a = MFMA16(qf[kc], bv, a);
      }
      facc[mt]=a;
    }
    #pragma unroll
    for (int mt=0;mt<4;++mt){
      #pragma unroll
      for (int j=0;j<4;++j){
        int rl = w*16 + rowg + j;
        mx[j] = fmaxf(mx[j], facc[mt][j]);
        float vq = __expf(facc[mt][j] - diag[rl]);
        u16 us = f2bf(vq);
        qpL[rl*72 + mt*16 + fr] = us;
        float uf = bf2f(us);
        dp[j] += uf*sK[mc*64 + mt*16 + fr];
        rs[j] += uf;
      }
    }
    if (mc<7) { SOFT_BAR_VM(2); } else { SOFT_BAR_VM(0); }
    #pragma unroll
    for (int ct=0;ct<4;++ct){
      #pragma unroll
      for (int kc=0;kc<2;++kc){
        bf16x8 av = *(const bf16x8*)&qpL[(w*16+fr)*72 + kc*32 + kb];
        bf16x8 bv = *(const bf16x8*)&sCt[(ct*16+fr)*64 + (((kc*4+kbg)^sw)<<3)];
        acc2[ct] = MFMA16(av,bv,acc2[ct]);
      }
    }
    if (mc<7) { SOFT_BAR_VM(0); }
  }
  #pragma unroll
  for (int j=0;j<4;++j){
    #pragma unroll
    for (int s=1;s<16;s<<=1){
      dp[j] += __shfl_xor(dp[j],s,64);
      rs[j] += __shfl_xor(rs[j],s,64);
      mx[j]  = fmaxf(mx[j], __shfl_xor(mx[j],s,64));
    }
  }
  float mk  = decf(kmaxEnc[bh]);
  float emk = __expf(mk);
  float Ssum = kcssum[bh];
  const float eps=1e-4f;
  float emq[4];
  #pragma unroll
  for (int j=0;j<4;++j) emq[j]=__expf(mx[j]);
  #pragma unroll
  for (int ct=0;ct<4;++ct){
    int d = ct*16 + fr;
    float cs = ctxsum[bh*64 + d];
    float vs = vsum[bh*64 + d];
    #pragma unroll
    for (int j=0;j<4;++j){
      float eq = emq[j];
      float numer = acc2[ct][j] + eps*(emk*vs*rs[j] + eq*cs + eps*eq*emk*512.0f*vs);
      float den   = dp[j]       + eps*(emk*2048.0f*rs[j] + eq*Ssum + eps*eq*emk*512.0f*2048.0f);
      int row = t0 + w*16 + rowg + j;
      outc[(size_t)row*512 + h*64 + d] = f2bf(numer/den);
    }
  }
}

extern "C" void kernel_launch(void* const* d_in, const int* in_sizes, int n_in,
                              void* d_out, int out_size, void* d_ws, size_t ws_size,
                              hipStream_t stream)
{
  (void)in_sizes; (void)n_in; (void)out_size; (void)ws_size;
  const float* x    = (const float*)d_in[0];
  const float* Wq   = (const float*)d_in[1];
  const float* bq   = (const float*)d_in[2];
  const float* Wk   = (const float*)d_in[3];
  const float* bk   = (const float*)d_in[4];
  const float* Wv   = (const float*)d_in[5];
  const float* bv   = (const float*)d_in[6];
  const float* Wo   = (const float*)d_in[7];
  const float* bo   = (const float*)d_in[8];
  const float* proj = (const float*)d_in[9];

  char* w = (char*)d_ws;
  size_t off=0;
  auto alloc=[&](size_t bytes)->char*{ char* p=w+off; off=(off+bytes+255)&~(size_t)255; return p; };
  u16*  xb   = (u16*)alloc(8192ull*512*2);
  u16*  qB   = (u16*)alloc(8192ull*512*2);
  u16*  kBf  = (u16*)alloc(8192ull*512*2);
  u16*  vB   = (u16*)alloc(8192ull*512*2);
  u16*  vT   = (u16*)alloc(32ull*64*2048*2);
  u16*  WqT  = (u16*)alloc(512ull*512*2);
  u16*  WkT  = (u16*)alloc(512ull*512*2);
  u16*  WvT  = (u16*)alloc(512ull*512*2);
  u16*  WoT  = (u16*)alloc(512ull*512*2);
  u16*  projS= (u16*)alloc(512ull*64*2);
  u16*  ctxT = (u16*)alloc(32ull*64*512*2);
  float* ctxPT=(float*)alloc(4ull*32*64*512*4);
  float* kcs = (float*)alloc(32ull*512*4);
  float* kcsP= (float*)alloc(4ull*32*512*4);
  float* diagK=(float*)alloc(32ull*2048*4);
  u32*  kmx  = (u32*)alloc(256);
  float* ctxs= (float*)alloc(32ull*64*4);
  float* kcss= (float*)alloc(32ull*4);
  float* vsm = (float*)alloc(32ull*64*4);
  u16*  outc = kBf;  // kBf dead after k_kpctx6; reuse

  dim3 TB(256);
  k_setup<<<dim3(1280),TB,0,stream>>>(kmx,projS,proj,x,xb, Wq,Wk,Wv,Wo, WqT,WkT,WvT,WoT);
  k_gemm2<false><<<dim3(64,8,3),TB,0,stream>>>(xb, WqT,WkT,WvT, bq,bk,bv, qB,kBf,vB);
  k_prep<<<dim3(4384),TB,0,stream>>>(vB, vT, vsm, kBf, diagK);
  k_kpctx6<<<dim3(8,32,4),TB,0,stream>>>(kBf, projS, vT, diagK, ctxPT, kcsP, kmx);
  k_comb4<<<dim3(32,8),TB,0,stream>>>(ctxPT, ctxT, kcsP, kcs, ctxs, kcss);
  k_qpout3<<<dim3(8,32,4),TB,0,stream>>>(qB, projS, kcs, ctxT, ctxs, kcss, vsm, kmx, outc);
  k_gemm2<true><<<dim3(64,8,1),TB,0,stream>>>(outc, WoT,WoT,WoT, bo,bo,bo,
                                              d_out,d_out,d_out);
}

// Round 19
// 126.269 us; speedup vs baseline: 1.2838x; 1.0013x over previous
//
#include <hip/hip_runtime.h>

typedef unsigned short u16;
typedef unsigned int   u32;
typedef __attribute__((ext_vector_type(8))) short bf16x8;
typedef __attribute__((ext_vector_type(4))) short s16x4;
typedef __attribute__((ext_vector_type(4))) float f32x4;

#define MFMA16(a,b,c) __builtin_amdgcn_mfma_f32_16x16x32_bf16((a),(b),(c),0,0,0)

// soft barriers: raw s_barrier + counted waits
#define SOFT_BAR_LG() do{ asm volatile("s_waitcnt lgkmcnt(0)" ::: "memory"); \
  __builtin_amdgcn_s_barrier(); __builtin_amdgcn_sched_barrier(0); }while(0)
#define SOFT_BAR_VM(N) do{ asm volatile("s_waitcnt vmcnt(" #N ") lgkmcnt(0)" ::: "memory"); \
  __builtin_amdgcn_s_barrier(); __builtin_amdgcn_sched_barrier(0); }while(0)

__device__ __forceinline__ float bf2f(u16 u){ return __uint_as_float(((u32)u)<<16); }
__device__ __forceinline__ u16 f2bf(float f){
  u32 u = __float_as_uint(f);
  return (u16)((u + 0x7fffu + ((u>>16)&1u)) >> 16);
}
__device__ __forceinline__ u32 encf(float f){ u32 u=__float_as_uint(f); return (u&0x80000000u)? ~u : (u|0x80000000u); }
__device__ __forceinline__ float decf(u32 u){ return (u&0x80000000u)? __uint_as_float(u&0x7fffffffu) : __uint_as_float(~u); }

__device__ __forceinline__ void async_lds16(u16* lds, const u16* g){
  __builtin_amdgcn_global_load_lds((const __attribute__((address_space(1))) void*)g,
                                   (__attribute__((address_space(3))) void*)lds,
                                   16, 0, 0);
}

// stage ROWS x 64 bf16 from global into LDS padded to 72/row
template<int ROWS>
__device__ __forceinline__ void stage64(u16* dst, const u16* src, int srcStride, int tid){
  #pragma unroll
  for (int u=tid; u<ROWS*8; u+=256){
    int r=u>>3, c=(u&7)<<3;
    *(int4*)&dst[r*72+c] = *(const int4*)&src[(size_t)r*srcStride + c];
  }
}

// ---------------- setup: weight transposes (blocks 0..1023) + init/cast (blocks 1024..1279) ----------------
__global__ __launch_bounds__(256) void k_setup(u32* kmaxEnc, u16* projS,
    const float* __restrict__ proj, const float* __restrict__ x, u16* __restrict__ xb,
    const float* s0, const float* s1, const float* s2, const float* s3,
    u16* d0, u16* d1, u16* d2, u16* d3)
{
  int bid=blockIdx.x, tid=threadIdx.x;
  if (bid < 1024){
    int z = bid>>8, t = bid&255;
    const float* src = z==0?s0:(z==1?s1:(z==2?s2:s3));
    u16* dst         = z==0?d0:(z==1?d1:(z==2?d2:d3));
    __shared__ u16 tl[32][34];
    int c0=(t&15)*32, r0=(t>>4)*32;
    for (int u=tid; u<1024; u+=256){ int r=u>>5, c=u&31; tl[r][c]=f2bf(src[(size_t)(r0+r)*512 + c0+c]); }
    __syncthreads();
    for (int u=tid; u<1024; u+=256){ int c=u>>5, r=u&31; dst[(size_t)(c0+c)*512 + r0+r]=tl[r][c]; }
  } else {
    int i = (bid-1024)*256 + tid;
    int st = 256*256;
    for (int j=i; j<32; j+=st) kmaxEnc[j]=0u;
    const float dn = 0.35355339059327373f; // 64^-0.25
    for (int j=i; j<512*64; j+=st) projS[j] = f2bf(dn*proj[j]);
    for (int j=i; j<524288; j+=st){
      float4 a = *(const float4*)&x[(size_t)j*8];
      float4 b = *(const float4*)&x[(size_t)j*8+4];
      u16 tmp[8] = {f2bf(a.x),f2bf(a.y),f2bf(a.z),f2bf(a.w),
                    f2bf(b.x),f2bf(b.y),f2bf(b.z),f2bf(b.w)};
      *(int4*)&xb[(size_t)j*8] = *(const int4*)tmp;
    }
  }
}

// ---------------- prep: trv (0..4095) + vsum (4096..4127) + kdiag (4128..4383) ----------------
__global__ __launch_bounds__(256) void k_prep(const u16* __restrict__ vB, u16* __restrict__ vT,
    float* __restrict__ vsum, const u16* __restrict__ kB, float* __restrict__ diagK)
{
  int bid=blockIdx.x, tid=threadIdx.x;
  if (bid < 4096){
    int xx=bid&1, y=(bid>>1)&63, bh=bid>>7;
    int b=bh>>3, h=bh&7;
    int dd0=xx*32, n0=y*32;
    __shared__ u16 t[32][34];
    const u16* s = vB + (size_t)(b*2048)*512 + h*64;
    for (int u=tid; u<1024; u+=256){ int r=u>>5, c=u&31; t[r][c]=s[(size_t)(n0+r)*512 + dd0+c]; }
    __syncthreads();
    u16* d = vT + (size_t)bh*64*2048;
    for (int u=tid; u<1024; u+=256){ int c=u>>5, r=u&31; d[(size_t)(dd0+c)*2048 + n0+r]=t[r][c]; }
  } else if (bid < 4128){
    int bh=bid-4096; int b=bh>>3, h=bh&7;
    int d=tid&63, part=tid>>6;
    const u16* src = vB + (size_t)(b*2048 + part*512)*512 + h*64 + d;
    float s=0.f;
    for (int n=0;n<512;++n) s += bf2f(src[(size_t)n*512]);
    __shared__ float red[256];
    red[tid]=s; __syncthreads();
    if (part==0) vsum[bh*64+d]=red[d]+red[64+d]+red[128+d]+red[192+d];
  } else {
    int idx=bid-4128;
    int bh=idx&31, seg=idx>>5;
    int b=bh>>3, h=bh&7;
    int part=tid&7;
    const u16* base = kB + (size_t)(b*2048 + seg*256)*512 + h*64 + part*8;
    for (int n0=0; n0<256; n0+=32){
      int n = n0 + (tid>>3);
      bf16x8 v = *(const bf16x8*)&base[(size_t)n*512];
      float sq=0.f;
      #pragma unroll
      for (int j=0;j<8;++j){ float f=bf2f((u16)v[j]); sq+=f*f; }
      sq += __shfl_xor(sq,1,64); sq += __shfl_xor(sq,2,64); sq += __shfl_xor(sq,4,64);
      if (part==0) diagK[(size_t)bh*2048 + seg*256 + n] = 0.0625f*sq;
    }
  }
}

// ---------------- GEMM m97-style + T2 swizzle (round-18 proven) ----------------
template<bool OF32>
__global__ __launch_bounds__(256) void k_gemm2(const u16* __restrict__ A,
    const u16* BT0, const u16* BT1, const u16* BT2,
    const float* b0, const float* b1, const float* b2,
    void* O0, void* O1, void* O2)
{
  int z = blockIdx.z;
  const u16* BT    = z==0?BT0:(z==1?BT1:BT2);
  const float* bias= z==0?b0 :(z==1?b1 :b2 );
  void* Ov         = z==0?O0 :(z==1?O1 :O2 );
  int bm = blockIdx.x*128, bn = blockIdx.y*64;
  __shared__ u16 sA[128*64];
  __shared__ u16 sB[64*64];
  int tid=threadIdx.x, w=tid>>6, lane=tid&63;
  int lr = lane>>3;
  int lgl = ((lane&7)^lr)*8;          // swizzled source granule; involution g ^= row&7
  f32x4 acc[8] = {};
  for (int kk=0; kk<512; kk+=64){
    __syncthreads();
    #pragma unroll
    for (int i=0;i<4;++i){
      int idx = w*4+i;
      async_lds16(&sA[idx*512], A + (size_t)(bm + idx*8 + lr)*512 + kk + lgl);
    }
    #pragma unroll
    for (int i=0;i<2;++i){
      int idx = w*2+i;
      async_lds16(&sB[idx*512], BT + (size_t)(bn + idx*8 + lr)*512 + kk + lgl);
    }
    __syncthreads();
    int fr = lane&15, kbg=lane>>4;
    int sw = fr&7;                    // read-side XOR key
    #pragma unroll
    for (int rt=0; rt<2; ++rt){
      int ar = (w*2+rt)*16 + fr;
      #pragma unroll
      for (int ct=0; ct<4; ++ct){
        int br = ct*16 + fr;
        #pragma unroll
        for (int kc=0; kc<2; ++kc){
          bf16x8 av = *(const bf16x8*)&sA[ar*64 + (((kc*4+kbg)^sw)<<3)];
          bf16x8 bv = *(const bf16x8*)&sB[br*64 + (((kc*4+kbg)^sw)<<3)];
          acc[rt*4+ct] = MFMA16(av,bv,acc[rt*4+ct]);
        }
      }
    }
  }
  int colg = lane&15, rowg=(lane>>4)*4;
  #pragma unroll
  for (int rt=0; rt<2; ++rt){
    #pragma unroll
    for (int ct=0; ct<4; ++ct){
      int col = bn + ct*16 + colg;
      float bv = bias[col];
      #pragma unroll
      for (int j=0;j<4;++j){
        int row = bm + (w*2+rt)*16 + rowg + j;
        if constexpr (OF32) ((float*)Ov)[(size_t)row*512 + col] = acc[rt*4+ct][j] + bv;
        else                ((u16*) Ov)[(size_t)row*512 + col] = f2bf(acc[rt*4+ct][j] + bv);
      }
    }
  }
}

// ---------------- k features + quarter-n ctx partial: sK AND sV double-buffered, rebalanced vmcnt ----------------
// Steady state: A issues sK(mc+1) then sV(mc+1); C waits vmcnt(4) -> retires exactly sV(mc)
// (issued one chunk ago = full-chunk latency cover); E waits vmcnt(2) -> retires exactly sK(mc+1).
__global__ __launch_bounds__(256) void k_kpctx6(const u16* __restrict__ kB, const u16* __restrict__ projS,
    const u16* __restrict__ vT, const float* __restrict__ diagK,
    float* __restrict__ ctxPT, float* __restrict__ kcsP, u32* __restrict__ kmaxEnc)
{
  int h=blockIdx.x, y=blockIdx.y, b=blockIdx.z;
  int mblk = y&7, s = y>>3;
  int bh=b*8+h;
  int m0 = mblk*64;
  __shared__ __align__(16) u16 sP[64*72];
  __shared__ __align__(16) u16 poolKV[4*4096];   // sK0 | sK1 | sV0 | sV1 (linear, swizzled)
  __shared__ __align__(16) u16 sT[64*72];
  __shared__ float sRed[4][64];
  __shared__ float red[4];
  u16* sK0 = poolKV;
  u16* sK1 = poolKV + 4096;
  u16* sV0 = poolKV + 8192;
  u16* sV1 = poolKV + 12288;
  int tid=threadIdx.x, w=tid>>6, lane=tid&63;
  int fr=lane&15, kbg=lane>>4, kb=kbg*8, rowg=kbg*4;
  int lr=lane>>3, lgl=((lane&7)^lr)*8;
  int sw=fr&7;
  const u16* gK = kB + (size_t)(b*2048 + s*512)*512 + h*64;
  const u16* gV = vT + (size_t)bh*64*2048 + s*512;
  const float* gD = diagK + (size_t)bh*2048 + s*512 + w*16 + rowg;
  stage64<64>(sP, projS + m0*64, 64, tid);
  float4 pD[8];
  #pragma unroll
  for (int mc=0;mc<8;++mc) pD[mc] = *(const float4*)&gD[mc*64];
  // prologue: issue sK(0) then sV(0); retire sK(0) (oldest 2), keep sV(0) in flight
  #pragma unroll
  for (int i=0;i<2;++i){
    int idx = w*2+i;
    async_lds16(&sK0[idx*512], gK + (size_t)(idx*8+lr)*512 + lgl);
  }
  #pragma unroll
  for (int i=0;i<2;++i){
    int idx = w*2+i;
    async_lds16(&sV0[idx*512], gV + (size_t)(idx*8+lr)*2048 + lgl);
  }
  f32x4 accc[4]={};
  float sSm[4]={0.f,0.f,0.f,0.f};
  float lm=-3.0e38f;
  SOFT_BAR_VM(2);   // sP (lgkm) + pD retired; sK(0) published; sV(0) flying
  #pragma unroll
  for (int mc=0; mc<8; ++mc){
    u16* sKc = (mc&1) ? sK1 : sK0;
    u16* sKn = (mc&1) ? sK0 : sK1;
    u16* sVc = (mc&1) ? sV1 : sV0;   // NOTE: sV(0) landed in sV0; chunk mc reads sV[(mc)&1]
    u16* sVn = (mc&1) ? sV0 : sV1;
    // fix buffer parity: chunk mc consumes sV[mc&1] — sV(0) is in sV0 => sVc must be sV0 at mc=0
    sVc = (mc&1) ? sV1 : sV0;
    sVn = (mc&1) ? sV0 : sV1;
    // A: issue next chunk's sK then sV
    if (mc<7){
      #pragma unroll
      for (int i=0;i<2;++i){
        int idx = w*2+i;
        async_lds16(&sKn[idx*512], gK + (size_t)((mc+1)*64 + idx*8+lr)*512 + lgl);
      }
      #pragma unroll
      for (int i=0;i<2;++i){
        int idx = w*2+i;
        async_lds16(&sVn[idx*512], gV + (size_t)(idx*8+lr)*2048 + (mc+1)*64 + lgl);
      }
    }
    // B: feature MFMA dd[64 n][64 m] on sK[cur] (published at prior barrier)
    int ar = w*16 + fr;
    f32x4 facc[4];
    #pragma unroll
    for (int mt=0;mt<4;++mt){
      f32x4 a={0.f,0.f,0.f,0.f};
      #pragma unroll
      for (int kc=0;kc<2;++kc){
        bf16x8 av = *(const bf16x8*)&sKc[ar*64 + (((kc*4+kbg)^sw)<<3)];
        bf16x8 bv = *(const bf16x8*)&sP[(mt*16+fr)*72 + kc*32 + kb];
        a = MFMA16(av,bv,a);
      }
      facc[mt]=a;
      lm=fmaxf(lm, fmaxf(fmaxf(a[0],a[1]),fmaxf(a[2],a[3])));
    }
    // exp -> sT[m][n] (padded), S in regs, diag from regs
    {
      int nl = w*16 + rowg;
      #pragma unroll
      for (int mt=0;mt<4;++mt){
        int ml=mt*16+fr;
        s16x4 pk;
        #pragma unroll
        for (int j=0;j<4;++j){
          float vk = __expf(facc[mt][j]-pD[mc][j]);
          u16 us = f2bf(vk);
          pk[j]=(short)us;
          sSm[mt] += bf2f(us);
        }
        *(s16x4*)&sT[ml*72+nl]=pk;
      }
      (void)nl;
    }
    // C: retire sV(mc) (oldest 2 of 6), keep sK(mc+1)+sV(mc+1) flying; publish sT
    if (mc<7) { SOFT_BAR_VM(4); } else { SOFT_BAR_VM(0); }
    // D: PV: ctx[m][d] += sT[m][n] @ sV[d][n]^T
    {
      int am=w*16+fr;
      #pragma unroll
      for (int ct=0;ct<4;++ct){
        #pragma unroll
        for (int kc=0;kc<2;++kc){
          bf16x8 av = *(const bf16x8*)&sT[am*72 + kc*32 + kb];
          bf16x8 bv = *(const bf16x8*)&sVc[(ct*16+fr)*64 + (((kc*4+kbg)^sw)<<3)];
          accc[ct] = MFMA16(av,bv,accc[ct]);
        }
      }
    }
    // E: retire sK(mc+1) (oldest 2 of 4), keep sV(mc+1) flying; protects sT overwrite
    if (mc<7) { SOFT_BAR_VM(2); }
  }
  __syncthreads();
  #pragma unroll
  for (int mt=0;mt<4;++mt){
    float t=sSm[mt];
    t += __shfl_xor(t,16,64); t += __shfl_xor(t,32,64);
    if (kbg==0) sRed[w][mt*16+fr]=t;
  }
  #pragma unroll
  for (int m2=1;m2<64;m2<<=1) lm=fmaxf(lm,__shfl_xor(lm,m2,64));
  if (lane==0) red[w]=lm;
  float* sTf = (float*)poolKV;   // 64*68*4 = 17408B <= 32768B
  int mloc = w*16+rowg;
  #pragma unroll
  for (int ct=0;ct<4;++ct){
    #pragma unroll
    for (int j=0;j<4;++j) sTf[(ct*16+fr)*68 + mloc + j] = accc[ct][j];
  }
  __syncthreads();
  if (tid==0) atomicMax(&kmaxEnc[bh], encf(fmaxf(fmaxf(red[0],red[1]),fmaxf(red[2],red[3]))));
  if (tid<64) kcsP[(size_t)(s*32+bh)*512 + m0 + tid] =
      sRed[0][tid]+sRed[1][tid]+sRed[2][tid]+sRed[3][tid];
  for (int u=tid; u<1024; u+=256){
    int r=u>>4, c=(u&15)*4;
    *(float4*)&ctxPT[((size_t)(s*32+bh)*64 + r)*512 + m0 + c] = *(const float4*)&sTf[r*68+c];
  }
}

// ---------------- combine 4 split-n partials -> ctxT bf16 + kcs, fused ctxsum/kcssum ----------------
__global__ __launch_bounds__(256) void k_comb4(const float* __restrict__ ctxPT, u16* __restrict__ ctxT,
    const float* __restrict__ kcsP, float* __restrict__ kcs,
    float* __restrict__ ctxsum, float* __restrict__ kcssum)
{
  int bh=blockIdx.x, dblk=blockIdx.y;
  int tid=threadIdx.x;
  int d0=dblk*8;
  __shared__ float sDsum[8];
  __shared__ float sKsum[256];
  if (tid<8) sDsum[tid]=0.f;
  __syncthreads();
  u16* o = ctxT + ((size_t)bh*64 + d0)*512;
  for (int u=tid; u<1024; u+=256){
    int r=u>>7, c=(u&127)*4;
    float4 a={0.f,0.f,0.f,0.f};
    #pragma unroll
    for (int s=0;s<4;++s){
      float4 p=*(const float4*)&ctxPT[((size_t)(s*32+bh)*64 + d0+r)*512 + c];
      a.x+=p.x; a.y+=p.y; a.z+=p.z; a.w+=p.w;
    }
    u16 t[4]={f2bf(a.x),f2bf(a.y),f2bf(a.z),f2bf(a.w)};
    *(int2*)&o[(size_t)r*512+c] = *(const int2*)t;
    atomicAdd(&sDsum[r], bf2f(t[0])+bf2f(t[1])+bf2f(t[2])+bf2f(t[3]));
  }
  float tpart=0.f;
  if (dblk==0){
    for (int u=tid; u<512; u+=256){
      float t=0.f;
      #pragma unroll
      for (int s=0;s<4;++s) t += kcsP[(size_t)(s*32+bh)*512+u];
      kcs[(size_t)bh*512+u]=t;
      tpart += t;
    }
  }
  sKsum[tid]=tpart;
  __syncthreads();
  if (tid<8) ctxsum[bh*64 + d0 + tid] = sDsum[tid];
  if (dblk==0 && tid<64){
    float a=sKsum[tid]+sKsum[tid+64]+sKsum[tid+128]+sKsum[tid+192];
    #pragma unroll
    for (int m2=1;m2<64;m2<<=1) a += __shfl_xor(a,m2,64);
    if (tid==0) kcssum[bh]=a;
  }
}

// ---------------- q features + PV + eps epilogue: 64 rows/block, swizzled LDS (round-16 proven) ----------------
__global__ __launch_bounds__(256) void k_qpout3(const u16* __restrict__ qB, const u16* __restrict__ projS,
    const float* __restrict__ kcs, const u16* __restrict__ ctxT,
    const float* __restrict__ ctxsum, const float* __restrict__ kcssum,
    const float* __restrict__ vsum, const u32* __restrict__ kmaxEnc,
    u16* __restrict__ outc)
{
  int h=blockIdx.x, chunk=blockIdx.y, b=blockIdx.z;
  int bh=b*8+h;
  int t0 = b*2048 + chunk*64;
  __shared__ u16 sP[2][64*64];
  __shared__ u16 sCt[64*64];
  __shared__ u16 qpL[64*72];
  __shared__ float sK[512];
  __shared__ float diag[64];
  int tid=threadIdx.x, w=tid>>6, lane=tid&63;
  int fr=lane&15, kbg=lane>>4, kb=kbg*8, rowg=kbg*4;
  int lr=lane>>3, lgl=((lane&7)^lr)*8;
  int sw=fr&7;
  bf16x8 qf[2];
  #pragma unroll
  for (int kc=0;kc<2;++kc)
    qf[kc] = *(const bf16x8*)&qB[(size_t)(t0 + w*16 + fr)*512 + h*64 + kc*32 + kb];
  {
    float ssum=0.f;
    #pragma unroll
    for (int kc=0;kc<2;++kc)
      #pragma unroll
      for (int j=0;j<8;++j){ float f=bf2f((u16)qf[kc][j]); ssum+=f*f; }
    ssum += __shfl_xor(ssum,16,64); ssum += __shfl_xor(ssum,32,64);
    if (lane<16) diag[w*16 + fr] = 0.0625f*ssum;
  }
  for (int u=tid; u<512; u+=256) sK[u] = kcs[(size_t)bh*512 + u];
  const u16* gcB = ctxT + (size_t)bh*64*512;
  #pragma unroll
  for (int i=0;i<2;++i){
    int idx = w*2+i;
    async_lds16(&sP[0][idx*512], projS + (size_t)(idx*8+lr)*64 + lgl);
  }
  f32x4 acc2[4]={};
  float mx[4], dp[4], rs[4];
  #pragma unroll
  for (int j=0;j<4;++j){ mx[j]=-3.0e38f; dp[j]=0.f; rs[j]=0.f; }
  SOFT_BAR_VM(0);
  for (int mc=0; mc<8; ++mc){
    int cur = mc&1;
    #pragma unroll
    for (int i=0;i<2;++i){
      int idx = w*2+i;
      async_lds16(&sCt[idx*512], gcB + (size_t)(idx*8+lr)*512 + mc*64 + lgl);
    }
    if (mc<7){
      const u16* gp = projS + (mc+1)*64*64;
      #pragma unroll
      for (int i=0;i<2;++i){
        int idx = w*2+i;
        async_lds16(&sP[cur^1][idx*512], gp + (size_t)(idx*8+lr)*64 + lgl);
      }
    }
    f32x4 facc[4];
    #pragma unroll
    for (int mt=0;mt<4;++mt){
      f32x4 a={0.f,0.f,0.f,0.f};
      #pragma unroll
      for (int kc=0;kc<2;++kc){
        bf16x8 bv = *(const bf16x8*)&sP[cur][(mt*16+fr)*64 + (((kc*4+kbg)^sw)<<3)];
        a = MFMA16(qf[kc], bv, a);
      }
      facc[mt]=a;
    }
    #pragma unroll
    for (int mt=0;mt<4;++mt){
      #pragma unroll
      for (int j=0;j<4;++j){
        int rl = w*16 + rowg + j;
        mx[j] = fmaxf(mx[j], facc[mt][j]);
        float vq = __expf(facc[mt][j] - diag[rl]);
        u16 us = f2bf(vq);
        qpL[rl*72 + mt*16 + fr] = us;
        float uf = bf2f(us);
        dp[j] += uf*sK[mc*64 + mt*16 + fr];
        rs[j] += uf;
      }
    }
    if (mc<7) { SOFT_BAR_VM(2); } else { SOFT_BAR_VM(0); }
    #pragma unroll
    for (int ct=0;ct<4;++ct){
      #pragma unroll
      for (int kc=0;kc<2;++kc){
        bf16x8 av = *(const bf16x8*)&qpL[(w*16+fr)*72 + kc*32 + kb];
        bf16x8 bv = *(const bf16x8*)&sCt[(ct*16+fr)*64 + (((kc*4+kbg)^sw)<<3)];
        acc2[ct] = MFMA16(av,bv,acc2[ct]);
      }
    }
    if (mc<7) { SOFT_BAR_VM(0); }
  }
  #pragma unroll
  for (int j=0;j<4;++j){
    #pragma unroll
    for (int s=1;s<16;s<<=1){
      dp[j] += __shfl_xor(dp[j],s,64);
      rs[j] += __shfl_xor(rs[j],s,64);
      mx[j]  = fmaxf(mx[j], __shfl_xor(mx[j],s,64));
    }
  }
  float mk  = decf(kmaxEnc[bh]);
  float emk = __expf(mk);
  float Ssum = kcssum[bh];
  const float eps=1e-4f;
  float emq[4];
  #pragma unroll
  for (int j=0;j<4;++j) emq[j]=__expf(mx[j]);
  #pragma unroll
  for (int ct=0;ct<4;++ct){
    int d = ct*16 + fr;
    float cs = ctxsum[bh*64 + d];
    float vs = vsum[bh*64 + d];
    #pragma unroll
    for (int j=0;j<4;++j){
      float eq = emq[j];
      float numer = acc2[ct][j] + eps*(emk*vs*rs[j] + eq*cs + eps*eq*emk*512.0f*vs);
      float den   = dp[j]       + eps*(emk*2048.0f*rs[j] + eq*Ssum + eps*eq*emk*512.0f*2048.0f);
      int row = t0 + w*16 + rowg + j;
      outc[(size_t)row*512 + h*64 + d] = f2bf(numer/den);
    }
  }
}

extern "C" void kernel_launch(void* const* d_in, const int* in_sizes, int n_in,
                              void* d_out, int out_size, void* d_ws, size_t ws_size,
                              hipStream_t stream)
{
  (void)in_sizes; (void)n_in; (void)out_size; (void)ws_size;
  const float* x    = (const float*)d_in[0];
  const float* Wq   = (const float*)d_in[1];
  const float* bq   = (const float*)d_in[2];
  const float* Wk   = (const float*)d_in[3];
  const float* bk   = (const float*)d_in[4];
  const float* Wv   = (const float*)d_in[5];
  const float* bv   = (const float*)d_in[6];
  const float* Wo   = (const float*)d_in[7];
  const float* bo   = (const float*)d_in[8];
  const float* proj = (const float*)d_in[9];

  char* w = (char*)d_ws;
  size_t off=0;
  auto alloc=[&](size_t bytes)->char*{ char* p=w+off; off=(off+bytes+255)&~(size_t)255; return p; };
  u16*  xb   = (u16*)alloc(8192ull*512*2);
  u16*  qB   = (u16*)alloc(8192ull*512*2);
  u16*  kBf  = (u16*)alloc(8192ull*512*2);
  u16*  vB   = (u16*)alloc(8192ull*512*2);
  u16*  vT   = (u16*)alloc(32ull*64*2048*2);
  u16*  WqT  = (u16*)alloc(512ull*512*2);
  u16*  WkT  = (u16*)alloc(512ull*512*2);
  u16*  WvT  = (u16*)alloc(512ull*512*2);
  u16*  WoT  = (u16*)alloc(512ull*512*2);
  u16*  projS= (u16*)alloc(512ull*64*2);
  u16*  ctxT = (u16*)alloc(32ull*64*512*2);
  float* ctxPT=(float*)alloc(4ull*32*64*512*4);
  float* kcs = (float*)alloc(32ull*512*4);
  float* kcsP= (float*)alloc(4ull*32*512*4);
  float* diagK=(float*)alloc(32ull*2048*4);
  u32*  kmx  = (u32*)alloc(256);
  float* ctxs= (float*)alloc(32ull*64*4);
  float* kcss= (float*)alloc(32ull*4);
  float* vsm = (float*)alloc(32ull*64*4);
  u16*  outc = kBf;  // kBf dead after k_kpctx6; reuse

  dim3 TB(256);
  k_setup<<<dim3(1280),TB,0,stream>>>(kmx,projS,proj,x,xb, Wq,Wk,Wv,Wo, WqT,WkT,WvT,WoT);
  k_gemm2<false><<<dim3(64,8,3),TB,0,stream>>>(xb, WqT,WkT,WvT, bq,bk,bv, qB,kBf,vB);
  k_prep<<<dim3(4384),TB,0,stream>>>(vB, vT, vsm, kBf, diagK);
  k_kpctx6<<<dim3(8,32,4),TB,0,stream>>>(kBf, projS, vT, diagK, ctxPT, kcsP, kmx);
  k_comb4<<<dim3(32,8),TB,0,stream>>>(ctxPT, ctxT, kcsP, kcs, ctxs, kcss);
  k_qpout3<<<dim3(8,32,4),TB,0,stream>>>(qB, projS, kcs, ctxT, ctxs, kcss, vsm, kmx, outc);
  k_gemm2<true><<<dim3(64,8,1),TB,0,stream>>>(outc, WoT,WoT,WoT, bo,bo,bo,
                                              d_out,d_out,d_out);
}

// Round 20
// 126.073 us; speedup vs baseline: 1.2857x; 1.0016x over previous
//
#include <hip/hip_runtime.h>

typedef unsigned short u16;
typedef unsigned int   u32;
typedef __attribute__((ext_vector_type(8))) short bf16x8;
typedef __attribute__((ext_vector_type(4))) short s16x4;
typedef __attribute__((ext_vector_type(4))) float f32x4;

#define MFMA16(a,b,c) __builtin_amdgcn_mfma_f32_16x16x32_bf16((a),(b),(c),0,0,0)

// soft barriers: raw s_barrier + counted waits
#define SOFT_BAR_LG() do{ asm volatile("s_waitcnt lgkmcnt(0)" ::: "memory"); \
  __builtin_amdgcn_s_barrier(); __builtin_amdgcn_sched_barrier(0); }while(0)
#define SOFT_BAR_VM(N) do{ asm volatile("s_waitcnt vmcnt(" #N ") lgkmcnt(0)" ::: "memory"); \
  __builtin_amdgcn_s_barrier(); __builtin_amdgcn_sched_barrier(0); }while(0)

__device__ __forceinline__ float bf2f(u16 u){ return __uint_as_float(((u32)u)<<16); }
__device__ __forceinline__ u16 f2bf(float f){
  u32 u = __float_as_uint(f);
  return (u16)((u + 0x7fffu + ((u>>16)&1u)) >> 16);
}
__device__ __forceinline__ u32 encf(float f){ u32 u=__float_as_uint(f); return (u&0x80000000u)? ~u : (u|0x80000000u); }
__device__ __forceinline__ float decf(u32 u){ return (u&0x80000000u)? __uint_as_float(u&0x7fffffffu) : __uint_as_float(~u); }

__device__ __forceinline__ void async_lds16(u16* lds, const u16* g){
  __builtin_amdgcn_global_load_lds((const __attribute__((address_space(1))) void*)g,
                                   (__attribute__((address_space(3))) void*)lds,
                                   16, 0, 0);
}

// stage ROWS x 64 bf16 from global into LDS padded to 72/row
template<int ROWS>
__device__ __forceinline__ void stage64(u16* dst, const u16* src, int srcStride, int tid){
  #pragma unroll
  for (int u=tid; u<ROWS*8; u+=256){
    int r=u>>3, c=(u&7)<<3;
    *(int4*)&dst[r*72+c] = *(const int4*)&src[(size_t)r*srcStride + c];
  }
}

// ---------------- setup: weight transposes (blocks 0..1023) + init/cast (blocks 1024..1279) ----------------
__global__ __launch_bounds__(256) void k_setup(u32* kmaxEnc, u16* projS,
    const float* __restrict__ proj, const float* __restrict__ x, u16* __restrict__ xb,
    const float* s0, const float* s1, const float* s2, const float* s3,
    u16* d0, u16* d1, u16* d2, u16* d3)
{
  int bid=blockIdx.x, tid=threadIdx.x;
  if (bid < 1024){
    int z = bid>>8, t = bid&255;
    const float* src = z==0?s0:(z==1?s1:(z==2?s2:s3));
    u16* dst         = z==0?d0:(z==1?d1:(z==2?d2:d3));
    __shared__ u16 tl[32][34];
    int c0=(t&15)*32, r0=(t>>4)*32;
    for (int u=tid; u<1024; u+=256){ int r=u>>5, c=u&31; tl[r][c]=f2bf(src[(size_t)(r0+r)*512 + c0+c]); }
    __syncthreads();
    for (int u=tid; u<1024; u+=256){ int c=u>>5, r=u&31; dst[(size_t)(c0+c)*512 + r0+r]=tl[r][c]; }
  } else {
    int i = (bid-1024)*256 + tid;
    int st = 256*256;
    for (int j=i; j<32; j+=st) kmaxEnc[j]=0u;
    const float dn = 0.35355339059327373f; // 64^-0.25
    for (int j=i; j<512*64; j+=st) projS[j] = f2bf(dn*proj[j]);
    for (int j=i; j<524288; j+=st){
      float4 a = *(const float4*)&x[(size_t)j*8];
      float4 b = *(const float4*)&x[(size_t)j*8+4];
      u16 tmp[8] = {f2bf(a.x),f2bf(a.y),f2bf(a.z),f2bf(a.w),
                    f2bf(b.x),f2bf(b.y),f2bf(b.z),f2bf(b.w)};
      *(int4*)&xb[(size_t)j*8] = *(const int4*)tmp;
    }
  }
}

// ---------------- prep: trv (0..4095) + vsum (4096..4127) + kdiag (4128..4383) ----------------
__global__ __launch_bounds__(256) void k_prep(const u16* __restrict__ vB, u16* __restrict__ vT,
    float* __restrict__ vsum, const u16* __restrict__ kB, float* __restrict__ diagK)
{
  int bid=blockIdx.x, tid=threadIdx.x;
  if (bid < 4096){
    int xx=bid&1, y=(bid>>1)&63, bh=bid>>7;
    int b=bh>>3, h=bh&7;
    int dd0=xx*32, n0=y*32;
    __shared__ u16 t[32][34];
    const u16* s = vB + (size_t)(b*2048)*512 + h*64;
    for (int u=tid; u<1024; u+=256){ int r=u>>5, c=u&31; t[r][c]=s[(size_t)(n0+r)*512 + dd0+c]; }
    __syncthreads();
    u16* d = vT + (size_t)bh*64*2048;
    for (int u=tid; u<1024; u+=256){ int c=u>>5, r=u&31; d[(size_t)(dd0+c)*2048 + n0+r]=t[r][c]; }
  } else if (bid < 4128){
    int bh=bid-4096; int b=bh>>3, h=bh&7;
    int d=tid&63, part=tid>>6;
    const u16* src = vB + (size_t)(b*2048 + part*512)*512 + h*64 + d;
    float s=0.f;
    for (int n=0;n<512;++n) s += bf2f(src[(size_t)n*512]);
    __shared__ float red[256];
    red[tid]=s; __syncthreads();
    if (part==0) vsum[bh*64+d]=red[d]+red[64+d]+red[128+d]+red[192+d];
  } else {
    int idx=bid-4128;
    int bh=idx&31, seg=idx>>5;
    int b=bh>>3, h=bh&7;
    int part=tid&7;
    const u16* base = kB + (size_t)(b*2048 + seg*256)*512 + h*64 + part*8;
    for (int n0=0; n0<256; n0+=32){
      int n = n0 + (tid>>3);
      bf16x8 v = *(const bf16x8*)&base[(size_t)n*512];
      float sq=0.f;
      #pragma unroll
      for (int j=0;j<8;++j){ float f=bf2f((u16)v[j]); sq+=f*f; }
      sq += __shfl_xor(sq,1,64); sq += __shfl_xor(sq,2,64); sq += __shfl_xor(sq,4,64);
      if (part==0) diagK[(size_t)bh*2048 + seg*256 + n] = 0.0625f*sq;
    }
  }
}

// ---------------- GEMM m97-style + T2 swizzle (round-18 proven) ----------------
template<bool OF32>
__global__ __launch_bounds__(256) void k_gemm2(const u16* __restrict__ A,
    const u16* BT0, const u16* BT1, const u16* BT2,
    const float* b0, const float* b1, const float* b2,
    void* O0, void* O1, void* O2)
{
  int z = blockIdx.z;
  const u16* BT    = z==0?BT0:(z==1?BT1:BT2);
  const float* bias= z==0?b0 :(z==1?b1 :b2 );
  void* Ov         = z==0?O0 :(z==1?O1 :O2 );
  int bm = blockIdx.x*128, bn = blockIdx.y*64;
  __shared__ u16 sA[128*64];
  __shared__ u16 sB[64*64];
  int tid=threadIdx.x, w=tid>>6, lane=tid&63;
  int lr = lane>>3;
  int lgl = ((lane&7)^lr)*8;          // swizzled source granule; involution g ^= row&7
  f32x4 acc[8] = {};
  for (int kk=0; kk<512; kk+=64){
    __syncthreads();
    #pragma unroll
    for (int i=0;i<4;++i){
      int idx = w*4+i;
      async_lds16(&sA[idx*512], A + (size_t)(bm + idx*8 + lr)*512 + kk + lgl);
    }
    #pragma unroll
    for (int i=0;i<2;++i){
      int idx = w*2+i;
      async_lds16(&sB[idx*512], BT + (size_t)(bn + idx*8 + lr)*512 + kk + lgl);
    }
    __syncthreads();
    int fr = lane&15, kbg=lane>>4;
    int sw = fr&7;                    // read-side XOR key
    #pragma unroll
    for (int rt=0; rt<2; ++rt){
      int ar = (w*2+rt)*16 + fr;
      #pragma unroll
      for (int ct=0; ct<4; ++ct){
        int br = ct*16 + fr;
        #pragma unroll
        for (int kc=0; kc<2; ++kc){
          bf16x8 av = *(const bf16x8*)&sA[ar*64 + (((kc*4+kbg)^sw)<<3)];
          bf16x8 bv = *(const bf16x8*)&sB[br*64 + (((kc*4+kbg)^sw)<<3)];
          acc[rt*4+ct] = MFMA16(av,bv,acc[rt*4+ct]);
        }
      }
    }
  }
  int colg = lane&15, rowg=(lane>>4)*4;
  #pragma unroll
  for (int rt=0; rt<2; ++rt){
    #pragma unroll
    for (int ct=0; ct<4; ++ct){
      int col = bn + ct*16 + colg;
      float bv = bias[col];
      #pragma unroll
      for (int j=0;j<4;++j){
        int row = bm + (w*2+rt)*16 + rowg + j;
        if constexpr (OF32) ((float*)Ov)[(size_t)row*512 + col] = acc[rt*4+ct][j] + bv;
        else                ((u16*) Ov)[(size_t)row*512 + col] = f2bf(acc[rt*4+ct][j] + bv);
      }
    }
  }
}

// ---------------- k features + quarter-n ctx partial: sK AND sV double-buffered, rebalanced vmcnt ----------------
__global__ __launch_bounds__(256) void k_kpctx6(const u16* __restrict__ kB, const u16* __restrict__ projS,
    const u16* __restrict__ vT, const float* __restrict__ diagK,
    float* __restrict__ ctxPT, float* __restrict__ kcsP, u32* __restrict__ kmaxEnc)
{
  int h=blockIdx.x, y=blockIdx.y, b=blockIdx.z;
  int mblk = y&7, s = y>>3;
  int bh=b*8+h;
  int m0 = mblk*64;
  __shared__ __align__(16) u16 sP[64*72];
  __shared__ __align__(16) u16 poolKV[4*4096];   // sK0 | sK1 | sV0 | sV1 (linear, swizzled)
  __shared__ __align__(16) u16 sT[64*72];
  __shared__ float sRed[4][64];
  __shared__ float red[4];
  u16* sK0 = poolKV;
  u16* sK1 = poolKV + 4096;
  u16* sV0 = poolKV + 8192;
  u16* sV1 = poolKV + 12288;
  int tid=threadIdx.x, w=tid>>6, lane=tid&63;
  int fr=lane&15, kbg=lane>>4, kb=kbg*8, rowg=kbg*4;
  int lr=lane>>3, lgl=((lane&7)^lr)*8;
  int sw=fr&7;
  const u16* gK = kB + (size_t)(b*2048 + s*512)*512 + h*64;
  const u16* gV = vT + (size_t)bh*64*2048 + s*512;
  const float* gD = diagK + (size_t)bh*2048 + s*512 + w*16 + rowg;
  stage64<64>(sP, projS + m0*64, 64, tid);
  float4 pD[8];
  #pragma unroll
  for (int mc=0;mc<8;++mc) pD[mc] = *(const float4*)&gD[mc*64];
  // prologue: issue sK(0) then sV(0); retire sK(0), keep sV(0) in flight
  #pragma unroll
  for (int i=0;i<2;++i){
    int idx = w*2+i;
    async_lds16(&sK0[idx*512], gK + (size_t)(idx*8+lr)*512 + lgl);
  }
  #pragma unroll
  for (int i=0;i<2;++i){
    int idx = w*2+i;
    async_lds16(&sV0[idx*512], gV + (size_t)(idx*8+lr)*2048 + lgl);
  }
  f32x4 accc[4]={};
  float sSm[4]={0.f,0.f,0.f,0.f};
  float lm=-3.0e38f;
  SOFT_BAR_VM(2);   // sP (lgkm) + pD retired; sK(0) published; sV(0) flying
  #pragma unroll
  for (int mc=0; mc<8; ++mc){
    u16* sKc = (mc&1) ? sK1 : sK0;
    u16* sKn = (mc&1) ? sK0 : sK1;
    u16* sVc = (mc&1) ? sV1 : sV0;
    u16* sVn = (mc&1) ? sV0 : sV1;
    // A: issue next chunk's sK then sV
    if (mc<7){
      #pragma unroll
      for (int i=0;i<2;++i){
        int idx = w*2+i;
        async_lds16(&sKn[idx*512], gK + (size_t)((mc+1)*64 + idx*8+lr)*512 + lgl);
      }
      #pragma unroll
      for (int i=0;i<2;++i){
        int idx = w*2+i;
        async_lds16(&sVn[idx*512], gV + (size_t)(idx*8+lr)*2048 + (mc+1)*64 + lgl);
      }
    }
    // B: feature MFMA dd[64 n][64 m] on sK[cur]
    int ar = w*16 + fr;
    f32x4 facc[4];
    #pragma unroll
    for (int mt=0;mt<4;++mt){
      f32x4 a={0.f,0.f,0.f,0.f};
      #pragma unroll
      for (int kc=0;kc<2;++kc){
        bf16x8 av = *(const bf16x8*)&sKc[ar*64 + (((kc*4+kbg)^sw)<<3)];
        bf16x8 bv = *(const bf16x8*)&sP[(mt*16+fr)*72 + kc*32 + kb];
        a = MFMA16(av,bv,a);
      }
      facc[mt]=a;
      lm=fmaxf(lm, fmaxf(fmaxf(a[0],a[1]),fmaxf(a[2],a[3])));
    }
    // exp -> sT[m][n] (padded), S in regs, diag from regs
    {
      int nl = w*16 + rowg;
      #pragma unroll
      for (int mt=0;mt<4;++mt){
        int ml=mt*16+fr;
        s16x4 pk;
        #pragma unroll
        for (int j=0;j<4;++j){
          float vk = __expf(facc[mt][j]-pD[mc][j]);
          u16 us = f2bf(vk);
          pk[j]=(short)us;
          sSm[mt] += bf2f(us);
        }
        *(s16x4*)&sT[ml*72+nl]=pk;
      }
      (void)nl;
    }
    // C: retire sV(mc), keep sK(mc+1)+sV(mc+1) flying; publish sT
    if (mc<7) { SOFT_BAR_VM(4); } else { SOFT_BAR_VM(0); }
    // D: PV: ctx[m][d] += sT[m][n] @ sV[d][n]^T
    {
      int am=w*16+fr;
      #pragma unroll
      for (int ct=0;ct<4;++ct){
        #pragma unroll
        for (int kc=0;kc<2;++kc){
          bf16x8 av = *(const bf16x8*)&sT[am*72 + kc*32 + kb];
          bf16x8 bv = *(const bf16x8*)&sVc[(ct*16+fr)*64 + (((kc*4+kbg)^sw)<<3)];
          accc[ct] = MFMA16(av,bv,accc[ct]);
        }
      }
    }
    // E: retire sK(mc+1), keep sV(mc+1) flying; protects sT overwrite
    if (mc<7) { SOFT_BAR_VM(2); }
  }
  __syncthreads();
  #pragma unroll
  for (int mt=0;mt<4;++mt){
    float t=sSm[mt];
    t += __shfl_xor(t,16,64); t += __shfl_xor(t,32,64);
    if (kbg==0) sRed[w][mt*16+fr]=t;
  }
  #pragma unroll
  for (int m2=1;m2<64;m2<<=1) lm=fmaxf(lm,__shfl_xor(lm,m2,64));
  if (lane==0) red[w]=lm;
  float* sTf = (float*)poolKV;   // 64*68*4 = 17408B <= 32768B
  int mloc = w*16+rowg;
  #pragma unroll
  for (int ct=0;ct<4;++ct){
    #pragma unroll
    for (int j=0;j<4;++j) sTf[(ct*16+fr)*68 + mloc + j] = accc[ct][j];
  }
  __syncthreads();
  if (tid==0) atomicMax(&kmaxEnc[bh], encf(fmaxf(fmaxf(red[0],red[1]),fmaxf(red[2],red[3]))));
  if (tid<64) kcsP[(size_t)(s*32+bh)*512 + m0 + tid] =
      sRed[0][tid]+sRed[1][tid]+sRed[2][tid]+sRed[3][tid];
  for (int u=tid; u<1024; u+=256){
    int r=u>>4, c=(u&15)*4;
    *(float4*)&ctxPT[((size_t)(s*32+bh)*64 + r)*512 + m0 + c] = *(const float4*)&sTf[r*68+c];
  }
}

// ---------------- combine 4 split-n partials -> ctxT bf16 + kcs, fused ctxsum/kcssum ----------------
__global__ __launch_bounds__(256) void k_comb4(const float* __restrict__ ctxPT, u16* __restrict__ ctxT,
    const float* __restrict__ kcsP, float* __restrict__ kcs,
    float* __restrict__ ctxsum, float* __restrict__ kcssum)
{
  int bh=blockIdx.x, dblk=blockIdx.y;
  int tid=threadIdx.x;
  int d0=dblk*8;
  __shared__ float sDsum[8];
  __shared__ float sKsum[256];
  if (tid<8) sDsum[tid]=0.f;
  __syncthreads();
  u16* o = ctxT + ((size_t)bh*64 + d0)*512;
  for (int u=tid; u<1024; u+=256){
    int r=u>>7, c=(u&127)*4;
    float4 a={0.f,0.f,0.f,0.f};
    #pragma unroll
    for (int s=0;s<4;++s){
      float4 p=*(const float4*)&ctxPT[((size_t)(s*32+bh)*64 + d0+r)*512 + c];
      a.x+=p.x; a.y+=p.y; a.z+=p.z; a.w+=p.w;
    }
    u16 t[4]={f2bf(a.x),f2bf(a.y),f2bf(a.z),f2bf(a.w)};
    *(int2*)&o[(size_t)r*512+c] = *(const int2*)t;
    atomicAdd(&sDsum[r], bf2f(t[0])+bf2f(t[1])+bf2f(t[2])+bf2f(t[3]));
  }
  float tpart=0.f;
  if (dblk==0){
    for (int u=tid; u<512; u+=256){
      float t=0.f;
      #pragma unroll
      for (int s=0;s<4;++s) t += kcsP[(size_t)(s*32+bh)*512+u];
      kcs[(size_t)bh*512+u]=t;
      tpart += t;
    }
  }
  sKsum[tid]=tpart;
  __syncthreads();
  if (tid<8) ctxsum[bh*64 + d0 + tid] = sDsum[tid];
  if (dblk==0 && tid<64){
    float a=sKsum[tid]+sKsum[tid+64]+sKsum[tid+128]+sKsum[tid+192];
    #pragma unroll
    for (int m2=1;m2<64;m2<<=1) a += __shfl_xor(a,m2,64);
    if (tid==0) kcssum[bh]=a;
  }
}

// ---------------- q features + PV + eps epilogue: 64 rows/block, swizzled LDS (round-16 proven) ----------------
__global__ __launch_bounds__(256) void k_qpout3(const u16* __restrict__ qB, const u16* __restrict__ projS,
    const float* __restrict__ kcs, const u16* __restrict__ ctxT,
    const float* __restrict__ ctxsum, const float* __restrict__ kcssum,
    const float* __restrict__ vsum, const u32* __restrict__ kmaxEnc,
    u16* __restrict__ outc)
{
  int h=blockIdx.x, chunk=blockIdx.y, b=blockIdx.z;
  int bh=b*8+h;
  int t0 = b*2048 + chunk*64;
  __shared__ u16 sP[2][64*64];
  __shared__ u16 sCt[64*64];
  __shared__ u16 qpL[64*72];
  __shared__ float sK[512];
  __shared__ float diag[64];
  int tid=threadIdx.x, w=tid>>6, lane=tid&63;
  int fr=lane&15, kbg=lane>>4, kb=kbg*8, rowg=kbg*4;
  int lr=lane>>3, lgl=((lane&7)^lr)*8;
  int sw=fr&7;
  bf16x8 qf[2];
  #pragma unroll
  for (int kc=0;kc<2;++kc)
    qf[kc] = *(const bf16x8*)&qB[(size_t)(t0 + w*16 + fr)*512 + h*64 + kc*32 + kb];
  {
    float ssum=0.f;
    #pragma unroll
    for (int kc=0;kc<2;++kc)
      #pragma unroll
      for (int j=0;j<8;++j){ float f=bf2f((u16)qf[kc][j]); ssum+=f*f; }
    ssum += __shfl_xor(ssum,16,64); ssum += __shfl_xor(ssum,32,64);
    if (lane<16) diag[w*16 + fr] = 0.0625f*ssum;
  }
  for (int u=tid; u<512; u+=256) sK[u] = kcs[(size_t)bh*512 + u];
  const u16* gcB = ctxT + (size_t)bh*64*512;
  #pragma unroll
  for (int i=0;i<2;++i){
    int idx = w*2+i;
    async_lds16(&sP[0][idx*512], projS + (size_t)(idx*8+lr)*64 + lgl);
  }
  f32x4 acc2[4]={};
  float mx[4], dp[4], rs[4];
  #pragma unroll
  for (int j=0;j<4;++j){ mx[j]=-3.0e38f; dp[j]=0.f; rs[j]=0.f; }
  SOFT_BAR_VM(0);
  for (int mc=0; mc<8; ++mc){
    int cur = mc&1;
    #pragma unroll
    for (int i=0;i<2;++i){
      int idx = w*2+i;
      async_lds16(&sCt[idx*512], gcB + (size_t)(idx*8+lr)*512 + mc*64 + lgl);
    }
    if (mc<7){
      const u16* gp = projS + (mc+1)*64*64;
      #pragma unroll
      for (int i=0;i<2;++i){
        int idx = w*2+i;
        async_lds16(&sP[cur^1][idx*512], gp + (size_t)(idx*8+lr)*64 + lgl);
      }
    }
    f32x4 facc[4];
    #pragma unroll
    for (int mt=0;mt<4;++mt){
      f32x4 a={0.f,0.f,0.f,0.f};
      #pragma unroll
      for (int kc=0;kc<2;++kc){
        bf16x8 bv = *(const bf16x8*)&sP[cur][(mt*16+fr)*64 + (((kc*4+kbg)^sw)<<3)];
        a = MFMA16(qf[kc], bv, a);
      }
      facc[mt]=a;
    }
    #pragma unroll
    for (int mt=0;mt<4;++mt){
      #pragma unroll
      for (int j=0;j<4;++j){
        int rl = w*16 + rowg + j;
        mx[j] = fmaxf(mx[j], facc[mt][j]);
        float vq = __expf(facc[mt][j] - diag[rl]);
        u16 us = f2bf(vq);
        qpL[rl*72 + mt*16 + fr] = us;
        float uf = bf2f(us);
        dp[j] += uf*sK[mc*64 + mt*16 + fr];
        rs[j] += uf;
      }
    }
    if (mc<7) { SOFT_BAR_VM(2); } else { SOFT_BAR_VM(0); }
    #pragma unroll
    for (int ct=0;ct<4;++ct){
      #pragma unroll
      for (int kc=0;kc<2;++kc){
        bf16x8 av = *(const bf16x8*)&qpL[(w*16+fr)*72 + kc*32 + kb];
        bf16x8 bv = *(const bf16x8*)&sCt[(ct*16+fr)*64 + (((kc*4+kbg)^sw)<<3)];
        acc2[ct] = MFMA16(av,bv,acc2[ct]);
      }
    }
    if (mc<7) { SOFT_BAR_VM(0); }
  }
  #pragma unroll
  for (int j=0;j<4;++j){
    #pragma unroll
    for (int s=1;s<16;s<<=1){
      dp[j] += __shfl_xor(dp[j],s,64);
      rs[j] += __shfl_xor(rs[j],s,64);
      mx[j]  = fmaxf(mx[j], __shfl_xor(mx[j],s,64));
    }
  }
  float mk  = decf(kmaxEnc[bh]);
  float emk = __expf(mk);
  float Ssum = kcssum[bh];
  const float eps=1e-4f;
  float emq[4];
  #pragma unroll
  for (int j=0;j<4;++j) emq[j]=__expf(mx[j]);
  #pragma unroll
  for (int ct=0;ct<4;++ct){
    int d = ct*16 + fr;
    float cs = ctxsum[bh*64 + d];
    float vs = vsum[bh*64 + d];
    #pragma unroll
    for (int j=0;j<4;++j){
      float eq = emq[j];
      float numer = acc2[ct][j] + eps*(emk*vs*rs[j] + eq*cs + eps*eq*emk*512.0f*vs);
      float den   = dp[j]       + eps*(emk*2048.0f*rs[j] + eq*Ssum + eps*eq*emk*512.0f*2048.0f);
      int row = t0 + w*16 + rowg + j;
      outc[(size_t)row*512 + h*64 + d] = f2bf(numer/den);
    }
  }
}

extern "C" void kernel_launch(void* const* d_in, const int* in_sizes, int n_in,
                              void* d_out, int out_size, void* d_ws, size_t ws_size,
                              hipStream_t stream)
{
  (void)in_sizes; (void)n_in; (void)out_size; (void)ws_size;
  const float* x    = (const float*)d_in[0];
  const float* Wq   = (const float*)d_in[1];
  const float* bq   = (const float*)d_in[2];
  const float* Wk   = (const float*)d_in[3];
  const float* bk   = (const float*)d_in[4];
  const float* Wv   = (const float*)d_in[5];
  const float* bv   = (const float*)d_in[6];
  const float* Wo   = (const float*)d_in[7];
  const float* bo   = (const float*)d_in[8];
  const float* proj = (const float*)d_in[9];

  char* w = (char*)d_ws;
  size_t off=0;
  auto alloc=[&](size_t bytes)->char*{ char* p=w+off; off=(off+bytes+255)&~(size_t)255; return p; };
  u16*  xb   = (u16*)alloc(8192ull*512*2);
  u16*  qB   = (u16*)alloc(8192ull*512*2);
  u16*  kBf  = (u16*)alloc(8192ull*512*2);
  u16*  vB   = (u16*)alloc(8192ull*512*2);
  u16*  vT   = (u16*)alloc(32ull*64*2048*2);
  u16*  WqT  = (u16*)alloc(512ull*512*2);
  u16*  WkT  = (u16*)alloc(512ull*512*2);
  u16*  WvT  = (u16*)alloc(512ull*512*2);
  u16*  WoT  = (u16*)alloc(512ull*512*2);
  u16*  projS= (u16*)alloc(512ull*64*2);
  u16*  ctxT = (u16*)alloc(32ull*64*512*2);
  float* ctxPT=(float*)alloc(4ull*32*64*512*4);
  float* kcs = (float*)alloc(32ull*512*4);
  float* kcsP= (float*)alloc(4ull*32*512*4);
  float* diagK=(float*)alloc(32ull*2048*4);
  u32*  kmx  = (u32*)alloc(256);
  float* ctxs= (float*)alloc(32ull*64*4);
  float* kcss= (float*)alloc(32ull*4);
  float* vsm = (float*)alloc(32ull*64*4);
  u16*  outc = kBf;  // kBf dead after k_kpctx6; reuse

  dim3 TB(256);
  k_setup<<<dim3(1280),TB,0,stream>>>(kmx,projS,proj,x,xb, Wq,Wk,Wv,Wo, WqT,WkT,WvT,WoT);
  k_gemm2<false><<<dim3(64,8,3),TB,0,stream>>>(xb, WqT,WkT,WvT, bq,bk,bv, qB,kBf,vB);
  k_prep<<<dim3(4384),TB,0,stream>>>(vB, vT, vsm, kBf, diagK);
  k_kpctx6<<<dim3(8,32,4),TB,0,stream>>>(kBf, projS, vT, diagK, ctxPT, kcsP, kmx);
  k_comb4<<<dim3(32,8),TB,0,stream>>>(ctxPT, ctxT, kcsP, kcs, ctxs, kcss);
  k_qpout3<<<dim3(8,32,4),TB,0,stream>>>(qB, projS, kcs, ctxT, ctxs, kcss, vsm, kmx, outc);
  k_gemm2<true><<<dim3(64,8,1),TB,0,stream>>>(outc, WoT,WoT,WoT, bo,bo,bo,
                                              d_out,d_out,d_out);
}

// Round 21
// 125.709 us; speedup vs baseline: 1.2895x; 1.0029x over previous
//
#include <hip/hip_runtime.h>

typedef unsigned short u16;
typedef unsigned int   u32;
typedef __attribute__((ext_vector_type(8))) short bf16x8;
typedef __attribute__((ext_vector_type(4))) short s16x4;
typedef __attribute__((ext_vector_type(4))) float f32x4;

#define MFMA16(a,b,c) __builtin_amdgcn_mfma_f32_16x16x32_bf16((a),(b),(c),0,0,0)

// soft barriers: raw s_barrier + counted waits
#define SOFT_BAR_LG() do{ asm volatile("s_waitcnt lgkmcnt(0)" ::: "memory"); \
  __builtin_amdgcn_s_barrier(); __builtin_amdgcn_sched_barrier(0); }while(0)
#define SOFT_BAR_VM(N) do{ asm volatile("s_waitcnt vmcnt(" #N ") lgkmcnt(0)" ::: "memory"); \
  __builtin_amdgcn_s_barrier(); __builtin_amdgcn_sched_barrier(0); }while(0)

__device__ __forceinline__ float bf2f(u16 u){ return __uint_as_float(((u32)u)<<16); }
__device__ __forceinline__ u16 f2bf(float f){
  u32 u = __float_as_uint(f);
  return (u16)((u + 0x7fffu + ((u>>16)&1u)) >> 16);
}
__device__ __forceinline__ u32 encf(float f){ u32 u=__float_as_uint(f); return (u&0x80000000u)? ~u : (u|0x80000000u); }
__device__ __forceinline__ float decf(u32 u){ return (u&0x80000000u)? __uint_as_float(u&0x7fffffffu) : __uint_as_float(~u); }

__device__ __forceinline__ void async_lds16(u16* lds, const u16* g){
  __builtin_amdgcn_global_load_lds((const __attribute__((address_space(1))) void*)g,
                                   (__attribute__((address_space(3))) void*)lds,
                                   16, 0, 0);
}

// stage ROWS x 64 bf16 from global into LDS padded to 72/row
template<int ROWS>
__device__ __forceinline__ void stage64(u16* dst, const u16* src, int srcStride, int tid){
  #pragma unroll
  for (int u=tid; u<ROWS*8; u+=256){
    int r=u>>3, c=(u&7)<<3;
    *(int4*)&dst[r*72+c] = *(const int4*)&src[(size_t)r*srcStride + c];
  }
}

// ---------------- setup: weight transposes (blocks 0..1023) + init/cast (blocks 1024..1279) ----------------
__global__ __launch_bounds__(256) void k_setup(u32* kmaxEnc, u16* projS,
    const float* __restrict__ proj, const float* __restrict__ x, u16* __restrict__ xb,
    const float* s0, const float* s1, const float* s2, const float* s3,
    u16* d0, u16* d1, u16* d2, u16* d3)
{
  int bid=blockIdx.x, tid=threadIdx.x;
  if (bid < 1024){
    int z = bid>>8, t = bid&255;
    const float* src = z==0?s0:(z==1?s1:(z==2?s2:s3));
    u16* dst         = z==0?d0:(z==1?d1:(z==2?d2:d3));
    __shared__ u16 tl[32][34];
    int c0=(t&15)*32, r0=(t>>4)*32;
    for (int u=tid; u<1024; u+=256){ int r=u>>5, c=u&31; tl[r][c]=f2bf(src[(size_t)(r0+r)*512 + c0+c]); }
    __syncthreads();
    for (int u=tid; u<1024; u+=256){ int c=u>>5, r=u&31; dst[(size_t)(c0+c)*512 + r0+r]=tl[r][c]; }
  } else {
    int i = (bid-1024)*256 + tid;
    int st = 256*256;
    for (int j=i; j<32; j+=st) kmaxEnc[j]=0u;
    const float dn = 0.35355339059327373f; // 64^-0.25
    for (int j=i; j<512*64; j+=st) projS[j] = f2bf(dn*proj[j]);
    for (int j=i; j<524288; j+=st){
      float4 a = *(const float4*)&x[(size_t)j*8];
      float4 b = *(const float4*)&x[(size_t)j*8+4];
      u16 tmp[8] = {f2bf(a.x),f2bf(a.y),f2bf(a.z),f2bf(a.w),
                    f2bf(b.x),f2bf(b.y),f2bf(b.z),f2bf(b.w)};
      *(int4*)&xb[(size_t)j*8] = *(const int4*)tmp;
    }
  }
}

// ---------------- prep: trv (0..4095) + vsum (4096..4127) + kdiag (4128..4383) ----------------
__global__ __launch_bounds__(256) void k_prep(const u16* __restrict__ vB, u16* __restrict__ vT,
    float* __restrict__ vsum, const u16* __restrict__ kB, float* __restrict__ diagK)
{
  int bid=blockIdx.x, tid=threadIdx.x;
  if (bid < 4096){
    int xx=bid&1, y=(bid>>1)&63, bh=bid>>7;
    int b=bh>>3, h=bh&7;
    int dd0=xx*32, n0=y*32;
    __shared__ u16 t[32][34];
    const u16* s = vB + (size_t)(b*2048)*512 + h*64;
    for (int u=tid; u<1024; u+=256){ int r=u>>5, c=u&31; t[r][c]=s[(size_t)(n0+r)*512 + dd0+c]; }
    __syncthreads();
    u16* d = vT + (size_t)bh*64*2048;
    for (int u=tid; u<1024; u+=256){ int c=u>>5, r=u&31; d[(size_t)(dd0+c)*2048 + n0+r]=t[r][c]; }
  } else if (bid < 4128){
    int bh=bid-4096; int b=bh>>3, h=bh&7;
    int d=tid&63, part=tid>>6;
    const u16* src = vB + (size_t)(b*2048 + part*512)*512 + h*64 + d;
    float s=0.f;
    for (int n=0;n<512;++n) s += bf2f(src[(size_t)n*512]);
    __shared__ float red[256];
    red[tid]=s; __syncthreads();
    if (part==0) vsum[bh*64+d]=red[d]+red[64+d]+red[128+d]+red[192+d];
  } else {
    int idx=bid-4128;
    int bh=idx&31, seg=idx>>5;
    int b=bh>>3, h=bh&7;
    int part=tid&7;
    const u16* base = kB + (size_t)(b*2048 + seg*256)*512 + h*64 + part*8;
    for (int n0=0; n0<256; n0+=32){
      int n = n0 + (tid>>3);
      bf16x8 v = *(const bf16x8*)&base[(size_t)n*512];
      float sq=0.f;
      #pragma unroll
      for (int j=0;j<8;++j){ float f=bf2f((u16)v[j]); sq+=f*f; }
      sq += __shfl_xor(sq,1,64); sq += __shfl_xor(sq,2,64); sq += __shfl_xor(sq,4,64);
      if (part==0) diagK[(size_t)bh*2048 + seg*256 + n] = 0.0625f*sq;
    }
  }
}

// ---------------- GEMM m97-style + T2 swizzle (round-18 proven) ----------------
template<bool OF32>
__global__ __launch_bounds__(256) void k_gemm2(const u16* __restrict__ A,
    const u16* BT0, const u16* BT1, const u16* BT2,
    const float* b0, const float* b1, const float* b2,
    void* O0, void* O1, void* O2)
{
  int z = blockIdx.z;
  const u16* BT    = z==0?BT0:(z==1?BT1:BT2);
  const float* bias= z==0?b0 :(z==1?b1 :b2 );
  void* Ov         = z==0?O0 :(z==1?O1 :O2 );
  int bm = blockIdx.x*128, bn = blockIdx.y*64;
  __shared__ u16 sA[128*64];
  __shared__ u16 sB[64*64];
  int tid=threadIdx.x, w=tid>>6, lane=tid&63;
  int lr = lane>>3;
  int lgl = ((lane&7)^lr)*8;          // swizzled source granule; involution g ^= row&7
  f32x4 acc[8] = {};
  for (int kk=0; kk<512; kk+=64){
    __syncthreads();
    #pragma unroll
    for (int i=0;i<4;++i){
      int idx = w*4+i;
      async_lds16(&sA[idx*512], A + (size_t)(bm + idx*8 + lr)*512 + kk + lgl);
    }
    #pragma unroll
    for (int i=0;i<2;++i){
      int idx = w*2+i;
      async_lds16(&sB[idx*512], BT + (size_t)(bn + idx*8 + lr)*512 + kk + lgl);
    }
    __syncthreads();
    int fr = lane&15, kbg=lane>>4;
    int sw = fr&7;                    // read-side XOR key
    #pragma unroll
    for (int rt=0; rt<2; ++rt){
      int ar = (w*2+rt)*16 + fr;
      #pragma unroll
      for (int ct=0; ct<4; ++ct){
        int br = ct*16 + fr;
        #pragma unroll
        for (int kc=0; kc<2; ++kc){
          bf16x8 av = *(const bf16x8*)&sA[ar*64 + (((kc*4+kbg)^sw)<<3)];
          bf16x8 bv = *(const bf16x8*)&sB[br*64 + (((kc*4+kbg)^sw)<<3)];
          acc[rt*4+ct] = MFMA16(av,bv,acc[rt*4+ct]);
        }
      }
    }
  }
  int colg = lane&15, rowg=(lane>>4)*4;
  #pragma unroll
  for (int rt=0; rt<2; ++rt){
    #pragma unroll
    for (int ct=0; ct<4; ++ct){
      int col = bn + ct*16 + colg;
      float bv = bias[col];
      #pragma unroll
      for (int j=0;j<4;++j){
        int row = bm + (w*2+rt)*16 + rowg + j;
        if constexpr (OF32) ((float*)Ov)[(size_t)row*512 + col] = acc[rt*4+ct][j] + bv;
        else                ((u16*) Ov)[(size_t)row*512 + col] = f2bf(acc[rt*4+ct][j] + bv);
      }
    }
  }
}

// ---------------- k features + quarter-n ctx partial: sK AND sV double-buffered, rebalanced vmcnt ----------------
__global__ __launch_bounds__(256) void k_kpctx6(const u16* __restrict__ kB, const u16* __restrict__ projS,
    const u16* __restrict__ vT, const float* __restrict__ diagK,
    float* __restrict__ ctxPT, float* __restrict__ kcsP, u32* __restrict__ kmaxEnc)
{
  int h=blockIdx.x, y=blockIdx.y, b=blockIdx.z;
  int mblk = y&7, s = y>>3;
  int bh=b*8+h;
  int m0 = mblk*64;
  __shared__ __align__(16) u16 sP[64*72];
  __shared__ __align__(16) u16 poolKV[4*4096];   // sK0 | sK1 | sV0 | sV1 (linear, swizzled)
  __shared__ __align__(16) u16 sT[64*72];
  __shared__ float sRed[4][64];
  __shared__ float red[4];
  u16* sK0 = poolKV;
  u16* sK1 = poolKV + 4096;
  u16* sV0 = poolKV + 8192;
  u16* sV1 = poolKV + 12288;
  int tid=threadIdx.x, w=tid>>6, lane=tid&63;
  int fr=lane&15, kbg=lane>>4, kb=kbg*8, rowg=kbg*4;
  int lr=lane>>3, lgl=((lane&7)^lr)*8;
  int sw=fr&7;
  const u16* gK = kB + (size_t)(b*2048 + s*512)*512 + h*64;
  const u16* gV = vT + (size_t)bh*64*2048 + s*512;
  const float* gD = diagK + (size_t)bh*2048 + s*512 + w*16 + rowg;
  stage64<64>(sP, projS + m0*64, 64, tid);
  float4 pD[8];
  #pragma unroll
  for (int mc=0;mc<8;++mc) pD[mc] = *(const float4*)&gD[mc*64];
  // prologue: issue sK(0) then sV(0); retire sK(0), keep sV(0) in flight
  #pragma unroll
  for (int i=0;i<2;++i){
    int idx = w*2+i;
    async_lds16(&sK0[idx*512], gK + (size_t)(idx*8+lr)*512 + lgl);
  }
  #pragma unroll
  for (int i=0;i<2;++i){
    int idx = w*2+i;
    async_lds16(&sV0[idx*512], gV + (size_t)(idx*8+lr)*2048 + lgl);
  }
  f32x4 accc[4]={};
  float sSm[4]={0.f,0.f,0.f,0.f};
  float lm=-3.0e38f;
  SOFT_BAR_VM(2);   // sP (lgkm) + pD retired; sK(0) published; sV(0) flying
  #pragma unroll
  for (int mc=0; mc<8; ++mc){
    u16* sKc = (mc&1) ? sK1 : sK0;
    u16* sKn = (mc&1) ? sK0 : sK1;
    u16* sVc = (mc&1) ? sV1 : sV0;
    u16* sVn = (mc&1) ? sV0 : sV1;
    // A: issue next chunk's sK then sV
    if (mc<7){
      #pragma unroll
      for (int i=0;i<2;++i){
        int idx = w*2+i;
        async_lds16(&sKn[idx*512], gK + (size_t)((mc+1)*64 + idx*8+lr)*512 + lgl);
      }
      #pragma unroll
      for (int i=0;i<2;++i){
        int idx = w*2+i;
        async_lds16(&sVn[idx*512], gV + (size_t)(idx*8+lr)*2048 + (mc+1)*64 + lgl);
      }
    }
    // B: feature MFMA dd[64 n][64 m] on sK[cur]
    int ar = w*16 + fr;
    f32x4 facc[4];
    #pragma unroll
    for (int mt=0;mt<4;++mt){
      f32x4 a={0.f,0.f,0.f,0.f};
      #pragma unroll
      for (int kc=0;kc<2;++kc){
        bf16x8 av = *(const bf16x8*)&sKc[ar*64 + (((kc*4+kbg)^sw)<<3)];
        bf16x8 bv = *(const bf16x8*)&sP[(mt*16+fr)*72 + kc*32 + kb];
        a = MFMA16(av,bv,a);
      }
      facc[mt]=a;
      lm=fmaxf(lm, fmaxf(fmaxf(a[0],a[1]),fmaxf(a[2],a[3])));
    }
    // exp -> sT[m][n] (padded), S in regs, diag from regs
    {
      int nl = w*16 + rowg;
      #pragma unroll
      for (int mt=0;mt<4;++mt){
        int ml=mt*16+fr;
        s16x4 pk;
        #pragma unroll
        for (int j=0;j<4;++j){
          float vk = __expf(facc[mt][j]-pD[mc][j]);
          u16 us = f2bf(vk);
          pk[j]=(short)us;
          sSm[mt] += bf2f(us);
        }
        *(s16x4*)&sT[ml*72+nl]=pk;
      }
      (void)nl;
    }
    // C: retire sV(mc), keep sK(mc+1)+sV(mc+1) flying; publish sT
    if (mc<7) { SOFT_BAR_VM(4); } else { SOFT_BAR_VM(0); }
    // D: PV: ctx[m][d] += sT[m][n] @ sV[d][n]^T
    {
      int am=w*16+fr;
      #pragma unroll
      for (int ct=0;ct<4;++ct){
        #pragma unroll
        for (int kc=0;kc<2;++kc){
          bf16x8 av = *(const bf16x8*)&sT[am*72 + kc*32 + kb];
          bf16x8 bv = *(const bf16x8*)&sVc[(ct*16+fr)*64 + (((kc*4+kbg)^sw)<<3)];
          accc[ct] = MFMA16(av,bv,accc[ct]);
        }
      }
    }
    // E: retire sK(mc+1), keep sV(mc+1) flying; protects sT overwrite
    if (mc<7) { SOFT_BAR_VM(2); }
  }
  __syncthreads();
  #pragma unroll
  for (int mt=0;mt<4;++mt){
    float t=sSm[mt];
    t += __shfl_xor(t,16,64); t += __shfl_xor(t,32,64);
    if (kbg==0) sRed[w][mt*16+fr]=t;
  }
  #pragma unroll
  for (int m2=1;m2<64;m2<<=1) lm=fmaxf(lm,__shfl_xor(lm,m2,64));
  if (lane==0) red[w]=lm;
  float* sTf = (float*)poolKV;   // 64*68*4 = 17408B <= 32768B
  int mloc = w*16+rowg;
  #pragma unroll
  for (int ct=0;ct<4;++ct){
    #pragma unroll
    for (int j=0;j<4;++j) sTf[(ct*16+fr)*68 + mloc + j] = accc[ct][j];
  }
  __syncthreads();
  if (tid==0) atomicMax(&kmaxEnc[bh], encf(fmaxf(fmaxf(red[0],red[1]),fmaxf(red[2],red[3]))));
  if (tid<64) kcsP[(size_t)(s*32+bh)*512 + m0 + tid] =
      sRed[0][tid]+sRed[1][tid]+sRed[2][tid]+sRed[3][tid];
  for (int u=tid; u<1024; u+=256){
    int r=u>>4, c=(u&15)*4;
    *(float4*)&ctxPT[((size_t)(s*32+bh)*64 + r)*512 + m0 + c] = *(const float4*)&sTf[r*68+c];
  }
}

// ---------------- combine 4 split-n partials -> ctxT bf16 + kcs, fused ctxsum/kcssum ----------------
__global__ __launch_bounds__(256) void k_comb4(const float* __restrict__ ctxPT, u16* __restrict__ ctxT,
    const float* __restrict__ kcsP, float* __restrict__ kcs,
    float* __restrict__ ctxsum, float* __restrict__ kcssum)
{
  int bh=blockIdx.x, dblk=blockIdx.y;
  int tid=threadIdx.x;
  int d0=dblk*8;
  __shared__ float sDsum[8];
  __shared__ float sKsum[256];
  if (tid<8) sDsum[tid]=0.f;
  __syncthreads();
  u16* o = ctxT + ((size_t)bh*64 + d0)*512;
  for (int u=tid; u<1024; u+=256){
    int r=u>>7, c=(u&127)*4;
    float4 a={0.f,0.f,0.f,0.f};
    #pragma unroll
    for (int s=0;s<4;++s){
      float4 p=*(const float4*)&ctxPT[((size_t)(s*32+bh)*64 + d0+r)*512 + c];
      a.x+=p.x; a.y+=p.y; a.z+=p.z; a.w+=p.w;
    }
    u16 t[4]={f2bf(a.x),f2bf(a.y),f2bf(a.z),f2bf(a.w)};
    *(int2*)&o[(size_t)r*512+c] = *(const int2*)t;
    atomicAdd(&sDsum[r], bf2f(t[0])+bf2f(t[1])+bf2f(t[2])+bf2f(t[3]));
  }
  float tpart=0.f;
  if (dblk==0){
    for (int u=tid; u<512; u+=256){
      float t=0.f;
      #pragma unroll
      for (int s=0;s<4;++s) t += kcsP[(size_t)(s*32+bh)*512+u];
      kcs[(size_t)bh*512+u]=t;
      tpart += t;
    }
  }
  sKsum[tid]=tpart;
  __syncthreads();
  if (tid<8) ctxsum[bh*64 + d0 + tid] = sDsum[tid];
  if (dblk==0 && tid<64){
    float a=sKsum[tid]+sKsum[tid+64]+sKsum[tid+128]+sKsum[tid+192];
    #pragma unroll
    for (int m2=1;m2<64;m2<<=1) a += __shfl_xor(a,m2,64);
    if (tid==0) kcssum[bh]=a;
  }
}

// ---------------- q features + PV + eps epilogue: 64 rows/block, swizzled LDS (round-16 proven) ----------------
__global__ __launch_bounds__(256) void k_qpout3(const u16* __restrict__ qB, const u16* __restrict__ projS,
    const float* __restrict__ kcs, const u16* __restrict__ ctxT,
    const float* __restrict__ ctxsum, const float* __restrict__ kcssum,
    const float* __restrict__ vsum, const u32* __restrict__ kmaxEnc,
    u16* __restrict__ outc)
{
  int h=blockIdx.x, chunk=blockIdx.y, b=blockIdx.z;
  int bh=b*8+h;
  int t0 = b*2048 + chunk*64;
  __shared__ u16 sP[2][64*64];
  __shared__ u16 sCt[64*64];
  __shared__ u16 qpL[64*72];
  __shared__ float sK[512];
  __shared__ float diag[64];
  int tid=threadIdx.x, w=tid>>6, lane=tid&63;
  int fr=lane&15, kbg=lane>>4, kb=kbg*8, rowg=kbg*4;
  int lr=lane>>3, lgl=((lane&7)^lr)*8;
  int sw=fr&7;
  bf16x8 qf[2];
  #pragma unroll
  for (int kc=0;kc<2;++kc)
    qf[kc] = *(const bf16x8*)&qB[(size_t)(t0 + w*16 + fr)*512 + h*64 + kc*32 + kb];
  {
    float ssum=0.f;
    #pragma unroll
    for (int kc=0;kc<2;++kc)
      #pragma unroll
      for (int j=0;j<8;++j){ float f=bf2f((u16)qf[kc][j]); ssum+=f*f; }
    ssum += __shfl_xor(ssum,16,64); ssum += __shfl_xor(ssum,32,64);
    if (lane<16) diag[w*16 + fr] = 0.0625f*ssum;
  }
  for (int u=tid; u<512; u+=256) sK[u] = kcs[(size_t)bh*512 + u];
  const u16* gcB = ctxT + (size_t)bh*64*512;
  #pragma unroll
  for (int i=0;i<2;++i){
    int idx = w*2+i;
    async_lds16(&sP[0][idx*512], projS + (size_t)(idx*8+lr)*64 + lgl);
  }
  f32x4 acc2[4]={};
  float mx[4], dp[4], rs[4];
  #pragma unroll
  for (int j=0;j<4;++j){ mx[j]=-3.0e38f; dp[j]=0.f; rs[j]=0.f; }
  SOFT_BAR_VM(0);
  for (int mc=0; mc<8; ++mc){
    int cur = mc&1;
    #pragma unroll
    for (int i=0;i<2;++i){
      int idx = w*2+i;
      async_lds16(&sCt[idx*512], gcB + (size_t)(idx*8+lr)*512 + mc*64 + lgl);
    }
    if (mc<7){
      const u16* gp = projS + (mc+1)*64*64;
      #pragma unroll
      for (int i=0;i<2;++i){
        int idx = w*2+i;
        async_lds16(&sP[cur^1][idx*512], gp + (size_t)(idx*8+lr)*64 + lgl);
      }
    }
    f32x4 facc[4];
    #pragma unroll
    for (int mt=0;mt<4;++mt){
      f32x4 a={0.f,0.f,0.f,0.f};
      #pragma unroll
      for (int kc=0;kc<2;++kc){
        bf16x8 bv = *(const bf16x8*)&sP[cur][(mt*16+fr)*64 + (((kc*4+kbg)^sw)<<3)];
        a = MFMA16(qf[kc], bv, a);
      }
      facc[mt]=a;
    }
    #pragma unroll
    for (int mt=0;mt<4;++mt){
      #pragma unroll
      for (int j=0;j<4;++j){
        int rl = w*16 + rowg + j;
        mx[j] = fmaxf(mx[j], facc[mt][j]);
        float vq = __expf(facc[mt][j] - diag[rl]);
        u16 us = f2bf(vq);
        qpL[rl*72 + mt*16 + fr] = us;
        float uf = bf2f(us);
        dp[j] += uf*sK[mc*64 + mt*16 + fr];
        rs[j] += uf;
      }
    }
    if (mc<7) { SOFT_BAR_VM(2); } else { SOFT_BAR_VM(0); }
    #pragma unroll
    for (int ct=0;ct<4;++ct){
      #pragma unroll
      for (int kc=0;kc<2;++kc){
        bf16x8 av = *(const bf16x8*)&qpL[(w*16+fr)*72 + kc*32 + kb];
        bf16x8 bv = *(const bf16x8*)&sCt[(ct*16+fr)*64 + (((kc*4+kbg)^sw)<<3)];
        acc2[ct] = MFMA16(av,bv,acc2[ct]);
      }
    }
    if (mc<7) { SOFT_BAR_VM(0); }
  }
  #pragma unroll
  for (int j=0;j<4;++j){
    #pragma unroll
    for (int s=1;s<16;s<<=1){
      dp[j] += __shfl_xor(dp[j],s,64);
      rs[j] += __shfl_xor(rs[j],s,64);
      mx[j]  = fmaxf(mx[j], __shfl_xor(mx[j],s,64));
    }
  }
  float mk  = decf(kmaxEnc[bh]);
  float emk = __expf(mk);
  float Ssum = kcssum[bh];
  const float eps=1e-4f;
  float emq[4];
  #pragma unroll
  for (int j=0;j<4;++j) emq[j]=__expf(mx[j]);
  #pragma unroll
  for (int ct=0;ct<4;++ct){
    int d = ct*16 + fr;
    float cs = ctxsum[bh*64 + d];
    float vs = vsum[bh*64 + d];
    #pragma unroll
    for (int j=0;j<4;++j){
      float eq = emq[j];
      float numer = acc2[ct][j] + eps*(emk*vs*rs[j] + eq*cs + eps*eq*emk*512.0f*vs);
      float den   = dp[j]       + eps*(emk*2048.0f*rs[j] + eq*Ssum + eps*eq*emk*512.0f*2048.0f);
      int row = t0 + w*16 + rowg + j;
      outc[(size_t)row*512 + h*64 + d] = f2bf(numer/den);
    }
  }
}

extern "C" void kernel_launch(void* const* d_in, const int* in_sizes, int n_in,
                              void* d_out, int out_size, void* d_ws, size_t ws_size,
                              hipStream_t stream)
{
  (void)in_sizes; (void)n_in; (void)out_size; (void)ws_size;
  const float* x    = (const float*)d_in[0];
  const float* Wq   = (const float*)d_in[1];
  const float* bq   = (const float*)d_in[2];
  const float* Wk   = (const float*)d_in[3];
  const float* bk   = (const float*)d_in[4];
  const float* Wv   = (const float*)d_in[5];
  const float* bv   = (const float*)d_in[6];
  const float* Wo   = (const float*)d_in[7];
  const float* bo   = (const float*)d_in[8];
  const float* proj = (const float*)d_in[9];

  char* w = (char*)d_ws;
  size_t off=0;
  auto alloc=[&](size_t bytes)->char*{ char* p=w+off; off=(off+bytes+255)&~(size_t)255; return p; };
  u16*  xb   = (u16*)alloc(8192ull*512*2);
  u16*  qB   = (u16*)alloc(8192ull*512*2);
  u16*  kBf  = (u16*)alloc(8192ull*512*2);
  u16*  vB   = (u16*)alloc(8192ull*512*2);
  u16*  vT   = (u16*)alloc(32ull*64*2048*2);
  u16*  WqT  = (u16*)alloc(512ull*512*2);
  u16*  WkT  = (u16*)alloc(512ull*512*2);
  u16*  WvT  = (u16*)alloc(512ull*512*2);
  u16*  WoT  = (u16*)alloc(512ull*512*2);
  u16*  projS= (u16*)alloc(512ull*64*2);
  u16*  ctxT = (u16*)alloc(32ull*64*512*2);
  float* ctxPT=(float*)alloc(4ull*32*64*512*4);
  float* kcs = (float*)alloc(32ull*512*4);
  float* kcsP= (float*)alloc(4ull*32*512*4);
  float* diagK=(float*)alloc(32ull*2048*4);
  u32*  kmx  = (u32*)alloc(256);
  float* ctxs= (float*)alloc(32ull*64*4);
  float* kcss= (float*)alloc(32ull*4);
  float* vsm = (float*)alloc(32ull*64*4);
  u16*  outc = kBf;  // kBf dead after k_kpctx6; reuse

  dim3 TB(256);
  k_setup<<<dim3(1280),TB,0,stream>>>(kmx,projS,proj,x,xb, Wq,Wk,Wv,Wo, WqT,WkT,WvT,WoT);
  k_gemm2<false><<<dim3(64,8,3),TB,0,stream>>>(xb, WqT,WkT,WvT, bq,bk,bv, qB,kBf,vB);
  k_prep<<<dim3(4384),TB,0,stream>>>(vB, vT, vsm, kBf, diagK);
  k_kpctx6<<<dim3(8,32,4),TB,0,stream>>>(kBf, projS, vT, diagK, ctxPT, kcsP, kmx);
  k_comb4<<<dim3(32,8),TB,0,stream>>>(ctxPT, ctxT, kcsP, kcs, ctxs, kcss);
  k_qpout3<<<dim3(8,32,4),TB,0,stream>>>(qB, projS, kcs, ctxT, ctxs, kcss, vsm, kmx, outc);
  k_gemm2<true><<<dim3(64,8,1),TB,0,stream>>>(outc, WoT,WoT,WoT, bo,bo,bo,
                                              d_out,d_out,d_out);
}